// Round 9
// baseline (317.550 us; speedup 1.0000x reference)
//
#include <hip/hip_runtime.h>
#include <math.h>

#define NG 128          // graphs
#define NPG 256         // nodes per graph
#define NN 32768        // total nodes
#define HDIM 256        // hidden
#define FIN 128         // input features

// ---------------- CSR build: block per graph, LDS counting sort ----------------
__global__ __launch_bounds__(256) void k_csr(const int* __restrict__ esrc,
                                             const int* __restrict__ edst, int EPG,
                                             int* __restrict__ rowptr, int* __restrict__ csr) {
    __shared__ int cnt[NPG];
    __shared__ int pref[NPG];
    __shared__ int cur[NPG];
    int g = blockIdx.x, tid = threadIdx.x;
    cnt[tid] = 0;
    __syncthreads();
    int base = g * EPG;
    for (int e = base + tid; e < base + EPG; e += 256)
        atomicAdd(&cnt[edst[e] & (NPG - 1)], 1);
    __syncthreads();
    int v = cnt[tid];
    pref[tid] = v;
    __syncthreads();
    for (int off = 1; off < NPG; off <<= 1) {
        int t = (tid >= off) ? pref[tid - off] : 0;
        __syncthreads();
        pref[tid] += t;
        __syncthreads();
    }
    int excl = pref[tid] - v;
    rowptr[g * NPG + tid] = base + excl;
    cur[tid] = base + excl;
    if (g == 0 && tid == 0) rowptr[NN] = NG * EPG;
    __syncthreads();
    for (int e = base + tid; e < base + EPG; e += 256) {
        int d = edst[e] & (NPG - 1);
        int p = atomicAdd(&cur[d], 1);
        csr[p] = esrc[e];
    }
}

// canonical sort by src value + stage-1 edge weights (all nodes active)
__global__ __launch_bounds__(256) void k_sortw(const int* __restrict__ rowptr,
                                               int* __restrict__ csr,
                                               float* __restrict__ wedge) {
    int wid = (blockIdx.x * blockDim.x + threadIdx.x) >> 6;
    int lane = threadIdx.x & 63;
    if (wid >= NN) return;
    int e0 = rowptr[wid];
    int d = rowptr[wid + 1] - e0;
    if (d == 0) return;
    float ddst = rsqrtf((float)(1 + d));
    if (d <= 64) {
        int key = (lane < d) ? csr[e0 + lane] : 0x7fffffff;
        int rank = 0;
        for (int j = 0; j < d; j++) {
            int kj = __shfl(key, j);
            rank += (kj < key || (kj == key && j < lane)) ? 1 : 0;
        }
        if (lane < d) {
            csr[e0 + rank] = key;
            int sdeg = rowptr[key + 1] - rowptr[key];
            wedge[e0 + rank] = rsqrtf((float)(1 + sdeg)) * ddst;
        }
    } else if (lane == 0) {
        for (int a = e0 + 1; a < e0 + d; a++) {
            int key = csr[a];
            int b = a - 1;
            while (b >= e0 && csr[b] > key) { csr[b + 1] = csr[b]; b--; }
            csr[b + 1] = key;
        }
        for (int a = e0; a < e0 + d; a++) {
            int s = csr[a];
            wedge[a] = rsqrtf((float)(1 + rowptr[s + 1] - rowptr[s])) * ddst;
        }
    }
}

// ---------------- SGEMM: C[list[m] x 256] = A[list[m] x K] @ B[K x 256], f32 ----------------
// BM=128 x BN=64 tile, 8x4 per thread. As padded (stride 132) => conflict-free transpose stage.
// optional epilogues: bias+relu (brelu); per-col-block score dots (wrel/wroot -> rrel4/rroot4)
#define BM 128
#define BN 64
#define BK 16
#define BMP 132
__global__ __launch_bounds__(256) void k_sgemm(const float* __restrict__ A,
                                               const float* __restrict__ B,
                                               float* __restrict__ C, int K,
                                               const int* __restrict__ list,
                                               const float* __restrict__ brelu,
                                               const float* __restrict__ wrel,
                                               const float* __restrict__ wroot,
                                               float* __restrict__ rrel4,
                                               float* __restrict__ rroot4) {
    const int N = HDIM;
    __shared__ float As[BK][BMP];
    __shared__ float Bs[BK][BN];
    int tid = threadIdx.x;
    int tx = tid & 15, ty = tid >> 4;            // 16 x 16 thread layout
    int row0 = blockIdx.y * BM, col0 = blockIdx.x * BN;
    // A-staging rows (2 float4 per thread)
    int am[2], arow[2];
#pragma unroll
    for (int rep = 0; rep < 2; rep++) {
        int idx = rep * 256 + tid;
        am[rep] = idx >> 2;
        int r = row0 + am[rep];
        arow[rep] = list ? list[r] : r;
    }
    // C rows (8 per thread)
    int crow[8];
#pragma unroll
    for (int i = 0; i < 8; i++) {
        int r = row0 + ty * 8 + i;
        crow[i] = list ? list[r] : r;
    }
    float acc[8][4] = {};
    for (int kb = 0; kb < K; kb += BK) {
#pragma unroll
        for (int rep = 0; rep < 2; rep++) {
            int idx = rep * 256 + tid;
            int k4 = (idx & 3) * 4;
            float4 av = *reinterpret_cast<const float4*>(&A[(size_t)arow[rep] * K + kb + k4]);
            int m = am[rep];
            As[k4 + 0][m] = av.x; As[k4 + 1][m] = av.y;
            As[k4 + 2][m] = av.z; As[k4 + 3][m] = av.w;
        }
        {
            int kk = tid >> 4, c = (tid & 15) * 4;
            *reinterpret_cast<float4*>(&Bs[kk][c]) =
                *reinterpret_cast<const float4*>(&B[(size_t)(kb + kk) * N + col0 + c]);
        }
        __syncthreads();
#pragma unroll
        for (int k = 0; k < BK; k++) {
            float4 a0 = *reinterpret_cast<float4*>(&As[k][ty * 8]);
            float4 a1 = *reinterpret_cast<float4*>(&As[k][ty * 8 + 4]);
            float4 b  = *reinterpret_cast<float4*>(&Bs[k][tx * 4]);
            float av[8] = {a0.x, a0.y, a0.z, a0.w, a1.x, a1.y, a1.z, a1.w};
            float bv[4] = {b.x, b.y, b.z, b.w};
#pragma unroll
            for (int i = 0; i < 8; i++)
#pragma unroll
                for (int j = 0; j < 4; j++) acc[i][j] += av[i] * bv[j];
        }
        __syncthreads();
    }
    float4 bb = make_float4(0.f, 0.f, 0.f, 0.f);
    if (brelu) bb = *reinterpret_cast<const float4*>(&brelu[col0 + tx * 4]);
    float4 wr = make_float4(0.f, 0.f, 0.f, 0.f), wo = wr;
    if (wrel) {
        wr = *reinterpret_cast<const float4*>(&wrel[col0 + tx * 4]);
        wo = *reinterpret_cast<const float4*>(&wroot[col0 + tx * 4]);
    }
#pragma unroll
    for (int i = 0; i < 8; i++) {
        float4 v = make_float4(acc[i][0], acc[i][1], acc[i][2], acc[i][3]);
        if (brelu) {
            v.x = fmaxf(v.x + bb.x, 0.f);
            v.y = fmaxf(v.y + bb.y, 0.f);
            v.z = fmaxf(v.z + bb.z, 0.f);
            v.w = fmaxf(v.w + bb.w, 0.f);
        }
        *reinterpret_cast<float4*>(&C[(size_t)crow[i] * N + col0 + tx * 4]) = v;
        if (wrel) {
            float s1 = v.x * wr.x + v.y * wr.y + v.z * wr.z + v.w * wr.w;
            float s2 = v.x * wo.x + v.y * wo.y + v.z * wo.z + v.w * wo.w;
            for (int off = 8; off > 0; off >>= 1) {
                s1 += __shfl_down(s1, off, 16);
                s2 += __shfl_down(s2, off, 16);
            }
            if (tx == 0) {
                rrel4[(size_t)crow[i] * 4 + blockIdx.x] = s1;
                rroot4[(size_t)crow[i] * 4 + blockIdx.x] = s2;
            }
        }
    }
}

// ---------------- stage 1 aggregation (dis inline from degrees) ----------------
__device__ __forceinline__ int swz_block(int bid, int bpg) {
    int xcd = bid & 7, r = bid >> 3;
    int graph = xcd * (NG / 8) + r / bpg;
    int sub = r - (r / bpg) * bpg;
    return graph * bpg + sub;
}

__global__ __launch_bounds__(256) void k_aggx(const float* __restrict__ x,
                                              const int* __restrict__ rowptr,
                                              const int* __restrict__ csr,
                                              const float* __restrict__ wedge,
                                              float* __restrict__ xa) {
    int blk = swz_block(blockIdx.x, NPG / 8);
    int n = blk * 8 + (threadIdx.x >> 5);
    int lane = threadIdx.x & 31;
    const float4* xp = reinterpret_cast<const float4*>(x);
    int e0 = rowptr[n], e1 = rowptr[n + 1];
    float di = rsqrtf((float)(1 + e1 - e0));
    float4 h = xp[(size_t)n * (FIN / 4) + lane];
    float self = di * di;
    float ax = h.x * self, ay = h.y * self, az = h.z * self, aw = h.w * self;
    for (int e = e0; e < e1; e++) {
        int s = csr[e];
        float w = wedge[e];
        float4 hs = xp[(size_t)s * (FIN / 4) + lane];
        ax += hs.x * w; ay += hs.y * w; az += hs.z * w; aw += hs.w * w;
    }
    float4 o = make_float4(ax, ay, az, aw);
    reinterpret_cast<float4*>(xa)[(size_t)n * (FIN / 4) + lane] = o;
}

// stages 2/3: wave per ACTIVE node, gather on hW, fused bias+relu+score dots
__global__ __launch_bounds__(256) void k_gcn_agg(const float* __restrict__ hW,
                                                 const float* __restrict__ dis,
                                                 const int* __restrict__ rowptr,
                                                 const int* __restrict__ csr,
                                                 const float* __restrict__ wedge,
                                                 const float* __restrict__ bias,
                                                 const int* __restrict__ list, int bpg,
                                                 const float* __restrict__ w_rel,
                                                 const float* __restrict__ w_root,
                                                 float* __restrict__ out,
                                                 float* __restrict__ r_rel,
                                                 float* __restrict__ r_root) {
    int blk = swz_block(blockIdx.x, bpg);
    int idx = blk * 4 + (threadIdx.x >> 6);
    int lane = threadIdx.x & 63;
    int wid = list[idx];
    float di = dis[wid];
    float4 h = *reinterpret_cast<const float4*>(&hW[(size_t)wid * HDIM + lane * 4]);
    float self = di * di;
    float ax = h.x * self, ay = h.y * self, az = h.z * self, aw = h.w * self;
    int e0 = rowptr[wid], e1 = rowptr[wid + 1];
    for (int e = e0; e < e1; e++) {
        float w = wedge[e];
        if (w > 0.f) {
            int s = csr[e];
            float4 hs = *reinterpret_cast<const float4*>(&hW[(size_t)s * HDIM + lane * 4]);
            ax += hs.x * w; ay += hs.y * w; az += hs.z * w; aw += hs.w * w;
        }
    }
    float4 b = *reinterpret_cast<const float4*>(&bias[lane * 4]);
    float4 o;
    o.x = fmaxf(ax + b.x, 0.f);
    o.y = fmaxf(ay + b.y, 0.f);
    o.z = fmaxf(az + b.z, 0.f);
    o.w = fmaxf(aw + b.w, 0.f);
    *reinterpret_cast<float4*>(&out[(size_t)wid * HDIM + lane * 4]) = o;
    float4 wr = *reinterpret_cast<const float4*>(&w_rel[lane * 4]);
    float4 wo = *reinterpret_cast<const float4*>(&w_root[lane * 4]);
    float s1 = o.x * wr.x + o.y * wr.y + o.z * wr.z + o.w * wr.w;
    float s2 = o.x * wo.x + o.y * wo.y + o.z * wo.z + o.w * wo.w;
    for (int off = 32; off > 0; off >>= 1) {
        s1 += __shfl_down(s1, off);
        s2 += __shfl_down(s2, off);
    }
    if (lane == 0) { r_rel[wid] = s1; r_root[wid] = s2; }
}

// fused score + stable top-k + (optionally) next-stage dis/wedge, block per graph
template<bool STAGE1, bool EMIT>
__global__ __launch_bounds__(256) void k_topkf(const float* __restrict__ dis,
                                               const int* __restrict__ rowptr,
                                               const int* __restrict__ csr,
                                               const float* __restrict__ r_rel,
                                               const float* __restrict__ r_root,
                                               const float* __restrict__ rrel4,
                                               const float* __restrict__ rroot4,
                                               const float* __restrict__ b_rel, int k,
                                               int* __restrict__ list,
                                               float* __restrict__ tansel,
                                               float* __restrict__ disN,
                                               float* __restrict__ wedgeN) {
    __shared__ float rrel[NPG];
    __shared__ float sc[NPG];
    __shared__ int pref[NPG];
    __shared__ int sels[NPG];
    __shared__ float disn[NPG];
    int g = blockIdx.x, tid = threadIdx.x;
    int n = g * NPG + tid;
    bool act = STAGE1 ? true : (dis[n] > 0.f);
    float rr, ro;
    if (STAGE1) {
        rr = ((rrel4[(size_t)n * 4 + 0] + rrel4[(size_t)n * 4 + 1]) +
              rrel4[(size_t)n * 4 + 2]) + rrel4[(size_t)n * 4 + 3];
        ro = ((rroot4[(size_t)n * 4 + 0] + rroot4[(size_t)n * 4 + 1]) +
              rroot4[(size_t)n * 4 + 2]) + rroot4[(size_t)n * 4 + 3];
    } else {
        rr = act ? r_rel[n] : 0.f;
        ro = act ? r_root[n] : 0.f;
    }
    rrel[tid] = act ? rr : 0.f;
    __syncthreads();
    int e0 = rowptr[n], e1 = rowptr[n + 1];
    float my;
    if (act) {
        float s = b_rel[0] + ro;
        for (int e = e0; e < e1; e++) s += rrel[csr[e] & (NPG - 1)];
        my = s;
    } else {
        my = -INFINITY;
    }
    sc[tid] = my;
    __syncthreads();
    int cnt = 0;
    for (int j = 0; j < NPG; j++) {
        float v = sc[j];
        cnt += (v > my || (v == my && j < tid)) ? 1 : 0;
    }
    int a = (cnt < k) ? 1 : 0;
    sels[tid] = a;
    pref[tid] = a;
    __syncthreads();
    for (int off = 1; off < NPG; off <<= 1) {
        int v = (tid >= off) ? pref[tid - off] : 0;
        __syncthreads();
        pref[tid] += v;
        __syncthreads();
    }
    if (a) {
        int rk = pref[tid] - 1;
        list[g * k + rk] = n;
        tansel[g * k + rk] = tanhf(my);
    }
    if (EMIT) {
        int c2 = 1;
        for (int e = e0; e < e1; e++) c2 += sels[csr[e] & (NPG - 1)];
        float dn = a ? rsqrtf((float)c2) : 0.f;
        disn[tid] = dn;
        disN[n] = dn;
        __syncthreads();
        if (a) {
            for (int e = e0; e < e1; e++) wedgeN[e] = disn[csr[e] & (NPG - 1)] * dn;
        }
    }
}

// grid = NG*4: block = (graph, 64-feature chunk); 256 thr = 64 feat x 4 node-partitions
template<bool FIRST>
__global__ __launch_bounds__(256) void k_poolout2(float* __restrict__ h,
                                                  const float* __restrict__ tansel,
                                                  const int* __restrict__ list, int k,
                                                  float invk, float* __restrict__ z) {
    __shared__ float tv[128];        // k <= 128
    __shared__ float red_s[4][64];
    __shared__ float red_m[4][64];
    int g = blockIdx.x >> 2, fc = blockIdx.x & 3;
    int tid = threadIdx.x;
    int x = tid & 63, y = tid >> 6;
    if (tid < k) tv[tid] = tansel[g * k + tid];
    __syncthreads();
    int f = fc * 64 + x;
    float s = 0.f, mx = -INFINITY;
    for (int idx = y; idx < k; idx += 4) {
        int node = list[g * k + idx];
        size_t p = (size_t)node * HDIM + f;
        float v = h[p] * tv[idx];
        h[p] = v;
        s += v;
        mx = fmaxf(mx, v);
    }
    red_s[y][x] = s;
    red_m[y][x] = mx;
    __syncthreads();
    if (y == 0) {
        s = red_s[0][x] + red_s[1][x] + red_s[2][x] + red_s[3][x];
        mx = fmaxf(fmaxf(red_m[0][x], red_m[1][x]), fmaxf(red_m[2][x], red_m[3][x]));
        if (FIRST) {
            z[g * 768 + f] = s * invk;
            z[g * 768 + 256 + f] = mx;
            z[g * 768 + 512 + f] = s;
        } else {
            z[g * 768 + f] += s * invk;
            z[g * 768 + 256 + f] += mx;
            z[g * 768 + 512 + f] += s;
        }
    }
}

// ---------------- MLP ----------------
__global__ __launch_bounds__(256) void k_fc1(const float* __restrict__ z,
                                             const float* __restrict__ W1,
                                             const float* __restrict__ b1,
                                             float* __restrict__ t1) {
    __shared__ float zb[768];
    __shared__ float red[4][64];
    int g = blockIdx.x >> 2, oc = blockIdx.x & 3;
    int tid = threadIdx.x;
    zb[tid] = z[g * 768 + tid];
    zb[tid + 256] = z[g * 768 + 256 + tid];
    zb[tid + 512] = z[g * 768 + 512 + tid];
    __syncthreads();
    int x = tid & 63, y = tid >> 6;
    int col = oc * 64 + x;
    float s = 0.f;
    for (int i = y * 192; i < (y + 1) * 192; i++) s += zb[i] * W1[(size_t)i * 256 + col];
    red[y][x] = s;
    __syncthreads();
    if (y == 0) {
        float t = red[0][x] + red[1][x] + red[2][x] + red[3][x] + b1[col];
        t1[g * 256 + col] = fmaxf(t, 0.f);
    }
}

__global__ __launch_bounds__(256) void k_fc2(const float* __restrict__ t1,
                                             const float* __restrict__ W2,
                                             const float* __restrict__ b2,
                                             float* __restrict__ t2) {
    __shared__ float t1s[256];
    __shared__ float red[4][64];
    int g = blockIdx.x >> 1, oc = blockIdx.x & 1;
    int tid = threadIdx.x;
    t1s[tid] = t1[g * 256 + tid];
    __syncthreads();
    int x = tid & 63, y = tid >> 6;
    int col = oc * 64 + x;
    float s = 0.f;
    for (int i = y * 64; i < (y + 1) * 64; i++) s += t1s[i] * W2[(size_t)i * 128 + col];
    red[y][x] = s;
    __syncthreads();
    if (y == 0) {
        float t = ((red[0][x] + red[1][x]) + red[2][x]) + red[3][x] + b2[col];
        t2[g * 128 + col] = fmaxf(t, 0.f);
    }
}

__global__ __launch_bounds__(256) void k_fc3(const float* __restrict__ t2,
                                             const float* __restrict__ W3,
                                             const float* __restrict__ b3,
                                             float* __restrict__ out) {
    __shared__ float t2s[128];
    __shared__ float t3[10];
    __shared__ float lse;
    int g = blockIdx.x, tid = threadIdx.x;
    if (tid < 128) t2s[tid] = t2[g * 128 + tid];
    __syncthreads();
    if (tid < 10) {
        float v = b3[tid];
        for (int i = 0; i < 128; i++) v += t2s[i] * W3[(size_t)i * 10 + tid];
        t3[tid] = v;
    }
    __syncthreads();
    if (tid == 0) {
        float m = t3[0];
        for (int c = 1; c < 10; c++) m = fmaxf(m, t3[c]);
        float se = 0.f;
        for (int c = 0; c < 10; c++) se += expf(t3[c] - m);
        lse = m + logf(se);
    }
    __syncthreads();
    if (tid < 10) out[g * 10 + tid] = t3[tid] - lse;
}

// ---------------- launcher ----------------
extern "C" void kernel_launch(void* const* d_in, const int* in_sizes, int n_in,
                              void* d_out, int out_size, void* d_ws, size_t ws_size,
                              hipStream_t stream) {
    const float* x        = (const float*)d_in[0];
    const int*   ei       = (const int*)d_in[1];
    const float* conv1_W  = (const float*)d_in[3];
    const float* conv1_b  = (const float*)d_in[4];
    const float* conv2_W  = (const float*)d_in[5];
    const float* conv2_b  = (const float*)d_in[6];
    const float* conv3_W  = (const float*)d_in[7];
    const float* conv3_b  = (const float*)d_in[8];
    const float* p1_relW  = (const float*)d_in[9];
    const float* p1_relb  = (const float*)d_in[10];
    const float* p1_rootW = (const float*)d_in[11];
    const float* p2_relW  = (const float*)d_in[12];
    const float* p2_relb  = (const float*)d_in[13];
    const float* p2_rootW = (const float*)d_in[14];
    const float* fc1_W    = (const float*)d_in[15];
    const float* fc1_b    = (const float*)d_in[16];
    const float* fc2_W    = (const float*)d_in[17];
    const float* fc2_b    = (const float*)d_in[18];
    const float* fc3_W    = (const float*)d_in[19];
    const float* fc3_b    = (const float*)d_in[20];
    float* out = (float*)d_out;

    const int E = in_sizes[1] / 2;
    const int EPG = E / NG;
    const int* e_src = ei;
    const int* e_dst = ei + E;

    // workspace layout
    char* base = (char*)d_ws;
    size_t off = 0;
    auto alloc = [&](size_t bytes) { size_t o = off; off = (off + bytes + 255) & ~(size_t)255; return o; };
    float* hW     = (float*)(base + alloc((size_t)NN * HDIM * 4));   // also xa (NN x FIN)
    float* hcur   = (float*)(base + alloc((size_t)NN * HDIM * 4));
    float* dis    = (float*)(base + alloc(NN * 4));
    float* r_rel  = (float*)(base + alloc(NN * 4));
    float* r_root = (float*)(base + alloc(NN * 4));
    float* rrel4  = (float*)(base + alloc((size_t)NN * 4 * 4));
    float* rroot4 = (float*)(base + alloc((size_t)NN * 4 * 4));
    int*   rowptr = (int*)(base + alloc((NN + 1) * 4));
    int*   csr    = (int*)(base + alloc((size_t)E * 4));
    float* wedge  = (float*)(base + alloc((size_t)E * 4));
    float* z      = (float*)(base + alloc((size_t)NG * 768 * 4));
    float* t1buf  = (float*)(base + alloc((size_t)NG * 256 * 4));
    float* t2buf  = (float*)(base + alloc((size_t)NG * 128 * 4));
    int*   list1  = (int*)(base + alloc((size_t)NG * 128 * 4));
    int*   list2  = (int*)(base + alloc((size_t)NG * 64 * 4));
    int*   list3  = (int*)(base + alloc((size_t)NG * 32 * 4));
    float* tans1  = (float*)(base + alloc((size_t)NG * 128 * 4));
    float* tans2  = (float*)(base + alloc((size_t)NG * 64 * 4));
    float* tans3  = (float*)(base + alloc((size_t)NG * 32 * 4));

    // CSR build (canonical sorted-by-src order => deterministic) + stage-1 wedge
    k_csr<<<NG, 256, 0, stream>>>(e_src, e_dst, EPG, rowptr, csr);
    k_sortw<<<NN * 64 / 256, 256, 0, stream>>>(rowptr, csr, wedge);

    float* xa = hW;

    // ---- stage 1 ----
    k_aggx<<<NN / 8, 256, 0, stream>>>(x, rowptr, csr, wedge, xa);
    {
        dim3 ggrid(HDIM / BN, NN / BM);
        k_sgemm<<<ggrid, 256, 0, stream>>>(xa, conv1_W, hcur, FIN, nullptr, conv1_b,
                                           p1_relW, p1_rootW, rrel4, rroot4);
    }
    k_topkf<true, true><<<NG, 256, 0, stream>>>(nullptr, rowptr, csr, nullptr, nullptr,
                                                rrel4, rroot4, p1_relb, 128,
                                                list1, tans1, dis, wedge);
    k_poolout2<true><<<NG * 4, 256, 0, stream>>>(hcur, tans1, list1, 128, 1.0f / 128.0f, z);

    // ---- stage 2 ----
    {
        dim3 ggrid(HDIM / BN, (NG * 128) / BM);
        k_sgemm<<<ggrid, 256, 0, stream>>>(hcur, conv2_W, hW, HDIM, list1, nullptr,
                                           nullptr, nullptr, nullptr, nullptr);
    }
    k_gcn_agg<<<(NG * 128) / 4, 256, 0, stream>>>(hW, dis, rowptr, csr, wedge, conv2_b,
                                                  list1, 32, p2_relW, p2_rootW,
                                                  hcur, r_rel, r_root);
    k_topkf<false, true><<<NG, 256, 0, stream>>>(dis, rowptr, csr, r_rel, r_root,
                                                 nullptr, nullptr, p2_relb, 64,
                                                 list2, tans2, dis, wedge);
    k_poolout2<false><<<NG * 4, 256, 0, stream>>>(hcur, tans2, list2, 64, 1.0f / 64.0f, z);

    // ---- stage 3 ----
    {
        dim3 ggrid(HDIM / BN, (NG * 64) / BM);
        k_sgemm<<<ggrid, 256, 0, stream>>>(hcur, conv3_W, hW, HDIM, list2, nullptr,
                                           nullptr, nullptr, nullptr, nullptr);
    }
    k_gcn_agg<<<(NG * 64) / 4, 256, 0, stream>>>(hW, dis, rowptr, csr, wedge, conv3_b,
                                                 list2, 16, p2_relW, p2_rootW,
                                                 hcur, r_rel, r_root);
    k_topkf<false, false><<<NG, 256, 0, stream>>>(dis, rowptr, csr, r_rel, r_root,
                                                  nullptr, nullptr, p2_relb, 32,
                                                  list3, tans3, nullptr, nullptr);
    k_poolout2<false><<<NG * 4, 256, 0, stream>>>(hcur, tans3, list3, 32, 1.0f / 32.0f, z);

    // ---- MLP ----
    k_fc1<<<NG * 4, 256, 0, stream>>>(z, fc1_W, fc1_b, t1buf);
    k_fc2<<<NG * 2, 256, 0, stream>>>(t1buf, fc2_W, fc2_b, t2buf);
    k_fc3<<<NG, 256, 0, stream>>>(t2buf, fc3_W, fc3_b, out);
}

// Round 10
// 309.086 us; speedup vs baseline: 1.0274x; 1.0274x over previous
//
#include <hip/hip_runtime.h>
#include <math.h>

#define NG 128          // graphs
#define NPG 256         // nodes per graph
#define NN 32768        // total nodes
#define HDIM 256        // hidden
#define FIN 128         // input features

// ---------------- CSR build: block per graph, LDS counting sort ----------------
__global__ __launch_bounds__(256) void k_csr(const int* __restrict__ esrc,
                                             const int* __restrict__ edst, int EPG,
                                             int* __restrict__ rowptr, int* __restrict__ csr) {
    __shared__ int cnt[NPG];
    __shared__ int pref[NPG];
    __shared__ int cur[NPG];
    int g = blockIdx.x, tid = threadIdx.x;
    cnt[tid] = 0;
    __syncthreads();
    int base = g * EPG;
    for (int e = base + tid; e < base + EPG; e += 256)
        atomicAdd(&cnt[edst[e] & (NPG - 1)], 1);
    __syncthreads();
    int v = cnt[tid];
    pref[tid] = v;
    __syncthreads();
    for (int off = 1; off < NPG; off <<= 1) {
        int t = (tid >= off) ? pref[tid - off] : 0;
        __syncthreads();
        pref[tid] += t;
        __syncthreads();
    }
    int excl = pref[tid] - v;
    rowptr[g * NPG + tid] = base + excl;
    cur[tid] = base + excl;
    if (g == 0 && tid == 0) rowptr[NN] = NG * EPG;
    __syncthreads();
    for (int e = base + tid; e < base + EPG; e += 256) {
        int d = edst[e] & (NPG - 1);
        int p = atomicAdd(&cur[d], 1);
        csr[p] = esrc[e];
    }
}

// canonical sort by src value + stage-1 edge weights (all nodes active)
__global__ __launch_bounds__(256) void k_sortw(const int* __restrict__ rowptr,
                                               int* __restrict__ csr,
                                               float* __restrict__ wedge) {
    int wid = (blockIdx.x * blockDim.x + threadIdx.x) >> 6;
    int lane = threadIdx.x & 63;
    if (wid >= NN) return;
    int e0 = rowptr[wid];
    int d = rowptr[wid + 1] - e0;
    if (d == 0) return;
    float ddst = rsqrtf((float)(1 + d));
    if (d <= 64) {
        int key = (lane < d) ? csr[e0 + lane] : 0x7fffffff;
        int rank = 0;
        for (int j = 0; j < d; j++) {
            int kj = __shfl(key, j);
            rank += (kj < key || (kj == key && j < lane)) ? 1 : 0;
        }
        if (lane < d) {
            csr[e0 + rank] = key;
            int sdeg = rowptr[key + 1] - rowptr[key];
            wedge[e0 + rank] = rsqrtf((float)(1 + sdeg)) * ddst;
        }
    } else if (lane == 0) {
        for (int a = e0 + 1; a < e0 + d; a++) {
            int key = csr[a];
            int b = a - 1;
            while (b >= e0 && csr[b] > key) { csr[b + 1] = csr[b]; b--; }
            csr[b + 1] = key;
        }
        for (int a = e0; a < e0 + d; a++) {
            int s = csr[a];
            wedge[a] = rsqrtf((float)(1 + rowptr[s + 1] - rowptr[s])) * ddst;
        }
    }
}

// ---------------- SGEMM: C[list[m] x 256] = A[list[m] x K] @ B[K x 256], f32 ----------------
// BM=64 x BN=64, 4x4 micro-tile (R8-proven geometry). As padded to stride 68:
// transpose-store bank = (16*(tid&3) + tid>>2 + 4j) % 32 -> exact 2-way (free, m136);
// compute read As[k][ty*4] -> 4 distinct banks, conflict-free.
// optional epilogues: bias+relu (brelu); per-col-block score dots (wrel/wroot -> rrel4/rroot4)
#define BM 64
#define BN 64
#define BK 16
#define BMP 68
__global__ __launch_bounds__(256) void k_sgemm(const float* __restrict__ A,
                                               const float* __restrict__ B,
                                               float* __restrict__ C, int K,
                                               const int* __restrict__ list,
                                               const float* __restrict__ brelu,
                                               const float* __restrict__ wrel,
                                               const float* __restrict__ wroot,
                                               float* __restrict__ rrel4,
                                               float* __restrict__ rroot4) {
    const int N = HDIM;
    __shared__ float As[BK][BMP];
    __shared__ float Bs[BK][BN];
    int tid = threadIdx.x;
    int tx = tid & 15, ty = tid >> 4;
    int row0 = blockIdx.y * BM, col0 = blockIdx.x * BN;
    int lm = tid >> 2;
    int arow = list ? list[row0 + lm] : (row0 + lm);
    int crow[4];
#pragma unroll
    for (int i = 0; i < 4; i++) {
        int r = row0 + ty * 4 + i;
        crow[i] = list ? list[r] : r;
    }
    float acc[4][4] = {};
    for (int kb = 0; kb < K; kb += BK) {
        {
            int k = (tid & 3) * 4;
            float4 av = *reinterpret_cast<const float4*>(&A[(size_t)arow * K + kb + k]);
            As[k + 0][lm] = av.x; As[k + 1][lm] = av.y; As[k + 2][lm] = av.z; As[k + 3][lm] = av.w;
        }
        {
            int l = tid * 4;
            int k = l >> 6, c = l & 63;
            *reinterpret_cast<float4*>(&Bs[k][c]) =
                *reinterpret_cast<const float4*>(&B[(size_t)(kb + k) * N + col0 + c]);
        }
        __syncthreads();
#pragma unroll
        for (int k = 0; k < BK; k++) {
            float4 a = *reinterpret_cast<float4*>(&As[k][ty * 4]);
            float4 b = *reinterpret_cast<float4*>(&Bs[k][tx * 4]);
            float av[4] = {a.x, a.y, a.z, a.w};
            float bv[4] = {b.x, b.y, b.z, b.w};
#pragma unroll
            for (int i = 0; i < 4; i++)
#pragma unroll
                for (int j = 0; j < 4; j++) acc[i][j] += av[i] * bv[j];
        }
        __syncthreads();
    }
    float4 bb = make_float4(0.f, 0.f, 0.f, 0.f);
    if (brelu) bb = *reinterpret_cast<const float4*>(&brelu[col0 + tx * 4]);
    float4 wr = make_float4(0.f, 0.f, 0.f, 0.f), wo = wr;
    if (wrel) {
        wr = *reinterpret_cast<const float4*>(&wrel[col0 + tx * 4]);
        wo = *reinterpret_cast<const float4*>(&wroot[col0 + tx * 4]);
    }
#pragma unroll
    for (int i = 0; i < 4; i++) {
        float4 v = make_float4(acc[i][0], acc[i][1], acc[i][2], acc[i][3]);
        if (brelu) {
            v.x = fmaxf(v.x + bb.x, 0.f);
            v.y = fmaxf(v.y + bb.y, 0.f);
            v.z = fmaxf(v.z + bb.z, 0.f);
            v.w = fmaxf(v.w + bb.w, 0.f);
        }
        *reinterpret_cast<float4*>(&C[(size_t)crow[i] * N + col0 + tx * 4]) = v;
        if (wrel) {
            float s1 = v.x * wr.x + v.y * wr.y + v.z * wr.z + v.w * wr.w;
            float s2 = v.x * wo.x + v.y * wo.y + v.z * wo.z + v.w * wo.w;
            for (int off = 8; off > 0; off >>= 1) {
                s1 += __shfl_down(s1, off, 16);
                s2 += __shfl_down(s2, off, 16);
            }
            if (tx == 0) {
                rrel4[(size_t)crow[i] * 4 + blockIdx.x] = s1;
                rroot4[(size_t)crow[i] * 4 + blockIdx.x] = s2;
            }
        }
    }
}

// ---------------- stage 1 aggregation (dis inline from degrees) ----------------
__device__ __forceinline__ int swz_block(int bid, int bpg) {
    int xcd = bid & 7, r = bid >> 3;
    int graph = xcd * (NG / 8) + r / bpg;
    int sub = r - (r / bpg) * bpg;
    return graph * bpg + sub;
}

__global__ __launch_bounds__(256) void k_aggx(const float* __restrict__ x,
                                              const int* __restrict__ rowptr,
                                              const int* __restrict__ csr,
                                              const float* __restrict__ wedge,
                                              float* __restrict__ xa) {
    int blk = swz_block(blockIdx.x, NPG / 8);
    int n = blk * 8 + (threadIdx.x >> 5);
    int lane = threadIdx.x & 31;
    const float4* xp = reinterpret_cast<const float4*>(x);
    int e0 = rowptr[n], e1 = rowptr[n + 1];
    float di = rsqrtf((float)(1 + e1 - e0));
    float4 h = xp[(size_t)n * (FIN / 4) + lane];
    float self = di * di;
    float ax = h.x * self, ay = h.y * self, az = h.z * self, aw = h.w * self;
    for (int e = e0; e < e1; e++) {
        int s = csr[e];
        float w = wedge[e];
        float4 hs = xp[(size_t)s * (FIN / 4) + lane];
        ax += hs.x * w; ay += hs.y * w; az += hs.z * w; aw += hs.w * w;
    }
    float4 o = make_float4(ax, ay, az, aw);
    reinterpret_cast<float4*>(xa)[(size_t)n * (FIN / 4) + lane] = o;
}

// stages 2/3: wave per ACTIVE node, gather on hW, fused bias+relu+score dots
__global__ __launch_bounds__(256) void k_gcn_agg(const float* __restrict__ hW,
                                                 const float* __restrict__ dis,
                                                 const int* __restrict__ rowptr,
                                                 const int* __restrict__ csr,
                                                 const float* __restrict__ wedge,
                                                 const float* __restrict__ bias,
                                                 const int* __restrict__ list, int bpg,
                                                 const float* __restrict__ w_rel,
                                                 const float* __restrict__ w_root,
                                                 float* __restrict__ out,
                                                 float* __restrict__ r_rel,
                                                 float* __restrict__ r_root) {
    int blk = swz_block(blockIdx.x, bpg);
    int idx = blk * 4 + (threadIdx.x >> 6);
    int lane = threadIdx.x & 63;
    int wid = list[idx];
    float di = dis[wid];
    float4 h = *reinterpret_cast<const float4*>(&hW[(size_t)wid * HDIM + lane * 4]);
    float self = di * di;
    float ax = h.x * self, ay = h.y * self, az = h.z * self, aw = h.w * self;
    int e0 = rowptr[wid], e1 = rowptr[wid + 1];
    for (int e = e0; e < e1; e++) {
        float w = wedge[e];
        if (w > 0.f) {
            int s = csr[e];
            float4 hs = *reinterpret_cast<const float4*>(&hW[(size_t)s * HDIM + lane * 4]);
            ax += hs.x * w; ay += hs.y * w; az += hs.z * w; aw += hs.w * w;
        }
    }
    float4 b = *reinterpret_cast<const float4*>(&bias[lane * 4]);
    float4 o;
    o.x = fmaxf(ax + b.x, 0.f);
    o.y = fmaxf(ay + b.y, 0.f);
    o.z = fmaxf(az + b.z, 0.f);
    o.w = fmaxf(aw + b.w, 0.f);
    *reinterpret_cast<float4*>(&out[(size_t)wid * HDIM + lane * 4]) = o;
    float4 wr = *reinterpret_cast<const float4*>(&w_rel[lane * 4]);
    float4 wo = *reinterpret_cast<const float4*>(&w_root[lane * 4]);
    float s1 = o.x * wr.x + o.y * wr.y + o.z * wr.z + o.w * wr.w;
    float s2 = o.x * wo.x + o.y * wo.y + o.z * wo.z + o.w * wo.w;
    for (int off = 32; off > 0; off >>= 1) {
        s1 += __shfl_down(s1, off);
        s2 += __shfl_down(s2, off);
    }
    if (lane == 0) { r_rel[wid] = s1; r_root[wid] = s2; }
}

// fused score + stable top-k + (optionally) next-stage dis/wedge, block per graph
template<bool STAGE1, bool EMIT>
__global__ __launch_bounds__(256) void k_topkf(const float* __restrict__ dis,
                                               const int* __restrict__ rowptr,
                                               const int* __restrict__ csr,
                                               const float* __restrict__ r_rel,
                                               const float* __restrict__ r_root,
                                               const float* __restrict__ rrel4,
                                               const float* __restrict__ rroot4,
                                               const float* __restrict__ b_rel, int k,
                                               int* __restrict__ list,
                                               float* __restrict__ tansel,
                                               float* __restrict__ disN,
                                               float* __restrict__ wedgeN) {
    __shared__ float rrel[NPG];
    __shared__ float sc[NPG];
    __shared__ int pref[NPG];
    __shared__ int sels[NPG];
    __shared__ float disn[NPG];
    int g = blockIdx.x, tid = threadIdx.x;
    int n = g * NPG + tid;
    bool act = STAGE1 ? true : (dis[n] > 0.f);
    float rr, ro;
    if (STAGE1) {
        rr = ((rrel4[(size_t)n * 4 + 0] + rrel4[(size_t)n * 4 + 1]) +
              rrel4[(size_t)n * 4 + 2]) + rrel4[(size_t)n * 4 + 3];
        ro = ((rroot4[(size_t)n * 4 + 0] + rroot4[(size_t)n * 4 + 1]) +
              rroot4[(size_t)n * 4 + 2]) + rroot4[(size_t)n * 4 + 3];
    } else {
        rr = act ? r_rel[n] : 0.f;
        ro = act ? r_root[n] : 0.f;
    }
    rrel[tid] = act ? rr : 0.f;
    __syncthreads();
    int e0 = rowptr[n], e1 = rowptr[n + 1];
    float my;
    if (act) {
        float s = b_rel[0] + ro;
        for (int e = e0; e < e1; e++) s += rrel[csr[e] & (NPG - 1)];
        my = s;
    } else {
        my = -INFINITY;
    }
    sc[tid] = my;
    __syncthreads();
    int cnt = 0;
    for (int j = 0; j < NPG; j++) {
        float v = sc[j];
        cnt += (v > my || (v == my && j < tid)) ? 1 : 0;
    }
    int a = (cnt < k) ? 1 : 0;
    sels[tid] = a;
    pref[tid] = a;
    __syncthreads();
    for (int off = 1; off < NPG; off <<= 1) {
        int v = (tid >= off) ? pref[tid - off] : 0;
        __syncthreads();
        pref[tid] += v;
        __syncthreads();
    }
    if (a) {
        int rk = pref[tid] - 1;
        list[g * k + rk] = n;
        tansel[g * k + rk] = tanhf(my);
    }
    if (EMIT) {
        int c2 = 1;
        for (int e = e0; e < e1; e++) c2 += sels[csr[e] & (NPG - 1)];
        float dn = a ? rsqrtf((float)c2) : 0.f;
        disn[tid] = dn;
        disN[n] = dn;
        __syncthreads();
        if (a) {
            for (int e = e0; e < e1; e++) wedgeN[e] = disn[csr[e] & (NPG - 1)] * dn;
        }
    }
}

// grid = NG*4: block = (graph, 64-feature chunk); 256 thr = 64 feat x 4 node-partitions
template<bool FIRST>
__global__ __launch_bounds__(256) void k_poolout2(float* __restrict__ h,
                                                  const float* __restrict__ tansel,
                                                  const int* __restrict__ list, int k,
                                                  float invk, float* __restrict__ z) {
    __shared__ float tv[128];        // k <= 128
    __shared__ float red_s[4][64];
    __shared__ float red_m[4][64];
    int g = blockIdx.x >> 2, fc = blockIdx.x & 3;
    int tid = threadIdx.x;
    int x = tid & 63, y = tid >> 6;
    if (tid < k) tv[tid] = tansel[g * k + tid];
    __syncthreads();
    int f = fc * 64 + x;
    float s = 0.f, mx = -INFINITY;
    for (int idx = y; idx < k; idx += 4) {
        int node = list[g * k + idx];
        size_t p = (size_t)node * HDIM + f;
        float v = h[p] * tv[idx];
        h[p] = v;
        s += v;
        mx = fmaxf(mx, v);
    }
    red_s[y][x] = s;
    red_m[y][x] = mx;
    __syncthreads();
    if (y == 0) {
        s = red_s[0][x] + red_s[1][x] + red_s[2][x] + red_s[3][x];
        mx = fmaxf(fmaxf(red_m[0][x], red_m[1][x]), fmaxf(red_m[2][x], red_m[3][x]));
        if (FIRST) {
            z[g * 768 + f] = s * invk;
            z[g * 768 + 256 + f] = mx;
            z[g * 768 + 512 + f] = s;
        } else {
            z[g * 768 + f] += s * invk;
            z[g * 768 + 256 + f] += mx;
            z[g * 768 + 512 + f] += s;
        }
    }
}

// ---------------- MLP ----------------
__global__ __launch_bounds__(256) void k_fc1(const float* __restrict__ z,
                                             const float* __restrict__ W1,
                                             const float* __restrict__ b1,
                                             float* __restrict__ t1) {
    __shared__ float zb[768];
    __shared__ float red[4][64];
    int g = blockIdx.x >> 2, oc = blockIdx.x & 3;
    int tid = threadIdx.x;
    zb[tid] = z[g * 768 + tid];
    zb[tid + 256] = z[g * 768 + 256 + tid];
    zb[tid + 512] = z[g * 768 + 512 + tid];
    __syncthreads();
    int x = tid & 63, y = tid >> 6;
    int col = oc * 64 + x;
    float s = 0.f;
    for (int i = y * 192; i < (y + 1) * 192; i++) s += zb[i] * W1[(size_t)i * 256 + col];
    red[y][x] = s;
    __syncthreads();
    if (y == 0) {
        float t = red[0][x] + red[1][x] + red[2][x] + red[3][x] + b1[col];
        t1[g * 256 + col] = fmaxf(t, 0.f);
    }
}

__global__ __launch_bounds__(256) void k_fc2(const float* __restrict__ t1,
                                             const float* __restrict__ W2,
                                             const float* __restrict__ b2,
                                             float* __restrict__ t2) {
    __shared__ float t1s[256];
    __shared__ float red[4][64];
    int g = blockIdx.x >> 1, oc = blockIdx.x & 1;
    int tid = threadIdx.x;
    t1s[tid] = t1[g * 256 + tid];
    __syncthreads();
    int x = tid & 63, y = tid >> 6;
    int col = oc * 64 + x;
    float s = 0.f;
    for (int i = y * 64; i < (y + 1) * 64; i++) s += t1s[i] * W2[(size_t)i * 128 + col];
    red[y][x] = s;
    __syncthreads();
    if (y == 0) {
        float t = ((red[0][x] + red[1][x]) + red[2][x]) + red[3][x] + b2[col];
        t2[g * 128 + col] = fmaxf(t, 0.f);
    }
}

__global__ __launch_bounds__(256) void k_fc3(const float* __restrict__ t2,
                                             const float* __restrict__ W3,
                                             const float* __restrict__ b3,
                                             float* __restrict__ out) {
    __shared__ float t2s[128];
    __shared__ float t3[10];
    __shared__ float lse;
    int g = blockIdx.x, tid = threadIdx.x;
    if (tid < 128) t2s[tid] = t2[g * 128 + tid];
    __syncthreads();
    if (tid < 10) {
        float v = b3[tid];
        for (int i = 0; i < 128; i++) v += t2s[i] * W3[(size_t)i * 10 + tid];
        t3[tid] = v;
    }
    __syncthreads();
    if (tid == 0) {
        float m = t3[0];
        for (int c = 1; c < 10; c++) m = fmaxf(m, t3[c]);
        float se = 0.f;
        for (int c = 0; c < 10; c++) se += expf(t3[c] - m);
        lse = m + logf(se);
    }
    __syncthreads();
    if (tid < 10) out[g * 10 + tid] = t3[tid] - lse;
}

// ---------------- launcher ----------------
extern "C" void kernel_launch(void* const* d_in, const int* in_sizes, int n_in,
                              void* d_out, int out_size, void* d_ws, size_t ws_size,
                              hipStream_t stream) {
    const float* x        = (const float*)d_in[0];
    const int*   ei       = (const int*)d_in[1];
    const float* conv1_W  = (const float*)d_in[3];
    const float* conv1_b  = (const float*)d_in[4];
    const float* conv2_W  = (const float*)d_in[5];
    const float* conv2_b  = (const float*)d_in[6];
    const float* conv3_W  = (const float*)d_in[7];
    const float* conv3_b  = (const float*)d_in[8];
    const float* p1_relW  = (const float*)d_in[9];
    const float* p1_relb  = (const float*)d_in[10];
    const float* p1_rootW = (const float*)d_in[11];
    const float* p2_relW  = (const float*)d_in[12];
    const float* p2_relb  = (const float*)d_in[13];
    const float* p2_rootW = (const float*)d_in[14];
    const float* fc1_W    = (const float*)d_in[15];
    const float* fc1_b    = (const float*)d_in[16];
    const float* fc2_W    = (const float*)d_in[17];
    const float* fc2_b    = (const float*)d_in[18];
    const float* fc3_W    = (const float*)d_in[19];
    const float* fc3_b    = (const float*)d_in[20];
    float* out = (float*)d_out;

    const int E = in_sizes[1] / 2;
    const int EPG = E / NG;
    const int* e_src = ei;
    const int* e_dst = ei + E;

    // workspace layout
    char* base = (char*)d_ws;
    size_t off = 0;
    auto alloc = [&](size_t bytes) { size_t o = off; off = (off + bytes + 255) & ~(size_t)255; return o; };
    float* hW     = (float*)(base + alloc((size_t)NN * HDIM * 4));   // also xa (NN x FIN)
    float* hcur   = (float*)(base + alloc((size_t)NN * HDIM * 4));
    float* dis    = (float*)(base + alloc(NN * 4));
    float* r_rel  = (float*)(base + alloc(NN * 4));
    float* r_root = (float*)(base + alloc(NN * 4));
    float* rrel4  = (float*)(base + alloc((size_t)NN * 4 * 4));
    float* rroot4 = (float*)(base + alloc((size_t)NN * 4 * 4));
    int*   rowptr = (int*)(base + alloc((NN + 1) * 4));
    int*   csr    = (int*)(base + alloc((size_t)E * 4));
    float* wedge  = (float*)(base + alloc((size_t)E * 4));
    float* z      = (float*)(base + alloc((size_t)NG * 768 * 4));
    float* t1buf  = (float*)(base + alloc((size_t)NG * 256 * 4));
    float* t2buf  = (float*)(base + alloc((size_t)NG * 128 * 4));
    int*   list1  = (int*)(base + alloc((size_t)NG * 128 * 4));
    int*   list2  = (int*)(base + alloc((size_t)NG * 64 * 4));
    int*   list3  = (int*)(base + alloc((size_t)NG * 32 * 4));
    float* tans1  = (float*)(base + alloc((size_t)NG * 128 * 4));
    float* tans2  = (float*)(base + alloc((size_t)NG * 64 * 4));
    float* tans3  = (float*)(base + alloc((size_t)NG * 32 * 4));

    // CSR build (canonical sorted-by-src order => deterministic) + stage-1 wedge
    k_csr<<<NG, 256, 0, stream>>>(e_src, e_dst, EPG, rowptr, csr);
    k_sortw<<<NN * 64 / 256, 256, 0, stream>>>(rowptr, csr, wedge);

    float* xa = hW;

    // ---- stage 1 ----
    k_aggx<<<NN / 8, 256, 0, stream>>>(x, rowptr, csr, wedge, xa);
    {
        dim3 ggrid(HDIM / BN, NN / BM);
        k_sgemm<<<ggrid, 256, 0, stream>>>(xa, conv1_W, hcur, FIN, nullptr, conv1_b,
                                           p1_relW, p1_rootW, rrel4, rroot4);
    }
    k_topkf<true, true><<<NG, 256, 0, stream>>>(nullptr, rowptr, csr, nullptr, nullptr,
                                                rrel4, rroot4, p1_relb, 128,
                                                list1, tans1, dis, wedge);
    k_poolout2<true><<<NG * 4, 256, 0, stream>>>(hcur, tans1, list1, 128, 1.0f / 128.0f, z);

    // ---- stage 2 ----
    {
        dim3 ggrid(HDIM / BN, (NG * 128) / BM);
        k_sgemm<<<ggrid, 256, 0, stream>>>(hcur, conv2_W, hW, HDIM, list1, nullptr,
                                           nullptr, nullptr, nullptr, nullptr);
    }
    k_gcn_agg<<<(NG * 128) / 4, 256, 0, stream>>>(hW, dis, rowptr, csr, wedge, conv2_b,
                                                  list1, 32, p2_relW, p2_rootW,
                                                  hcur, r_rel, r_root);
    k_topkf<false, true><<<NG, 256, 0, stream>>>(dis, rowptr, csr, r_rel, r_root,
                                                 nullptr, nullptr, p2_relb, 64,
                                                 list2, tans2, dis, wedge);
    k_poolout2<false><<<NG * 4, 256, 0, stream>>>(hcur, tans2, list2, 64, 1.0f / 64.0f, z);

    // ---- stage 3 ----
    {
        dim3 ggrid(HDIM / BN, (NG * 64) / BM);
        k_sgemm<<<ggrid, 256, 0, stream>>>(hcur, conv3_W, hW, HDIM, list2, nullptr,
                                           nullptr, nullptr, nullptr, nullptr);
    }
    k_gcn_agg<<<(NG * 64) / 4, 256, 0, stream>>>(hW, dis, rowptr, csr, wedge, conv3_b,
                                                 list2, 16, p2_relW, p2_rootW,
                                                 hcur, r_rel, r_root);
    k_topkf<false, false><<<NG, 256, 0, stream>>>(dis, rowptr, csr, r_rel, r_root,
                                                  nullptr, nullptr, p2_relb, 32,
                                                  list3, tans3, nullptr, nullptr);
    k_poolout2<false><<<NG * 4, 256, 0, stream>>>(hcur, tans3, list3, 32, 1.0f / 32.0f, z);

    // ---- MLP ----
    k_fc1<<<NG * 4, 256, 0, stream>>>(z, fc1_W, fc1_b, t1buf);
    k_fc2<<<NG * 2, 256, 0, stream>>>(t1buf, fc2_W, fc2_b, t2buf);
    k_fc3<<<NG, 256, 0, stream>>>(t2buf, fc3_W, fc3_b, out);
}

// Round 11
// 294.107 us; speedup vs baseline: 1.0797x; 1.0509x over previous
//
#include <hip/hip_runtime.h>
#include <math.h>

#define NG 128          // graphs
#define NPG 256         // nodes per graph
#define NN 32768        // total nodes
#define HDIM 256        // hidden
#define FIN 128         // in features

// ---------------- CSR build: block per graph, LDS counting sort ----------------
__global__ __launch_bounds__(256) void k_csr(const int* __restrict__ esrc,
                                             const int* __restrict__ edst, int EPG,
                                             int* __restrict__ rowptr, int* __restrict__ csr) {
    __shared__ int cnt[NPG];
    __shared__ int pref[NPG];
    __shared__ int cur[NPG];
    int g = blockIdx.x, tid = threadIdx.x;
    cnt[tid] = 0;
    __syncthreads();
    int base = g * EPG;
    for (int e = base + tid; e < base + EPG; e += 256)
        atomicAdd(&cnt[edst[e] & (NPG - 1)], 1);
    __syncthreads();
    int v = cnt[tid];
    pref[tid] = v;
    __syncthreads();
    for (int off = 1; off < NPG; off <<= 1) {
        int t = (tid >= off) ? pref[tid - off] : 0;
        __syncthreads();
        pref[tid] += t;
        __syncthreads();
    }
    int excl = pref[tid] - v;
    rowptr[g * NPG + tid] = base + excl;
    cur[tid] = base + excl;
    if (g == 0 && tid == 0) rowptr[NN] = NG * EPG;
    __syncthreads();
    for (int e = base + tid; e < base + EPG; e += 256) {
        int d = edst[e] & (NPG - 1);
        int p = atomicAdd(&cur[d], 1);
        csr[p] = esrc[e];
    }
}

// XCD-locality swizzle: all blocks of one graph land on one XCD's L2
__device__ __forceinline__ int swz_block(int bid, int bpg) {
    int xcd = bid & 7, r = bid >> 3;
    int graph = xcd * (NG / 8) + r / bpg;
    int sub = r - (r / bpg) * bpg;
    return graph * bpg + sub;
}

// ---------------- fused sort + stage-1 aggregation: wave per node ----------------
// sorts node's csr segment (canonical ascending by src), computes stage-1 edge weights
// in regs/LDS (never touching global wedge), aggregates x -> xa in sorted order.
__global__ __launch_bounds__(256) void k_sortagg(const float* __restrict__ x,
                                                 const int* __restrict__ rowptr,
                                                 int* __restrict__ csr,
                                                 float* __restrict__ xa) {
    __shared__ int skey[4][64];
    __shared__ float swgt[4][64];
    int blk = swz_block(blockIdx.x, NPG / 4);
    int w = threadIdx.x >> 6, lane = threadIdx.x & 63;
    int n = blk * 4 + w;
    int e0 = rowptr[n];
    int d = rowptr[n + 1] - e0;
    float ddst = rsqrtf((float)(1 + d));
    bool big = d > 64;
    if (!big) {
        int key = (lane < d) ? csr[e0 + lane] : 0x7fffffff;
        int rank = 0;
        for (int j = 0; j < d; j++) {
            int kj = __shfl(key, j);
            rank += (kj < key || (kj == key && j < lane)) ? 1 : 0;
        }
        if (lane < d) {
            csr[e0 + rank] = key;
            skey[w][rank] = key;
            swgt[w][rank] = rsqrtf((float)(1 + rowptr[key + 1] - rowptr[key])) * ddst;
        }
    } else if (lane == 0) {
        for (int a = e0 + 1; a < e0 + d; a++) {
            int key = csr[a];
            int b = a - 1;
            while (b >= e0 && csr[b] > key) { csr[b + 1] = csr[b]; b--; }
            csr[b + 1] = key;
        }
    }
    __syncthreads();
    const float2* x2 = reinterpret_cast<const float2*>(x);
    float di = ddst;
    float2 h = x2[(size_t)n * (FIN / 2) + lane];
    float self = di * di;
    float ax = h.x * self, ay = h.y * self;
    if (!big) {
        for (int j = 0; j < d; j++) {
            int s = skey[w][j];
            float we = swgt[w][j];
            float2 hs = x2[(size_t)s * (FIN / 2) + lane];
            ax += hs.x * we; ay += hs.y * we;
        }
    } else {
        for (int e = e0; e < e0 + d; e++) {
            int s = csr[e];
            float we = rsqrtf((float)(1 + rowptr[s + 1] - rowptr[s])) * ddst;
            float2 hs = x2[(size_t)s * (FIN / 2) + lane];
            ax += hs.x * we; ay += hs.y * we;
        }
    }
    float2 o; o.x = ax; o.y = ay;
    reinterpret_cast<float2*>(xa)[(size_t)n * (FIN / 2) + lane] = o;
}

// ---------------- SGEMM: C[list[m] x 256] = A[list[m] x K] @ B[K x 256], f32 ----------------
// BM=64 x BN=64, 4x4 micro-tile, As padded to 68, register double-buffered staging.
// optional epilogues: bias+relu; per-col-block score dots (wrel/wroot -> rrel4/rroot4)
#define BM 64
#define BN 64
#define BK 16
#define BMP 68
__global__ __launch_bounds__(256) void k_sgemm(const float* __restrict__ A,
                                               const float* __restrict__ B,
                                               float* __restrict__ C, int K,
                                               const int* __restrict__ list,
                                               const float* __restrict__ brelu,
                                               const float* __restrict__ wrel,
                                               const float* __restrict__ wroot,
                                               float* __restrict__ rrel4,
                                               float* __restrict__ rroot4) {
    const int N = HDIM;
    __shared__ float As[BK][BMP];
    __shared__ float Bs[BK][BN];
    int tid = threadIdx.x;
    int tx = tid & 15, ty = tid >> 4;
    int row0 = blockIdx.y * BM, col0 = blockIdx.x * BN;
    int lm = tid >> 2;
    int arow = list ? list[row0 + lm] : (row0 + lm);
    int crow[4];
#pragma unroll
    for (int i = 0; i < 4; i++) {
        int r = row0 + ty * 4 + i;
        crow[i] = list ? list[r] : r;
    }
    int k4 = (tid & 3) * 4;
    int kkB = tid >> 4, cB = (tid & 15) * 4;
    float4 aP = *reinterpret_cast<const float4*>(&A[(size_t)arow * K + k4]);
    float4 bP = *reinterpret_cast<const float4*>(&B[(size_t)kkB * N + col0 + cB]);
    float acc[4][4] = {};
    for (int kb = 0; kb < K; kb += BK) {
        As[k4 + 0][lm] = aP.x; As[k4 + 1][lm] = aP.y;
        As[k4 + 2][lm] = aP.z; As[k4 + 3][lm] = aP.w;
        *reinterpret_cast<float4*>(&Bs[kkB][cB]) = bP;
        __syncthreads();
        if (kb + BK < K) {
            aP = *reinterpret_cast<const float4*>(&A[(size_t)arow * K + kb + BK + k4]);
            bP = *reinterpret_cast<const float4*>(&B[(size_t)(kb + BK + kkB) * N + col0 + cB]);
        }
#pragma unroll
        for (int k = 0; k < BK; k++) {
            float4 a = *reinterpret_cast<float4*>(&As[k][ty * 4]);
            float4 b = *reinterpret_cast<float4*>(&Bs[k][tx * 4]);
            float av[4] = {a.x, a.y, a.z, a.w};
            float bv[4] = {b.x, b.y, b.z, b.w};
#pragma unroll
            for (int i = 0; i < 4; i++)
#pragma unroll
                for (int j = 0; j < 4; j++) acc[i][j] += av[i] * bv[j];
        }
        __syncthreads();
    }
    float4 bb = make_float4(0.f, 0.f, 0.f, 0.f);
    if (brelu) bb = *reinterpret_cast<const float4*>(&brelu[col0 + tx * 4]);
    float4 wr = make_float4(0.f, 0.f, 0.f, 0.f), wo = wr;
    if (wrel) {
        wr = *reinterpret_cast<const float4*>(&wrel[col0 + tx * 4]);
        wo = *reinterpret_cast<const float4*>(&wroot[col0 + tx * 4]);
    }
#pragma unroll
    for (int i = 0; i < 4; i++) {
        float4 v = make_float4(acc[i][0], acc[i][1], acc[i][2], acc[i][3]);
        if (brelu) {
            v.x = fmaxf(v.x + bb.x, 0.f);
            v.y = fmaxf(v.y + bb.y, 0.f);
            v.z = fmaxf(v.z + bb.z, 0.f);
            v.w = fmaxf(v.w + bb.w, 0.f);
        }
        *reinterpret_cast<float4*>(&C[(size_t)crow[i] * N + col0 + tx * 4]) = v;
        if (wrel) {
            float s1 = v.x * wr.x + v.y * wr.y + v.z * wr.z + v.w * wr.w;
            float s2 = v.x * wo.x + v.y * wo.y + v.z * wo.z + v.w * wo.w;
            for (int off = 8; off > 0; off >>= 1) {
                s1 += __shfl_down(s1, off, 16);
                s2 += __shfl_down(s2, off, 16);
            }
            if (tx == 0) {
                rrel4[(size_t)crow[i] * 4 + blockIdx.x] = s1;
                rroot4[(size_t)crow[i] * 4 + blockIdx.x] = s2;
            }
        }
    }
}

// stages 2/3: wave per ACTIVE node, gather on hW, fused bias+relu+score dots
__global__ __launch_bounds__(256) void k_gcn_agg(const float* __restrict__ hW,
                                                 const float* __restrict__ dis,
                                                 const int* __restrict__ rowptr,
                                                 const int* __restrict__ csr,
                                                 const float* __restrict__ wedge,
                                                 const float* __restrict__ bias,
                                                 const int* __restrict__ list, int bpg,
                                                 const float* __restrict__ w_rel,
                                                 const float* __restrict__ w_root,
                                                 float* __restrict__ out,
                                                 float* __restrict__ r_rel,
                                                 float* __restrict__ r_root) {
    int blk = swz_block(blockIdx.x, bpg);
    int idx = blk * 4 + (threadIdx.x >> 6);
    int lane = threadIdx.x & 63;
    int wid = list[idx];
    float di = dis[wid];
    float4 h = *reinterpret_cast<const float4*>(&hW[(size_t)wid * HDIM + lane * 4]);
    float self = di * di;
    float ax = h.x * self, ay = h.y * self, az = h.z * self, aw = h.w * self;
    int e0 = rowptr[wid], e1 = rowptr[wid + 1];
    for (int e = e0; e < e1; e++) {
        float w = wedge[e];
        if (w > 0.f) {
            int s = csr[e];
            float4 hs = *reinterpret_cast<const float4*>(&hW[(size_t)s * HDIM + lane * 4]);
            ax += hs.x * w; ay += hs.y * w; az += hs.z * w; aw += hs.w * w;
        }
    }
    float4 b = *reinterpret_cast<const float4*>(&bias[lane * 4]);
    float4 o;
    o.x = fmaxf(ax + b.x, 0.f);
    o.y = fmaxf(ay + b.y, 0.f);
    o.z = fmaxf(az + b.z, 0.f);
    o.w = fmaxf(aw + b.w, 0.f);
    *reinterpret_cast<float4*>(&out[(size_t)wid * HDIM + lane * 4]) = o;
    float4 wr = *reinterpret_cast<const float4*>(&w_rel[lane * 4]);
    float4 wo = *reinterpret_cast<const float4*>(&w_root[lane * 4]);
    float s1 = o.x * wr.x + o.y * wr.y + o.z * wr.z + o.w * wr.w;
    float s2 = o.x * wo.x + o.y * wo.y + o.z * wo.z + o.w * wo.w;
    for (int off = 32; off > 0; off >>= 1) {
        s1 += __shfl_down(s1, off);
        s2 += __shfl_down(s2, off);
    }
    if (lane == 0) { r_rel[wid] = s1; r_root[wid] = s2; }
}

// ---------------- fused score + stable top-k + pool/readout, grid = NG*4 ----------------
// 4 blocks per graph redundantly compute top-k (LDS); global side-products (list,
// disN, wedgeN) written by block fc==0 only. dis double-buffered by caller (no race).
template<bool STAGE1, bool EMIT, bool FIRST>
__global__ __launch_bounds__(256) void k_topkpool(const float* __restrict__ dis,
                                                  const int* __restrict__ rowptr,
                                                  const int* __restrict__ csr,
                                                  const float* __restrict__ r_rel,
                                                  const float* __restrict__ r_root,
                                                  const float* __restrict__ rrel4,
                                                  const float* __restrict__ rroot4,
                                                  const float* __restrict__ b_rel, int k,
                                                  int* __restrict__ list,
                                                  float* __restrict__ h,
                                                  float* __restrict__ z, float invk,
                                                  float* __restrict__ disN,
                                                  float* __restrict__ wedgeN) {
    __shared__ float rrel[NPG];
    __shared__ float sc[NPG];
    __shared__ int pref[NPG];
    __shared__ int sels[NPG];
    __shared__ float disn[NPG];
    __shared__ int newl[128];
    __shared__ float tvsel[128];
    __shared__ float red_s[4][64];
    __shared__ float red_m[4][64];
    int g = blockIdx.x >> 2, fc = blockIdx.x & 3;
    int tid = threadIdx.x;
    int n = g * NPG + tid;
    bool act = STAGE1 ? true : (dis[n] > 0.f);
    float rr, ro;
    if (STAGE1) {
        rr = ((rrel4[(size_t)n * 4 + 0] + rrel4[(size_t)n * 4 + 1]) +
              rrel4[(size_t)n * 4 + 2]) + rrel4[(size_t)n * 4 + 3];
        ro = ((rroot4[(size_t)n * 4 + 0] + rroot4[(size_t)n * 4 + 1]) +
              rroot4[(size_t)n * 4 + 2]) + rroot4[(size_t)n * 4 + 3];
    } else {
        rr = act ? r_rel[n] : 0.f;
        ro = act ? r_root[n] : 0.f;
    }
    rrel[tid] = act ? rr : 0.f;
    __syncthreads();
    int e0 = rowptr[n], e1 = rowptr[n + 1];
    float my;
    if (act) {
        float s = b_rel[0] + ro;
        for (int e = e0; e < e1; e++) s += rrel[csr[e] & (NPG - 1)];
        my = s;
    } else {
        my = -INFINITY;
    }
    sc[tid] = my;
    __syncthreads();
    int cnt = 0;
    for (int j = 0; j < NPG; j++) {
        float v = sc[j];
        cnt += (v > my || (v == my && j < tid)) ? 1 : 0;
    }
    int a = (cnt < k) ? 1 : 0;
    sels[tid] = a;
    pref[tid] = a;
    __syncthreads();
    for (int off = 1; off < NPG; off <<= 1) {
        int v = (tid >= off) ? pref[tid - off] : 0;
        __syncthreads();
        pref[tid] += v;
        __syncthreads();
    }
    if (a) {
        int rk = pref[tid] - 1;
        newl[rk] = tid;
        tvsel[rk] = tanhf(my);
        if (fc == 0 && list) list[g * k + rk] = n;
    }
    if (EMIT) {
        int c2 = 1;
        for (int e = e0; e < e1; e++) c2 += sels[csr[e] & (NPG - 1)];
        float dn = a ? rsqrtf((float)c2) : 0.f;
        disn[tid] = dn;
        if (fc == 0) disN[n] = dn;
        __syncthreads();
        if (a && fc == 0) {
            for (int e = e0; e < e1; e++) wedgeN[e] = disn[csr[e] & (NPG - 1)] * dn;
        }
    }
    __syncthreads();
    // pool + readout for this block's 64-feature chunk
    int xq = tid & 63, y = tid >> 6;
    int f = fc * 64 + xq;
    float s = 0.f, mx = -INFINITY;
    for (int idx = y; idx < k; idx += 4) {
        int node = g * NPG + newl[idx];
        size_t p = (size_t)node * HDIM + f;
        float v = h[p] * tvsel[idx];
        h[p] = v;
        s += v;
        mx = fmaxf(mx, v);
    }
    red_s[y][xq] = s;
    red_m[y][xq] = mx;
    __syncthreads();
    if (y == 0) {
        s = red_s[0][xq] + red_s[1][xq] + red_s[2][xq] + red_s[3][xq];
        mx = fmaxf(fmaxf(red_m[0][xq], red_m[1][xq]), fmaxf(red_m[2][xq], red_m[3][xq]));
        if (FIRST) {
            z[g * 768 + f] = s * invk;
            z[g * 768 + 256 + f] = mx;
            z[g * 768 + 512 + f] = s;
        } else {
            z[g * 768 + f] += s * invk;
            z[g * 768 + 256 + f] += mx;
            z[g * 768 + 512 + f] += s;
        }
    }
}

// ---------------- fused MLP: fc1+fc2+fc3+log_softmax, block per graph ----------------
// partial-sum groupings identical to the previous split kernels (bitwise same).
__global__ __launch_bounds__(256) void k_mlp(const float* __restrict__ z,
                                             const float* __restrict__ W1, const float* __restrict__ b1,
                                             const float* __restrict__ W2, const float* __restrict__ b2,
                                             const float* __restrict__ W3, const float* __restrict__ b3,
                                             float* __restrict__ out) {
    __shared__ float zb[768];
    __shared__ float t1[256];
    __shared__ float t2[128];
    __shared__ float t3[10];
    __shared__ float lse;
    int g = blockIdx.x, tid = threadIdx.x;
    zb[tid] = z[g * 768 + tid];
    zb[tid + 256] = z[g * 768 + 256 + tid];
    zb[tid + 512] = z[g * 768 + 512 + tid];
    __syncthreads();
    {
        int col = tid;
        float r0 = 0.f, r1 = 0.f, r2 = 0.f, r3 = 0.f;
        for (int i = 0;   i < 192; i++) r0 += zb[i] * W1[(size_t)i * 256 + col];
        for (int i = 192; i < 384; i++) r1 += zb[i] * W1[(size_t)i * 256 + col];
        for (int i = 384; i < 576; i++) r2 += zb[i] * W1[(size_t)i * 256 + col];
        for (int i = 576; i < 768; i++) r3 += zb[i] * W1[(size_t)i * 256 + col];
        t1[col] = fmaxf(r0 + r1 + r2 + r3 + b1[col], 0.f);
    }
    __syncthreads();
    if (tid < 128) {
        int col = tid;
        float r0 = 0.f, r1 = 0.f, r2 = 0.f, r3 = 0.f;
        for (int i = 0;   i < 64;  i++) r0 += t1[i] * W2[(size_t)i * 128 + col];
        for (int i = 64;  i < 128; i++) r1 += t1[i] * W2[(size_t)i * 128 + col];
        for (int i = 128; i < 192; i++) r2 += t1[i] * W2[(size_t)i * 128 + col];
        for (int i = 192; i < 256; i++) r3 += t1[i] * W2[(size_t)i * 128 + col];
        t2[col] = fmaxf(((r0 + r1) + r2) + r3 + b2[col], 0.f);
    }
    __syncthreads();
    if (tid < 10) {
        float v = b3[tid];
        for (int i = 0; i < 128; i++) v += t2[i] * W3[(size_t)i * 10 + tid];
        t3[tid] = v;
    }
    __syncthreads();
    if (tid == 0) {
        float m = t3[0];
        for (int c = 1; c < 10; c++) m = fmaxf(m, t3[c]);
        float se = 0.f;
        for (int c = 0; c < 10; c++) se += expf(t3[c] - m);
        lse = m + logf(se);
    }
    __syncthreads();
    if (tid < 10) out[g * 10 + tid] = t3[tid] - lse;
}

// ---------------- launcher ----------------
extern "C" void kernel_launch(void* const* d_in, const int* in_sizes, int n_in,
                              void* d_out, int out_size, void* d_ws, size_t ws_size,
                              hipStream_t stream) {
    const float* x        = (const float*)d_in[0];
    const int*   ei       = (const int*)d_in[1];
    const float* conv1_W  = (const float*)d_in[3];
    const float* conv1_b  = (const float*)d_in[4];
    const float* conv2_W  = (const float*)d_in[5];
    const float* conv2_b  = (const float*)d_in[6];
    const float* conv3_W  = (const float*)d_in[7];
    const float* conv3_b  = (const float*)d_in[8];
    const float* p1_relW  = (const float*)d_in[9];
    const float* p1_relb  = (const float*)d_in[10];
    const float* p1_rootW = (const float*)d_in[11];
    const float* p2_relW  = (const float*)d_in[12];
    const float* p2_relb  = (const float*)d_in[13];
    const float* p2_rootW = (const float*)d_in[14];
    const float* fc1_W    = (const float*)d_in[15];
    const float* fc1_b    = (const float*)d_in[16];
    const float* fc2_W    = (const float*)d_in[17];
    const float* fc2_b    = (const float*)d_in[18];
    const float* fc3_W    = (const float*)d_in[19];
    const float* fc3_b    = (const float*)d_in[20];
    float* out = (float*)d_out;

    const int E = in_sizes[1] / 2;
    const int EPG = E / NG;
    const int* e_src = ei;
    const int* e_dst = ei + E;

    // workspace layout
    char* base = (char*)d_ws;
    size_t off = 0;
    auto alloc = [&](size_t bytes) { size_t o = off; off = (off + bytes + 255) & ~(size_t)255; return o; };
    float* hW     = (float*)(base + alloc((size_t)NN * HDIM * 4));   // also xa (NN x FIN)
    float* hcur   = (float*)(base + alloc((size_t)NN * HDIM * 4));
    float* dis    = (float*)(base + alloc(NN * 4));   // stage-2 dis
    float* dis2   = (float*)(base + alloc(NN * 4));   // stage-3 dis (double-buffer: no cross-block race)
    float* r_rel  = (float*)(base + alloc(NN * 4));
    float* r_root = (float*)(base + alloc(NN * 4));
    float* rrel4  = (float*)(base + alloc((size_t)NN * 4 * 4));
    float* rroot4 = (float*)(base + alloc((size_t)NN * 4 * 4));
    int*   rowptr = (int*)(base + alloc((NN + 1) * 4));
    int*   csr    = (int*)(base + alloc((size_t)E * 4));
    float* wedge  = (float*)(base + alloc((size_t)E * 4));
    float* z      = (float*)(base + alloc((size_t)NG * 768 * 4));
    int*   list1  = (int*)(base + alloc((size_t)NG * 128 * 4));
    int*   list2  = (int*)(base + alloc((size_t)NG * 64 * 4));

    // CSR build + fused sort/stage-1 aggregation
    k_csr<<<NG, 256, 0, stream>>>(e_src, e_dst, EPG, rowptr, csr);
    float* xa = hW;
    k_sortagg<<<NN / 4, 256, 0, stream>>>(x, rowptr, csr, xa);

    // ---- stage 1 ----
    {
        dim3 ggrid(HDIM / BN, NN / BM);
        k_sgemm<<<ggrid, 256, 0, stream>>>(xa, conv1_W, hcur, FIN, nullptr, conv1_b,
                                           p1_relW, p1_rootW, rrel4, rroot4);
    }
    k_topkpool<true, true, true><<<NG * 4, 256, 0, stream>>>(
        nullptr, rowptr, csr, nullptr, nullptr, rrel4, rroot4, p1_relb, 128,
        list1, hcur, z, 1.0f / 128.0f, dis, wedge);

    // ---- stage 2 ----
    {
        dim3 ggrid(HDIM / BN, (NG * 128) / BM);
        k_sgemm<<<ggrid, 256, 0, stream>>>(hcur, conv2_W, hW, HDIM, list1, nullptr,
                                           nullptr, nullptr, nullptr, nullptr);
    }
    k_gcn_agg<<<(NG * 128) / 4, 256, 0, stream>>>(hW, dis, rowptr, csr, wedge, conv2_b,
                                                  list1, 32, p2_relW, p2_rootW,
                                                  hcur, r_rel, r_root);
    k_topkpool<false, true, false><<<NG * 4, 256, 0, stream>>>(
        dis, rowptr, csr, r_rel, r_root, nullptr, nullptr, p2_relb, 64,
        list2, hcur, z, 1.0f / 64.0f, dis2, wedge);

    // ---- stage 3 ----
    {
        dim3 ggrid(HDIM / BN, (NG * 64) / BM);
        k_sgemm<<<ggrid, 256, 0, stream>>>(hcur, conv3_W, hW, HDIM, list2, nullptr,
                                           nullptr, nullptr, nullptr, nullptr);
    }
    k_gcn_agg<<<(NG * 64) / 4, 256, 0, stream>>>(hW, dis2, rowptr, csr, wedge, conv3_b,
                                                 list2, 16, p2_relW, p2_rootW,
                                                 hcur, r_rel, r_root);
    k_topkpool<false, false, false><<<NG * 4, 256, 0, stream>>>(
        dis2, rowptr, csr, r_rel, r_root, nullptr, nullptr, p2_relb, 32,
        nullptr, hcur, z, 1.0f / 32.0f, nullptr, nullptr);

    // ---- MLP ----
    k_mlp<<<NG, 256, 0, stream>>>(z, fc1_W, fc1_b, fc2_W, fc2_b, fc3_W, fc3_b, out);
}

// Round 12
// 281.222 us; speedup vs baseline: 1.1292x; 1.0458x over previous
//
#include <hip/hip_runtime.h>
#include <math.h>

#define NG 128          // graphs
#define NPG 256         // nodes per graph
#define NN 32768        // total nodes
#define HDIM 256        // hidden
#define FIN 128         // in features

// ---------------- CSR build: block per graph, LDS counting sort ----------------
__global__ __launch_bounds__(256) void k_csr(const int* __restrict__ esrc,
                                             const int* __restrict__ edst, int EPG,
                                             int* __restrict__ rowptr, int* __restrict__ csr) {
    __shared__ int cnt[NPG];
    __shared__ int pref[NPG];
    __shared__ int cur[NPG];
    int g = blockIdx.x, tid = threadIdx.x;
    cnt[tid] = 0;
    __syncthreads();
    int base = g * EPG;
    for (int e = base + tid; e < base + EPG; e += 256)
        atomicAdd(&cnt[edst[e] & (NPG - 1)], 1);
    __syncthreads();
    int v = cnt[tid];
    pref[tid] = v;
    __syncthreads();
    for (int off = 1; off < NPG; off <<= 1) {
        int t = (tid >= off) ? pref[tid - off] : 0;
        __syncthreads();
        pref[tid] += t;
        __syncthreads();
    }
    int excl = pref[tid] - v;
    rowptr[g * NPG + tid] = base + excl;
    cur[tid] = base + excl;
    if (g == 0 && tid == 0) rowptr[NN] = NG * EPG;
    __syncthreads();
    for (int e = base + tid; e < base + EPG; e += 256) {
        int d = edst[e] & (NPG - 1);
        int p = atomicAdd(&cur[d], 1);
        csr[p] = esrc[e];
    }
}

// XCD-locality swizzle
__device__ __forceinline__ int swz_block(int bid, int bpg) {
    int xcd = bid & 7, r = bid >> 3;
    int graph = xcd * (NG / 8) + r / bpg;
    int sub = r - (r / bpg) * bpg;
    return graph * bpg + sub;
}

// ---------------- fused sort + stage-1 aggregation: wave per node ----------------
__global__ __launch_bounds__(256) void k_sortagg(const float* __restrict__ x,
                                                 const int* __restrict__ rowptr,
                                                 int* __restrict__ csr,
                                                 float* __restrict__ xa) {
    __shared__ int skey[4][64];
    __shared__ float swgt[4][64];
    int blk = swz_block(blockIdx.x, NPG / 4);
    int w = threadIdx.x >> 6, lane = threadIdx.x & 63;
    int n = blk * 4 + w;
    int e0 = rowptr[n];
    int d = rowptr[n + 1] - e0;
    float ddst = rsqrtf((float)(1 + d));
    bool big = d > 64;
    if (!big) {
        int key = (lane < d) ? csr[e0 + lane] : 0x7fffffff;
        int rank = 0;
        for (int j = 0; j < d; j++) {
            int kj = __shfl(key, j);
            rank += (kj < key || (kj == key && j < lane)) ? 1 : 0;
        }
        if (lane < d) {
            csr[e0 + rank] = key;
            skey[w][rank] = key;
            swgt[w][rank] = rsqrtf((float)(1 + rowptr[key + 1] - rowptr[key])) * ddst;
        }
    } else if (lane == 0) {
        for (int a = e0 + 1; a < e0 + d; a++) {
            int key = csr[a];
            int b = a - 1;
            while (b >= e0 && csr[b] > key) { csr[b + 1] = csr[b]; b--; }
            csr[b + 1] = key;
        }
    }
    __syncthreads();
    const float2* x2 = reinterpret_cast<const float2*>(x);
    float di = ddst;
    float2 h = x2[(size_t)n * (FIN / 2) + lane];
    float self = di * di;
    float ax = h.x * self, ay = h.y * self;
    if (!big) {
        for (int j = 0; j < d; j++) {
            int s = skey[w][j];
            float we = swgt[w][j];
            float2 hs = x2[(size_t)s * (FIN / 2) + lane];
            ax += hs.x * we; ay += hs.y * we;
        }
    } else {
        for (int e = e0; e < e0 + d; e++) {
            int s = csr[e];
            float we = rsqrtf((float)(1 + rowptr[s + 1] - rowptr[s])) * ddst;
            float2 hs = x2[(size_t)s * (FIN / 2) + lane];
            ax += hs.x * we; ay += hs.y * we;
        }
    }
    float2 o; o.x = ax; o.y = ay;
    reinterpret_cast<float2*>(xa)[(size_t)n * (FIN / 2) + lane] = o;
}

// ---------------- SGEMM (R10-proven: 64x64, 4x4, pad 68, reg dbuf) ----------------
#define BM 64
#define BN 64
#define BK 16
#define BMP 68
__global__ __launch_bounds__(256) void k_sgemm(const float* __restrict__ A,
                                               const float* __restrict__ B,
                                               float* __restrict__ C, int K,
                                               const int* __restrict__ list,
                                               const float* __restrict__ brelu,
                                               const float* __restrict__ wrel,
                                               const float* __restrict__ wroot,
                                               float* __restrict__ rrel4,
                                               float* __restrict__ rroot4) {
    const int N = HDIM;
    __shared__ float As[BK][BMP];
    __shared__ float Bs[BK][BN];
    int tid = threadIdx.x;
    int tx = tid & 15, ty = tid >> 4;
    int row0 = blockIdx.y * BM, col0 = blockIdx.x * BN;
    int lm = tid >> 2;
    int arow = list ? list[row0 + lm] : (row0 + lm);
    int crow[4];
#pragma unroll
    for (int i = 0; i < 4; i++) {
        int r = row0 + ty * 4 + i;
        crow[i] = list ? list[r] : r;
    }
    int k4 = (tid & 3) * 4;
    int kkB = tid >> 4, cB = (tid & 15) * 4;
    float4 aP = *reinterpret_cast<const float4*>(&A[(size_t)arow * K + k4]);
    float4 bP = *reinterpret_cast<const float4*>(&B[(size_t)kkB * N + col0 + cB]);
    float acc[4][4] = {};
    for (int kb = 0; kb < K; kb += BK) {
        As[k4 + 0][lm] = aP.x; As[k4 + 1][lm] = aP.y;
        As[k4 + 2][lm] = aP.z; As[k4 + 3][lm] = aP.w;
        *reinterpret_cast<float4*>(&Bs[kkB][cB]) = bP;
        __syncthreads();
        if (kb + BK < K) {
            aP = *reinterpret_cast<const float4*>(&A[(size_t)arow * K + kb + BK + k4]);
            bP = *reinterpret_cast<const float4*>(&B[(size_t)(kb + BK + kkB) * N + col0 + cB]);
        }
#pragma unroll
        for (int k = 0; k < BK; k++) {
            float4 a = *reinterpret_cast<float4*>(&As[k][ty * 4]);
            float4 b = *reinterpret_cast<float4*>(&Bs[k][tx * 4]);
            float av[4] = {a.x, a.y, a.z, a.w};
            float bv[4] = {b.x, b.y, b.z, b.w};
#pragma unroll
            for (int i = 0; i < 4; i++)
#pragma unroll
                for (int j = 0; j < 4; j++) acc[i][j] += av[i] * bv[j];
        }
        __syncthreads();
    }
    float4 bb = make_float4(0.f, 0.f, 0.f, 0.f);
    if (brelu) bb = *reinterpret_cast<const float4*>(&brelu[col0 + tx * 4]);
    float4 wr = make_float4(0.f, 0.f, 0.f, 0.f), wo = wr;
    if (wrel) {
        wr = *reinterpret_cast<const float4*>(&wrel[col0 + tx * 4]);
        wo = *reinterpret_cast<const float4*>(&wroot[col0 + tx * 4]);
    }
#pragma unroll
    for (int i = 0; i < 4; i++) {
        float4 v = make_float4(acc[i][0], acc[i][1], acc[i][2], acc[i][3]);
        if (brelu) {
            v.x = fmaxf(v.x + bb.x, 0.f);
            v.y = fmaxf(v.y + bb.y, 0.f);
            v.z = fmaxf(v.z + bb.z, 0.f);
            v.w = fmaxf(v.w + bb.w, 0.f);
        }
        *reinterpret_cast<float4*>(&C[(size_t)crow[i] * N + col0 + tx * 4]) = v;
        if (wrel) {
            float s1 = v.x * wr.x + v.y * wr.y + v.z * wr.z + v.w * wr.w;
            float s2 = v.x * wo.x + v.y * wo.y + v.z * wo.z + v.w * wo.w;
            for (int off = 8; off > 0; off >>= 1) {
                s1 += __shfl_down(s1, off, 16);
                s2 += __shfl_down(s2, off, 16);
            }
            if (tx == 0) {
                rrel4[(size_t)crow[i] * 4 + blockIdx.x] = s1;
                rroot4[(size_t)crow[i] * 4 + blockIdx.x] = s2;
            }
        }
    }
}

// stages 2/3: wave per ACTIVE node, branch-free gather over COMPACT edge rows
__global__ __launch_bounds__(256) void k_gcn_agg(const float* __restrict__ hW,
                                                 const float* __restrict__ dis,
                                                 const int* __restrict__ rs,
                                                 const int* __restrict__ re,
                                                 const int* __restrict__ ccsr,
                                                 const float* __restrict__ cwedge,
                                                 const float* __restrict__ bias,
                                                 const int* __restrict__ list, int bpg,
                                                 const float* __restrict__ w_rel,
                                                 const float* __restrict__ w_root,
                                                 float* __restrict__ out,
                                                 float* __restrict__ r_rel,
                                                 float* __restrict__ r_root) {
    int blk = swz_block(blockIdx.x, bpg);
    int idx = blk * 4 + (threadIdx.x >> 6);
    int lane = threadIdx.x & 63;
    int wid = list[idx];
    float di = dis[wid];
    float4 h = *reinterpret_cast<const float4*>(&hW[(size_t)wid * HDIM + lane * 4]);
    float self = di * di;
    float ax = h.x * self, ay = h.y * self, az = h.z * self, aw = h.w * self;
    int e0 = rs[wid], e1 = re[wid];
    for (int e = e0; e < e1; e++) {
        float w = cwedge[e];
        int s = ccsr[e];
        float4 hs = *reinterpret_cast<const float4*>(&hW[(size_t)s * HDIM + lane * 4]);
        ax += hs.x * w; ay += hs.y * w; az += hs.z * w; aw += hs.w * w;
    }
    float4 b = *reinterpret_cast<const float4*>(&bias[lane * 4]);
    float4 o;
    o.x = fmaxf(ax + b.x, 0.f);
    o.y = fmaxf(ay + b.y, 0.f);
    o.z = fmaxf(az + b.z, 0.f);
    o.w = fmaxf(aw + b.w, 0.f);
    *reinterpret_cast<float4*>(&out[(size_t)wid * HDIM + lane * 4]) = o;
    float4 wr = *reinterpret_cast<const float4*>(&w_rel[lane * 4]);
    float4 wo = *reinterpret_cast<const float4*>(&w_root[lane * 4]);
    float s1 = o.x * wr.x + o.y * wr.y + o.z * wr.z + o.w * wr.w;
    float s2 = o.x * wo.x + o.y * wo.y + o.z * wo.z + o.w * wo.w;
    for (int off = 32; off > 0; off >>= 1) {
        s1 += __shfl_down(s1, off);
        s2 += __shfl_down(s2, off);
    }
    if (lane == 0) { r_rel[wid] = s1; r_root[wid] = s2; }
}

// ---------------- fused score + top-k + pool/readout (+compact-CSR emit) ----------------
// grid = NG*4; 4 blocks per graph redundantly compute top-k in LDS; global side
// products (list, disN, compact CSR) written by block fc==0 only.
// Score gather over rows [rs[n],re[n]) of csr_in: for stages 2/3 these are the
// previous stage's COMPACT rows (identical sums bit-exact: dropped terms were +0).
template<bool STAGE1, bool EMIT, bool FIRST>
__global__ __launch_bounds__(256) void k_topkpool(const float* __restrict__ dis,
                                                  const int* __restrict__ rs,
                                                  const int* __restrict__ re,
                                                  const int* __restrict__ csr_in,
                                                  const float* __restrict__ r_rel,
                                                  const float* __restrict__ r_root,
                                                  const float* __restrict__ rrel4,
                                                  const float* __restrict__ rroot4,
                                                  const float* __restrict__ b_rel, int k,
                                                  int* __restrict__ list,
                                                  float* __restrict__ h,
                                                  float* __restrict__ z, float invk,
                                                  float* __restrict__ disN,
                                                  int* __restrict__ csN,
                                                  int* __restrict__ ceN,
                                                  int* __restrict__ ccsrN,
                                                  float* __restrict__ cwedgeN,
                                                  int EPG) {
    __shared__ float rrel[NPG];
    __shared__ float sc[NPG];
    __shared__ int pref[NPG];
    __shared__ int sels[NPG];
    __shared__ float disn[NPG];
    __shared__ int newl[128];
    __shared__ float tvsel[128];
    __shared__ float red_s[4][64];
    __shared__ float red_m[4][64];
    int g = blockIdx.x >> 2, fc = blockIdx.x & 3;
    int tid = threadIdx.x;
    int n = g * NPG + tid;
    bool act = STAGE1 ? true : (dis[n] > 0.f);
    float rr, ro;
    if (STAGE1) {
        rr = ((rrel4[(size_t)n * 4 + 0] + rrel4[(size_t)n * 4 + 1]) +
              rrel4[(size_t)n * 4 + 2]) + rrel4[(size_t)n * 4 + 3];
        ro = ((rroot4[(size_t)n * 4 + 0] + rroot4[(size_t)n * 4 + 1]) +
              rroot4[(size_t)n * 4 + 2]) + rroot4[(size_t)n * 4 + 3];
    } else {
        rr = act ? r_rel[n] : 0.f;
        ro = act ? r_root[n] : 0.f;
    }
    rrel[tid] = act ? rr : 0.f;
    __syncthreads();
    int e0 = rs[n], e1 = re[n];
    float my;
    if (act) {
        float s = b_rel[0] + ro;
        for (int e = e0; e < e1; e++) s += rrel[csr_in[e] & (NPG - 1)];
        my = s;
    } else {
        my = -INFINITY;
    }
    sc[tid] = my;
    __syncthreads();
    int cnt = 0;
    for (int j = 0; j < NPG; j++) {
        float v = sc[j];
        cnt += (v > my || (v == my && j < tid)) ? 1 : 0;
    }
    int a = (cnt < k) ? 1 : 0;
    sels[tid] = a;
    pref[tid] = a;
    __syncthreads();
    for (int off = 1; off < NPG; off <<= 1) {
        int v = (tid >= off) ? pref[tid - off] : 0;
        __syncthreads();
        pref[tid] += v;
        __syncthreads();
    }
    if (a) {
        int rk = pref[tid] - 1;
        newl[rk] = tid;
        tvsel[rk] = tanhf(my);
        if (fc == 0 && list) list[g * k + rk] = n;
    }
    if (EMIT) {
        // compact degree = #selected in-neighbors (only meaningful for selected n)
        int deg2 = 0;
        if (a) {
            for (int e = e0; e < e1; e++) deg2 += sels[csr_in[e] & (NPG - 1)];
        }
        float dn = a ? rsqrtf((float)(1 + deg2)) : 0.f;
        disn[tid] = dn;
        __syncthreads();
        pref[tid] = deg2;
        __syncthreads();
        for (int off = 1; off < NPG; off <<= 1) {
            int v = (tid >= off) ? pref[tid - off] : 0;
            __syncthreads();
            pref[tid] += v;
            __syncthreads();
        }
        if (fc == 0) {
            disN[n] = dn;
            int start = g * EPG + pref[tid] - deg2;
            csN[n] = start;
            ceN[n] = start + deg2;
            if (a) {
                int p = start;
                for (int e = e0; e < e1; e++) {
                    int srcg = csr_in[e];
                    int j = srcg & (NPG - 1);
                    if (sels[j]) {
                        ccsrN[p] = srcg;
                        cwedgeN[p] = disn[j] * dn;
                        p++;
                    }
                }
            }
        }
    }
    __syncthreads();
    // pool + readout for this block's 64-feature chunk
    int xq = tid & 63, y = tid >> 6;
    int f = fc * 64 + xq;
    float s = 0.f, mx = -INFINITY;
    for (int idx = y; idx < k; idx += 4) {
        int node = g * NPG + newl[idx];
        size_t p = (size_t)node * HDIM + f;
        float v = h[p] * tvsel[idx];
        h[p] = v;
        s += v;
        mx = fmaxf(mx, v);
    }
    red_s[y][xq] = s;
    red_m[y][xq] = mx;
    __syncthreads();
    if (y == 0) {
        s = red_s[0][xq] + red_s[1][xq] + red_s[2][xq] + red_s[3][xq];
        mx = fmaxf(fmaxf(red_m[0][xq], red_m[1][xq]), fmaxf(red_m[2][xq], red_m[3][xq]));
        if (FIRST) {
            z[g * 768 + f] = s * invk;
            z[g * 768 + 256 + f] = mx;
            z[g * 768 + 512 + f] = s;
        } else {
            z[g * 768 + f] += s * invk;
            z[g * 768 + 256 + f] += mx;
            z[g * 768 + 512 + f] += s;
        }
    }
}

// ---------------- fused MLP (partial-sum groupings fixed) ----------------
__global__ __launch_bounds__(256) void k_mlp(const float* __restrict__ z,
                                             const float* __restrict__ W1, const float* __restrict__ b1,
                                             const float* __restrict__ W2, const float* __restrict__ b2,
                                             const float* __restrict__ W3, const float* __restrict__ b3,
                                             float* __restrict__ out) {
    __shared__ float zb[768];
    __shared__ float t1[256];
    __shared__ float t2[128];
    __shared__ float t3[10];
    __shared__ float lse;
    int g = blockIdx.x, tid = threadIdx.x;
    zb[tid] = z[g * 768 + tid];
    zb[tid + 256] = z[g * 768 + 256 + tid];
    zb[tid + 512] = z[g * 768 + 512 + tid];
    __syncthreads();
    {
        int col = tid;
        float r0 = 0.f, r1 = 0.f, r2 = 0.f, r3 = 0.f;
        for (int i = 0;   i < 192; i++) r0 += zb[i] * W1[(size_t)i * 256 + col];
        for (int i = 192; i < 384; i++) r1 += zb[i] * W1[(size_t)i * 256 + col];
        for (int i = 384; i < 576; i++) r2 += zb[i] * W1[(size_t)i * 256 + col];
        for (int i = 576; i < 768; i++) r3 += zb[i] * W1[(size_t)i * 256 + col];
        t1[col] = fmaxf(r0 + r1 + r2 + r3 + b1[col], 0.f);
    }
    __syncthreads();
    if (tid < 128) {
        int col = tid;
        float r0 = 0.f, r1 = 0.f, r2 = 0.f, r3 = 0.f;
        for (int i = 0;   i < 64;  i++) r0 += t1[i] * W2[(size_t)i * 128 + col];
        for (int i = 64;  i < 128; i++) r1 += t1[i] * W2[(size_t)i * 128 + col];
        for (int i = 128; i < 192; i++) r2 += t1[i] * W2[(size_t)i * 128 + col];
        for (int i = 192; i < 256; i++) r3 += t1[i] * W2[(size_t)i * 128 + col];
        t2[col] = fmaxf(((r0 + r1) + r2) + r3 + b2[col], 0.f);
    }
    __syncthreads();
    if (tid < 10) {
        float v = b3[tid];
        for (int i = 0; i < 128; i++) v += t2[i] * W3[(size_t)i * 10 + tid];
        t3[tid] = v;
    }
    __syncthreads();
    if (tid == 0) {
        float m = t3[0];
        for (int c = 1; c < 10; c++) m = fmaxf(m, t3[c]);
        float se = 0.f;
        for (int c = 0; c < 10; c++) se += expf(t3[c] - m);
        lse = m + logf(se);
    }
    __syncthreads();
    if (tid < 10) out[g * 10 + tid] = t3[tid] - lse;
}

// ---------------- launcher ----------------
extern "C" void kernel_launch(void* const* d_in, const int* in_sizes, int n_in,
                              void* d_out, int out_size, void* d_ws, size_t ws_size,
                              hipStream_t stream) {
    const float* x        = (const float*)d_in[0];
    const int*   ei       = (const int*)d_in[1];
    const float* conv1_W  = (const float*)d_in[3];
    const float* conv1_b  = (const float*)d_in[4];
    const float* conv2_W  = (const float*)d_in[5];
    const float* conv2_b  = (const float*)d_in[6];
    const float* conv3_W  = (const float*)d_in[7];
    const float* conv3_b  = (const float*)d_in[8];
    const float* p1_relW  = (const float*)d_in[9];
    const float* p1_relb  = (const float*)d_in[10];
    const float* p1_rootW = (const float*)d_in[11];
    const float* p2_relW  = (const float*)d_in[12];
    const float* p2_relb  = (const float*)d_in[13];
    const float* p2_rootW = (const float*)d_in[14];
    const float* fc1_W    = (const float*)d_in[15];
    const float* fc1_b    = (const float*)d_in[16];
    const float* fc2_W    = (const float*)d_in[17];
    const float* fc2_b    = (const float*)d_in[18];
    const float* fc3_W    = (const float*)d_in[19];
    const float* fc3_b    = (const float*)d_in[20];
    float* out = (float*)d_out;

    const int E = in_sizes[1] / 2;
    const int EPG = E / NG;
    const int* e_src = ei;
    const int* e_dst = ei + E;

    // workspace layout
    char* base = (char*)d_ws;
    size_t off = 0;
    auto alloc = [&](size_t bytes) { size_t o = off; off = (off + bytes + 255) & ~(size_t)255; return o; };
    float* hW     = (float*)(base + alloc((size_t)NN * HDIM * 4));   // also xa (NN x FIN)
    float* hcur   = (float*)(base + alloc((size_t)NN * HDIM * 4));
    float* dis    = (float*)(base + alloc(NN * 4));   // stage-2 dis
    float* dis2   = (float*)(base + alloc(NN * 4));   // stage-3 dis
    float* r_rel  = (float*)(base + alloc(NN * 4));
    float* r_root = (float*)(base + alloc(NN * 4));
    float* rrel4  = (float*)(base + alloc((size_t)NN * 4 * 4));
    float* rroot4 = (float*)(base + alloc((size_t)NN * 4 * 4));
    int*   rowptr = (int*)(base + alloc((NN + 1) * 4));
    int*   csr    = (int*)(base + alloc((size_t)E * 4));
    // stage-1 compact (consumed by stage 2)
    int*   cs1    = (int*)(base + alloc(NN * 4));
    int*   ce1    = (int*)(base + alloc(NN * 4));
    int*   ccsr1  = (int*)(base + alloc((size_t)E * 4));
    float* cwdg1  = (float*)(base + alloc((size_t)E * 4));
    // stage-2 compact (consumed by stage 3)
    int*   cs2    = (int*)(base + alloc(NN * 4));
    int*   ce2    = (int*)(base + alloc(NN * 4));
    int*   ccsr2  = (int*)(base + alloc((size_t)E * 4));
    float* cwdg2  = (float*)(base + alloc((size_t)E * 4));
    float* z      = (float*)(base + alloc((size_t)NG * 768 * 4));
    int*   list1  = (int*)(base + alloc((size_t)NG * 128 * 4));
    int*   list2  = (int*)(base + alloc((size_t)NG * 64 * 4));

    // CSR build + fused sort/stage-1 aggregation
    k_csr<<<NG, 256, 0, stream>>>(e_src, e_dst, EPG, rowptr, csr);
    float* xa = hW;
    k_sortagg<<<NN / 4, 256, 0, stream>>>(x, rowptr, csr, xa);

    // ---- stage 1 ----
    {
        dim3 ggrid(HDIM / BN, NN / BM);
        k_sgemm<<<ggrid, 256, 0, stream>>>(xa, conv1_W, hcur, FIN, nullptr, conv1_b,
                                           p1_relW, p1_rootW, rrel4, rroot4);
    }
    k_topkpool<true, true, true><<<NG * 4, 256, 0, stream>>>(
        nullptr, rowptr, rowptr + 1, csr, nullptr, nullptr, rrel4, rroot4, p1_relb, 128,
        list1, hcur, z, 1.0f / 128.0f, dis, cs1, ce1, ccsr1, cwdg1, EPG);

    // ---- stage 2 ----
    {
        dim3 ggrid(HDIM / BN, (NG * 128) / BM);
        k_sgemm<<<ggrid, 256, 0, stream>>>(hcur, conv2_W, hW, HDIM, list1, nullptr,
                                           nullptr, nullptr, nullptr, nullptr);
    }
    k_gcn_agg<<<(NG * 128) / 4, 256, 0, stream>>>(hW, dis, cs1, ce1, ccsr1, cwdg1, conv2_b,
                                                  list1, 32, p2_relW, p2_rootW,
                                                  hcur, r_rel, r_root);
    k_topkpool<false, true, false><<<NG * 4, 256, 0, stream>>>(
        dis, cs1, ce1, ccsr1, r_rel, r_root, nullptr, nullptr, p2_relb, 64,
        list2, hcur, z, 1.0f / 64.0f, dis2, cs2, ce2, ccsr2, cwdg2, EPG);

    // ---- stage 3 ----
    {
        dim3 ggrid(HDIM / BN, (NG * 64) / BM);
        k_sgemm<<<ggrid, 256, 0, stream>>>(hcur, conv3_W, hW, HDIM, list2, nullptr,
                                           nullptr, nullptr, nullptr, nullptr);
    }
    k_gcn_agg<<<(NG * 64) / 4, 256, 0, stream>>>(hW, dis2, cs2, ce2, ccsr2, cwdg2, conv3_b,
                                                 list2, 16, p2_relW, p2_rootW,
                                                 hcur, r_rel, r_root);
    k_topkpool<false, false, false><<<NG * 4, 256, 0, stream>>>(
        dis2, cs2, ce2, ccsr2, r_rel, r_root, nullptr, nullptr, p2_relb, 32,
        nullptr, hcur, z, 1.0f / 32.0f, nullptr, nullptr, nullptr, nullptr, nullptr, EPG);

    // ---- MLP ----
    k_mlp<<<NG, 256, 0, stream>>>(z, fc1_W, fc1_b, fc2_W, fc2_b, fc3_W, fc3_b, out);
}

// Round 13
// 275.588 us; speedup vs baseline: 1.1523x; 1.0204x over previous
//
#include <hip/hip_runtime.h>
#include <math.h>

#define NG 128          // graphs
#define NPG 256         // nodes per graph
#define NN 32768        // total nodes
#define HDIM 256        // hidden
#define FIN 128         // in features

// ---------------- CSR build: block per graph, LDS counting sort ----------------
__global__ __launch_bounds__(256) void k_csr(const int* __restrict__ esrc,
                                             const int* __restrict__ edst, int EPG,
                                             int* __restrict__ rowptr, int* __restrict__ csr) {
    __shared__ int cnt[NPG];
    __shared__ int pref[NPG];
    __shared__ int cur[NPG];
    int g = blockIdx.x, tid = threadIdx.x;
    cnt[tid] = 0;
    __syncthreads();
    int base = g * EPG;
    for (int e = base + tid; e < base + EPG; e += 256)
        atomicAdd(&cnt[edst[e] & (NPG - 1)], 1);
    __syncthreads();
    int v = cnt[tid];
    pref[tid] = v;
    __syncthreads();
    for (int off = 1; off < NPG; off <<= 1) {
        int t = (tid >= off) ? pref[tid - off] : 0;
        __syncthreads();
        pref[tid] += t;
        __syncthreads();
    }
    int excl = pref[tid] - v;
    rowptr[g * NPG + tid] = base + excl;
    cur[tid] = base + excl;
    if (g == 0 && tid == 0) rowptr[NN] = NG * EPG;
    __syncthreads();
    for (int e = base + tid; e < base + EPG; e += 256) {
        int d = edst[e] & (NPG - 1);
        int p = atomicAdd(&cur[d], 1);
        csr[p] = esrc[e];
    }
}

// XCD-locality swizzle
__device__ __forceinline__ int swz_block(int bid, int bpg) {
    int xcd = bid & 7, r = bid >> 3;
    int graph = xcd * (NG / 8) + r / bpg;
    int sub = r - (r / bpg) * bpg;
    return graph * bpg + sub;
}

// ---------------- fused sort + stage-1 aggregation: wave per node ----------------
__global__ __launch_bounds__(256) void k_sortagg(const float* __restrict__ x,
                                                 const int* __restrict__ rowptr,
                                                 int* __restrict__ csr,
                                                 float* __restrict__ xa) {
    __shared__ int skey[4][64];
    __shared__ float swgt[4][64];
    int blk = swz_block(blockIdx.x, NPG / 4);
    int w = threadIdx.x >> 6, lane = threadIdx.x & 63;
    int n = blk * 4 + w;
    int e0 = rowptr[n];
    int d = rowptr[n + 1] - e0;
    float ddst = rsqrtf((float)(1 + d));
    bool big = d > 64;
    if (!big) {
        int key = (lane < d) ? csr[e0 + lane] : 0x7fffffff;
        int rank = 0;
        for (int j = 0; j < d; j++) {
            int kj = __shfl(key, j);
            rank += (kj < key || (kj == key && j < lane)) ? 1 : 0;
        }
        if (lane < d) {
            csr[e0 + rank] = key;
            skey[w][rank] = key;
            swgt[w][rank] = rsqrtf((float)(1 + rowptr[key + 1] - rowptr[key])) * ddst;
        }
    } else if (lane == 0) {
        for (int a = e0 + 1; a < e0 + d; a++) {
            int key = csr[a];
            int b = a - 1;
            while (b >= e0 && csr[b] > key) { csr[b + 1] = csr[b]; b--; }
            csr[b + 1] = key;
        }
    }
    __syncthreads();
    const float2* x2 = reinterpret_cast<const float2*>(x);
    float di = ddst;
    float2 h = x2[(size_t)n * (FIN / 2) + lane];
    float self = di * di;
    float ax = h.x * self, ay = h.y * self;
    if (!big) {
        for (int j = 0; j < d; j++) {
            int s = skey[w][j];
            float we = swgt[w][j];
            float2 hs = x2[(size_t)s * (FIN / 2) + lane];
            ax += hs.x * we; ay += hs.y * we;
        }
    } else {
        for (int e = e0; e < e0 + d; e++) {
            int s = csr[e];
            float we = rsqrtf((float)(1 + rowptr[s + 1] - rowptr[s])) * ddst;
            float2 hs = x2[(size_t)s * (FIN / 2) + lane];
            ax += hs.x * we; ay += hs.y * we;
        }
    }
    float2 o; o.x = ax; o.y = ay;
    reinterpret_cast<float2*>(xa)[(size_t)n * (FIN / 2) + lane] = o;
}

// ---------------- SGEMM (64x64, 4x4, pad 68, reg dbuf) ----------------
// optional A-row scaling by tansel[list position] (pool fold-in; bit-exact vs
// pre-scaled rows since h*t rounds once either way).
#define BM 64
#define BN 64
#define BK 16
#define BMP 68
__global__ __launch_bounds__(256) void k_sgemm(const float* __restrict__ A,
                                               const float* __restrict__ B,
                                               float* __restrict__ C, int K,
                                               const int* __restrict__ list,
                                               const float* __restrict__ tansel,
                                               const float* __restrict__ brelu,
                                               const float* __restrict__ wrel,
                                               const float* __restrict__ wroot,
                                               float* __restrict__ rrel4,
                                               float* __restrict__ rroot4) {
    const int N = HDIM;
    __shared__ float As[BK][BMP];
    __shared__ float Bs[BK][BN];
    int tid = threadIdx.x;
    int tx = tid & 15, ty = tid >> 4;
    int row0 = blockIdx.y * BM, col0 = blockIdx.x * BN;
    int lm = tid >> 2;
    int arow = list ? list[row0 + lm] : (row0 + lm);
    float tv = tansel ? tansel[row0 + lm] : 1.0f;
    int crow[4];
#pragma unroll
    for (int i = 0; i < 4; i++) {
        int r = row0 + ty * 4 + i;
        crow[i] = list ? list[r] : r;
    }
    int k4 = (tid & 3) * 4;
    int kkB = tid >> 4, cB = (tid & 15) * 4;
    float4 aP = *reinterpret_cast<const float4*>(&A[(size_t)arow * K + k4]);
    float4 bP = *reinterpret_cast<const float4*>(&B[(size_t)kkB * N + col0 + cB]);
    float acc[4][4] = {};
    for (int kb = 0; kb < K; kb += BK) {
        As[k4 + 0][lm] = aP.x * tv; As[k4 + 1][lm] = aP.y * tv;
        As[k4 + 2][lm] = aP.z * tv; As[k4 + 3][lm] = aP.w * tv;
        *reinterpret_cast<float4*>(&Bs[kkB][cB]) = bP;
        __syncthreads();
        if (kb + BK < K) {
            aP = *reinterpret_cast<const float4*>(&A[(size_t)arow * K + kb + BK + k4]);
            bP = *reinterpret_cast<const float4*>(&B[(size_t)(kb + BK + kkB) * N + col0 + cB]);
        }
#pragma unroll
        for (int k = 0; k < BK; k++) {
            float4 a = *reinterpret_cast<float4*>(&As[k][ty * 4]);
            float4 b = *reinterpret_cast<float4*>(&Bs[k][tx * 4]);
            float av[4] = {a.x, a.y, a.z, a.w};
            float bv[4] = {b.x, b.y, b.z, b.w};
#pragma unroll
            for (int i = 0; i < 4; i++)
#pragma unroll
                for (int j = 0; j < 4; j++) acc[i][j] += av[i] * bv[j];
        }
        __syncthreads();
    }
    float4 bb = make_float4(0.f, 0.f, 0.f, 0.f);
    if (brelu) bb = *reinterpret_cast<const float4*>(&brelu[col0 + tx * 4]);
    float4 wr = make_float4(0.f, 0.f, 0.f, 0.f), wo = wr;
    if (wrel) {
        wr = *reinterpret_cast<const float4*>(&wrel[col0 + tx * 4]);
        wo = *reinterpret_cast<const float4*>(&wroot[col0 + tx * 4]);
    }
#pragma unroll
    for (int i = 0; i < 4; i++) {
        float4 v = make_float4(acc[i][0], acc[i][1], acc[i][2], acc[i][3]);
        if (brelu) {
            v.x = fmaxf(v.x + bb.x, 0.f);
            v.y = fmaxf(v.y + bb.y, 0.f);
            v.z = fmaxf(v.z + bb.z, 0.f);
            v.w = fmaxf(v.w + bb.w, 0.f);
        }
        *reinterpret_cast<float4*>(&C[(size_t)crow[i] * N + col0 + tx * 4]) = v;
        if (wrel) {
            float s1 = v.x * wr.x + v.y * wr.y + v.z * wr.z + v.w * wr.w;
            float s2 = v.x * wo.x + v.y * wo.y + v.z * wo.z + v.w * wo.w;
            for (int off = 8; off > 0; off >>= 1) {
                s1 += __shfl_down(s1, off, 16);
                s2 += __shfl_down(s2, off, 16);
            }
            if (tx == 0) {
                rrel4[(size_t)crow[i] * 4 + blockIdx.x] = s1;
                rroot4[(size_t)crow[i] * 4 + blockIdx.x] = s2;
            }
        }
    }
}

// stages 2/3: wave per ACTIVE node, branch-free gather over COMPACT edge rows
__global__ __launch_bounds__(256) void k_gcn_agg(const float* __restrict__ hW,
                                                 const float* __restrict__ dis,
                                                 const int* __restrict__ rs,
                                                 const int* __restrict__ re,
                                                 const int* __restrict__ ccsr,
                                                 const float* __restrict__ cwedge,
                                                 const float* __restrict__ bias,
                                                 const int* __restrict__ list, int bpg,
                                                 const float* __restrict__ w_rel,
                                                 const float* __restrict__ w_root,
                                                 float* __restrict__ out,
                                                 float* __restrict__ r_rel,
                                                 float* __restrict__ r_root) {
    int blk = swz_block(blockIdx.x, bpg);
    int idx = blk * 4 + (threadIdx.x >> 6);
    int lane = threadIdx.x & 63;
    int wid = list[idx];
    float di = dis[wid];
    float4 h = *reinterpret_cast<const float4*>(&hW[(size_t)wid * HDIM + lane * 4]);
    float self = di * di;
    float ax = h.x * self, ay = h.y * self, az = h.z * self, aw = h.w * self;
    int e0 = rs[wid], e1 = re[wid];
    for (int e = e0; e < e1; e++) {
        float w = cwedge[e];
        int s = ccsr[e];
        float4 hs = *reinterpret_cast<const float4*>(&hW[(size_t)s * HDIM + lane * 4]);
        ax += hs.x * w; ay += hs.y * w; az += hs.z * w; aw += hs.w * w;
    }
    float4 b = *reinterpret_cast<const float4*>(&bias[lane * 4]);
    float4 o;
    o.x = fmaxf(ax + b.x, 0.f);
    o.y = fmaxf(ay + b.y, 0.f);
    o.z = fmaxf(az + b.z, 0.f);
    o.w = fmaxf(aw + b.w, 0.f);
    *reinterpret_cast<float4*>(&out[(size_t)wid * HDIM + lane * 4]) = o;
    float4 wr = *reinterpret_cast<const float4*>(&w_rel[lane * 4]);
    float4 wo = *reinterpret_cast<const float4*>(&w_root[lane * 4]);
    float s1 = o.x * wr.x + o.y * wr.y + o.z * wr.z + o.w * wr.w;
    float s2 = o.x * wo.x + o.y * wo.y + o.z * wo.z + o.w * wo.w;
    for (int off = 32; off > 0; off >>= 1) {
        s1 += __shfl_down(s1, off);
        s2 += __shfl_down(s2, off);
    }
    if (lane == 0) { r_rel[wid] = s1; r_root[wid] = s2; }
}

// ---------------- fused score + top-k + readout (+compact-CSR emit) ----------------
// grid = NG*4; 4 blocks per graph redundantly compute top-k in LDS; global side
// products (list, tansel, disN, compact CSR) written by block fc==0 only.
// h is READ-ONLY: the pool scale folds into the next GEMM's A-staging.
template<bool STAGE1, bool EMIT, bool FIRST>
__global__ __launch_bounds__(256) void k_topkpool(const float* __restrict__ dis,
                                                  const int* __restrict__ rs,
                                                  const int* __restrict__ re,
                                                  const int* __restrict__ csr_in,
                                                  const float* __restrict__ r_rel,
                                                  const float* __restrict__ r_root,
                                                  const float* __restrict__ rrel4,
                                                  const float* __restrict__ rroot4,
                                                  const float* __restrict__ b_rel, int k,
                                                  int* __restrict__ list,
                                                  float* __restrict__ tanselG,
                                                  const float* __restrict__ h,
                                                  float* __restrict__ z, float invk,
                                                  float* __restrict__ disN,
                                                  int* __restrict__ csN,
                                                  int* __restrict__ ceN,
                                                  int* __restrict__ ccsrN,
                                                  float* __restrict__ cwedgeN,
                                                  int EPG) {
    __shared__ float rrel[NPG];
    __shared__ float sc[NPG];
    __shared__ int pref[NPG];
    __shared__ int sels[NPG];
    __shared__ float disn[NPG];
    __shared__ int newl[128];
    __shared__ float tvsel[128];
    __shared__ float red_s[4][64];
    __shared__ float red_m[4][64];
    int g = blockIdx.x >> 2, fc = blockIdx.x & 3;
    int tid = threadIdx.x;
    int n = g * NPG + tid;
    bool act = STAGE1 ? true : (dis[n] > 0.f);
    float rr, ro;
    if (STAGE1) {
        float4 r4 = *reinterpret_cast<const float4*>(&rrel4[(size_t)n * 4]);
        float4 o4 = *reinterpret_cast<const float4*>(&rroot4[(size_t)n * 4]);
        rr = ((r4.x + r4.y) + r4.z) + r4.w;
        ro = ((o4.x + o4.y) + o4.z) + o4.w;
    } else {
        rr = act ? r_rel[n] : 0.f;
        ro = act ? r_root[n] : 0.f;
    }
    rrel[tid] = act ? rr : 0.f;
    __syncthreads();
    int e0 = rs[n], e1 = re[n];
    float my;
    if (act) {
        float s = b_rel[0] + ro;
        for (int e = e0; e < e1; e++) s += rrel[csr_in[e] & (NPG - 1)];
        my = s;
    } else {
        my = -INFINITY;
    }
    sc[tid] = my;
    __syncthreads();
    int cnt = 0;
    for (int j = 0; j < NPG; j++) {
        float v = sc[j];
        cnt += (v > my || (v == my && j < tid)) ? 1 : 0;
    }
    int a = (cnt < k) ? 1 : 0;
    sels[tid] = a;
    pref[tid] = a;
    __syncthreads();
    for (int off = 1; off < NPG; off <<= 1) {
        int v = (tid >= off) ? pref[tid - off] : 0;
        __syncthreads();
        pref[tid] += v;
        __syncthreads();
    }
    if (a) {
        int rk = pref[tid] - 1;
        newl[rk] = tid;
        float t = tanhf(my);
        tvsel[rk] = t;
        if (fc == 0 && list) {
            list[g * k + rk] = n;
            tanselG[g * k + rk] = t;
        }
    }
    if (EMIT) {
        int deg2 = 0;
        if (a) {
            for (int e = e0; e < e1; e++) deg2 += sels[csr_in[e] & (NPG - 1)];
        }
        float dn = a ? rsqrtf((float)(1 + deg2)) : 0.f;
        disn[tid] = dn;
        __syncthreads();
        pref[tid] = deg2;
        __syncthreads();
        for (int off = 1; off < NPG; off <<= 1) {
            int v = (tid >= off) ? pref[tid - off] : 0;
            __syncthreads();
            pref[tid] += v;
            __syncthreads();
        }
        if (fc == 0) {
            disN[n] = dn;
            int start = g * EPG + pref[tid] - deg2;
            csN[n] = start;
            ceN[n] = start + deg2;
            if (a) {
                int p = start;
                for (int e = e0; e < e1; e++) {
                    int srcg = csr_in[e];
                    int j = srcg & (NPG - 1);
                    if (sels[j]) {
                        ccsrN[p] = srcg;
                        cwedgeN[p] = disn[j] * dn;
                        p++;
                    }
                }
            }
        }
    }
    __syncthreads();
    // readout for this block's 64-feature chunk (h read-only)
    int xq = tid & 63, y = tid >> 6;
    int f = fc * 64 + xq;
    float s = 0.f, mx = -INFINITY;
    for (int idx = y; idx < k; idx += 4) {
        int node = g * NPG + newl[idx];
        float v = h[(size_t)node * HDIM + f] * tvsel[idx];
        s += v;
        mx = fmaxf(mx, v);
    }
    red_s[y][xq] = s;
    red_m[y][xq] = mx;
    __syncthreads();
    if (y == 0) {
        s = red_s[0][xq] + red_s[1][xq] + red_s[2][xq] + red_s[3][xq];
        mx = fmaxf(fmaxf(red_m[0][xq], red_m[1][xq]), fmaxf(red_m[2][xq], red_m[3][xq]));
        if (FIRST) {
            z[g * 768 + f] = s * invk;
            z[g * 768 + 256 + f] = mx;
            z[g * 768 + 512 + f] = s;
        } else {
            z[g * 768 + f] += s * invk;
            z[g * 768 + 256 + f] += mx;
            z[g * 768 + 512 + f] += s;
        }
    }
}

// ---------------- fused MLP (partial-sum groupings fixed) ----------------
__global__ __launch_bounds__(256) void k_mlp(const float* __restrict__ z,
                                             const float* __restrict__ W1, const float* __restrict__ b1,
                                             const float* __restrict__ W2, const float* __restrict__ b2,
                                             const float* __restrict__ W3, const float* __restrict__ b3,
                                             float* __restrict__ out) {
    __shared__ float zb[768];
    __shared__ float t1[256];
    __shared__ float t2[128];
    __shared__ float t3[10];
    __shared__ float lse;
    int g = blockIdx.x, tid = threadIdx.x;
    zb[tid] = z[g * 768 + tid];
    zb[tid + 256] = z[g * 768 + 256 + tid];
    zb[tid + 512] = z[g * 768 + 512 + tid];
    __syncthreads();
    {
        int col = tid;
        float r0 = 0.f, r1 = 0.f, r2 = 0.f, r3 = 0.f;
        for (int i = 0;   i < 192; i++) r0 += zb[i] * W1[(size_t)i * 256 + col];
        for (int i = 192; i < 384; i++) r1 += zb[i] * W1[(size_t)i * 256 + col];
        for (int i = 384; i < 576; i++) r2 += zb[i] * W1[(size_t)i * 256 + col];
        for (int i = 576; i < 768; i++) r3 += zb[i] * W1[(size_t)i * 256 + col];
        t1[col] = fmaxf(r0 + r1 + r2 + r3 + b1[col], 0.f);
    }
    __syncthreads();
    if (tid < 128) {
        int col = tid;
        float r0 = 0.f, r1 = 0.f, r2 = 0.f, r3 = 0.f;
        for (int i = 0;   i < 64;  i++) r0 += t1[i] * W2[(size_t)i * 128 + col];
        for (int i = 64;  i < 128; i++) r1 += t1[i] * W2[(size_t)i * 128 + col];
        for (int i = 128; i < 192; i++) r2 += t1[i] * W2[(size_t)i * 128 + col];
        for (int i = 192; i < 256; i++) r3 += t1[i] * W2[(size_t)i * 128 + col];
        t2[col] = fmaxf(((r0 + r1) + r2) + r3 + b2[col], 0.f);
    }
    __syncthreads();
    if (tid < 10) {
        float v = b3[tid];
        for (int i = 0; i < 128; i++) v += t2[i] * W3[(size_t)i * 10 + tid];
        t3[tid] = v;
    }
    __syncthreads();
    if (tid == 0) {
        float m = t3[0];
        for (int c = 1; c < 10; c++) m = fmaxf(m, t3[c]);
        float se = 0.f;
        for (int c = 0; c < 10; c++) se += expf(t3[c] - m);
        lse = m + logf(se);
    }
    __syncthreads();
    if (tid < 10) out[g * 10 + tid] = t3[tid] - lse;
}

// ---------------- launcher ----------------
extern "C" void kernel_launch(void* const* d_in, const int* in_sizes, int n_in,
                              void* d_out, int out_size, void* d_ws, size_t ws_size,
                              hipStream_t stream) {
    const float* x        = (const float*)d_in[0];
    const int*   ei       = (const int*)d_in[1];
    const float* conv1_W  = (const float*)d_in[3];
    const float* conv1_b  = (const float*)d_in[4];
    const float* conv2_W  = (const float*)d_in[5];
    const float* conv2_b  = (const float*)d_in[6];
    const float* conv3_W  = (const float*)d_in[7];
    const float* conv3_b  = (const float*)d_in[8];
    const float* p1_relW  = (const float*)d_in[9];
    const float* p1_relb  = (const float*)d_in[10];
    const float* p1_rootW = (const float*)d_in[11];
    const float* p2_relW  = (const float*)d_in[12];
    const float* p2_relb  = (const float*)d_in[13];
    const float* p2_rootW = (const float*)d_in[14];
    const float* fc1_W    = (const float*)d_in[15];
    const float* fc1_b    = (const float*)d_in[16];
    const float* fc2_W    = (const float*)d_in[17];
    const float* fc2_b    = (const float*)d_in[18];
    const float* fc3_W    = (const float*)d_in[19];
    const float* fc3_b    = (const float*)d_in[20];
    float* out = (float*)d_out;

    const int E = in_sizes[1] / 2;
    const int EPG = E / NG;
    const int* e_src = ei;
    const int* e_dst = ei + E;

    // workspace layout
    char* base = (char*)d_ws;
    size_t off = 0;
    auto alloc = [&](size_t bytes) { size_t o = off; off = (off + bytes + 255) & ~(size_t)255; return o; };
    float* hW     = (float*)(base + alloc((size_t)NN * HDIM * 4));   // also xa (NN x FIN)
    float* hcur   = (float*)(base + alloc((size_t)NN * HDIM * 4));
    float* dis    = (float*)(base + alloc(NN * 4));   // stage-2 dis
    float* dis2   = (float*)(base + alloc(NN * 4));   // stage-3 dis
    float* r_rel  = (float*)(base + alloc(NN * 4));
    float* r_root = (float*)(base + alloc(NN * 4));
    float* rrel4  = (float*)(base + alloc((size_t)NN * 4 * 4));
    float* rroot4 = (float*)(base + alloc((size_t)NN * 4 * 4));
    int*   rowptr = (int*)(base + alloc((NN + 1) * 4));
    int*   csr    = (int*)(base + alloc((size_t)E * 4));
    int*   cs1    = (int*)(base + alloc(NN * 4));
    int*   ce1    = (int*)(base + alloc(NN * 4));
    int*   ccsr1  = (int*)(base + alloc((size_t)E * 4));
    float* cwdg1  = (float*)(base + alloc((size_t)E * 4));
    int*   cs2    = (int*)(base + alloc(NN * 4));
    int*   ce2    = (int*)(base + alloc(NN * 4));
    int*   ccsr2  = (int*)(base + alloc((size_t)E * 4));
    float* cwdg2  = (float*)(base + alloc((size_t)E * 4));
    float* z      = (float*)(base + alloc((size_t)NG * 768 * 4));
    int*   list1  = (int*)(base + alloc((size_t)NG * 128 * 4));
    int*   list2  = (int*)(base + alloc((size_t)NG * 64 * 4));
    float* tans1  = (float*)(base + alloc((size_t)NG * 128 * 4));
    float* tans2  = (float*)(base + alloc((size_t)NG * 64 * 4));

    // CSR build + fused sort/stage-1 aggregation
    k_csr<<<NG, 256, 0, stream>>>(e_src, e_dst, EPG, rowptr, csr);
    float* xa = hW;
    k_sortagg<<<NN / 4, 256, 0, stream>>>(x, rowptr, csr, xa);

    // ---- stage 1 ----
    {
        dim3 ggrid(HDIM / BN, NN / BM);
        k_sgemm<<<ggrid, 256, 0, stream>>>(xa, conv1_W, hcur, FIN, nullptr, nullptr, conv1_b,
                                           p1_relW, p1_rootW, rrel4, rroot4);
    }
    k_topkpool<true, true, true><<<NG * 4, 256, 0, stream>>>(
        nullptr, rowptr, rowptr + 1, csr, nullptr, nullptr, rrel4, rroot4, p1_relb, 128,
        list1, tans1, hcur, z, 1.0f / 128.0f, dis, cs1, ce1, ccsr1, cwdg1, EPG);

    // ---- stage 2 ----
    {
        dim3 ggrid(HDIM / BN, (NG * 128) / BM);
        k_sgemm<<<ggrid, 256, 0, stream>>>(hcur, conv2_W, hW, HDIM, list1, tans1, nullptr,
                                           nullptr, nullptr, nullptr, nullptr);
    }
    k_gcn_agg<<<(NG * 128) / 4, 256, 0, stream>>>(hW, dis, cs1, ce1, ccsr1, cwdg1, conv2_b,
                                                  list1, 32, p2_relW, p2_rootW,
                                                  hcur, r_rel, r_root);
    k_topkpool<false, true, false><<<NG * 4, 256, 0, stream>>>(
        dis, cs1, ce1, ccsr1, r_rel, r_root, nullptr, nullptr, p2_relb, 64,
        list2, tans2, hcur, z, 1.0f / 64.0f, dis2, cs2, ce2, ccsr2, cwdg2, EPG);

    // ---- stage 3 ----
    {
        dim3 ggrid(HDIM / BN, (NG * 64) / BM);
        k_sgemm<<<ggrid, 256, 0, stream>>>(hcur, conv3_W, hW, HDIM, list2, tans2, nullptr,
                                           nullptr, nullptr, nullptr, nullptr);
    }
    k_gcn_agg<<<(NG * 64) / 4, 256, 0, stream>>>(hW, dis2, cs2, ce2, ccsr2, cwdg2, conv3_b,
                                                 list2, 16, p2_relW, p2_rootW,
                                                 hcur, r_rel, r_root);
    k_topkpool<false, false, false><<<NG * 4, 256, 0, stream>>>(
        dis2, cs2, ce2, ccsr2, r_rel, r_root, nullptr, nullptr, p2_relb, 32,
        nullptr, nullptr, hcur, z, 1.0f / 32.0f, nullptr, nullptr, nullptr, nullptr, nullptr, EPG);

    // ---- MLP ----
    k_mlp<<<NG, 256, 0, stream>>>(z, fc1_W, fc1_b, fc2_W, fc2_b, fc3_W, fc3_b, out);
}

// Round 14
// 265.010 us; speedup vs baseline: 1.1983x; 1.0399x over previous
//
#include <hip/hip_runtime.h>
#include <math.h>

#define NG 128          // graphs
#define NPG 256         // nodes per graph
#define NN 32768        // total nodes
#define HDIM 256        // hidden
#define FIN 128         // in features

// ---------------- CSR build: block per graph, LDS counting sort ----------------
__global__ __launch_bounds__(256) void k_csr(const int* __restrict__ esrc,
                                             const int* __restrict__ edst, int EPG,
                                             int* __restrict__ rowptr, int* __restrict__ csr) {
    __shared__ int cnt[NPG];
    __shared__ int pref[NPG];
    __shared__ int cur[NPG];
    int g = blockIdx.x, tid = threadIdx.x;
    cnt[tid] = 0;
    __syncthreads();
    int base = g * EPG;
    for (int e = base + tid; e < base + EPG; e += 256)
        atomicAdd(&cnt[edst[e] & (NPG - 1)], 1);
    __syncthreads();
    int v = cnt[tid];
    pref[tid] = v;
    __syncthreads();
    for (int off = 1; off < NPG; off <<= 1) {
        int t = (tid >= off) ? pref[tid - off] : 0;
        __syncthreads();
        pref[tid] += t;
        __syncthreads();
    }
    int excl = pref[tid] - v;
    rowptr[g * NPG + tid] = base + excl;
    cur[tid] = base + excl;
    if (g == 0 && tid == 0) rowptr[NN] = NG * EPG;
    __syncthreads();
    for (int e = base + tid; e < base + EPG; e += 256) {
        int d = edst[e] & (NPG - 1);
        int p = atomicAdd(&cur[d], 1);
        csr[p] = esrc[e];
    }
}

// XCD-locality swizzle
__device__ __forceinline__ int swz_block(int bid, int bpg) {
    int xcd = bid & 7, r = bid >> 3;
    int graph = xcd * (NG / 8) + r / bpg;
    int sub = r - (r / bpg) * bpg;
    return graph * bpg + sub;
}

// ---------------- fused sort + stage-1 aggregation: wave per node ----------------
__global__ __launch_bounds__(256) void k_sortagg(const float* __restrict__ x,
                                                 const int* __restrict__ rowptr,
                                                 int* __restrict__ csr,
                                                 float* __restrict__ xa) {
    __shared__ int skey[4][64];
    __shared__ float swgt[4][64];
    int blk = swz_block(blockIdx.x, NPG / 4);
    int w = threadIdx.x >> 6, lane = threadIdx.x & 63;
    int n = blk * 4 + w;
    int e0 = rowptr[n];
    int d = rowptr[n + 1] - e0;
    float ddst = rsqrtf((float)(1 + d));
    bool big = d > 64;
    if (!big) {
        int key = (lane < d) ? csr[e0 + lane] : 0x7fffffff;
        int rank = 0;
        for (int j = 0; j < d; j++) {
            int kj = __shfl(key, j);
            rank += (kj < key || (kj == key && j < lane)) ? 1 : 0;
        }
        if (lane < d) {
            csr[e0 + rank] = key;
            skey[w][rank] = key;
            swgt[w][rank] = rsqrtf((float)(1 + rowptr[key + 1] - rowptr[key])) * ddst;
        }
    } else if (lane == 0) {
        for (int a = e0 + 1; a < e0 + d; a++) {
            int key = csr[a];
            int b = a - 1;
            while (b >= e0 && csr[b] > key) { csr[b + 1] = csr[b]; b--; }
            csr[b + 1] = key;
        }
    }
    __syncthreads();
    const float2* x2 = reinterpret_cast<const float2*>(x);
    float di = ddst;
    float2 h = x2[(size_t)n * (FIN / 2) + lane];
    float self = di * di;
    float ax = h.x * self, ay = h.y * self;
    if (!big) {
        for (int j = 0; j < d; j++) {
            int s = skey[w][j];
            float we = swgt[w][j];
            float2 hs = x2[(size_t)s * (FIN / 2) + lane];
            ax += hs.x * we; ay += hs.y * we;
        }
    } else {
        for (int e = e0; e < e0 + d; e++) {
            int s = csr[e];
            float we = rsqrtf((float)(1 + rowptr[s + 1] - rowptr[s])) * ddst;
            float2 hs = x2[(size_t)s * (FIN / 2) + lane];
            ax += hs.x * we; ay += hs.y * we;
        }
    }
    float2 o; o.x = ax; o.y = ay;
    reinterpret_cast<float2*>(xa)[(size_t)n * (FIN / 2) + lane] = o;
}

// ---------------- SGEMM (64x64, 4x4, pad 68, reg dbuf) ----------------
#define BM 64
#define BN 64
#define BK 16
#define BMP 68
__global__ __launch_bounds__(256) void k_sgemm(const float* __restrict__ A,
                                               const float* __restrict__ B,
                                               float* __restrict__ C, int K,
                                               const int* __restrict__ list,
                                               const float* __restrict__ tansel,
                                               const float* __restrict__ brelu,
                                               const float* __restrict__ wrel,
                                               const float* __restrict__ wroot,
                                               float* __restrict__ rrel4,
                                               float* __restrict__ rroot4) {
    const int N = HDIM;
    __shared__ float As[BK][BMP];
    __shared__ float Bs[BK][BN];
    int tid = threadIdx.x;
    int tx = tid & 15, ty = tid >> 4;
    int row0 = blockIdx.y * BM, col0 = blockIdx.x * BN;
    int lm = tid >> 2;
    int arow = list ? list[row0 + lm] : (row0 + lm);
    float tv = tansel ? tansel[row0 + lm] : 1.0f;
    int crow[4];
#pragma unroll
    for (int i = 0; i < 4; i++) {
        int r = row0 + ty * 4 + i;
        crow[i] = list ? list[r] : r;
    }
    int k4 = (tid & 3) * 4;
    int kkB = tid >> 4, cB = (tid & 15) * 4;
    float4 aP = *reinterpret_cast<const float4*>(&A[(size_t)arow * K + k4]);
    float4 bP = *reinterpret_cast<const float4*>(&B[(size_t)kkB * N + col0 + cB]);
    float acc[4][4] = {};
    for (int kb = 0; kb < K; kb += BK) {
        As[k4 + 0][lm] = aP.x * tv; As[k4 + 1][lm] = aP.y * tv;
        As[k4 + 2][lm] = aP.z * tv; As[k4 + 3][lm] = aP.w * tv;
        *reinterpret_cast<float4*>(&Bs[kkB][cB]) = bP;
        __syncthreads();
        if (kb + BK < K) {
            aP = *reinterpret_cast<const float4*>(&A[(size_t)arow * K + kb + BK + k4]);
            bP = *reinterpret_cast<const float4*>(&B[(size_t)(kb + BK + kkB) * N + col0 + cB]);
        }
#pragma unroll
        for (int k = 0; k < BK; k++) {
            float4 a = *reinterpret_cast<float4*>(&As[k][ty * 4]);
            float4 b = *reinterpret_cast<float4*>(&Bs[k][tx * 4]);
            float av[4] = {a.x, a.y, a.z, a.w};
            float bv[4] = {b.x, b.y, b.z, b.w};
#pragma unroll
            for (int i = 0; i < 4; i++)
#pragma unroll
                for (int j = 0; j < 4; j++) acc[i][j] += av[i] * bv[j];
        }
        __syncthreads();
    }
    float4 bb = make_float4(0.f, 0.f, 0.f, 0.f);
    if (brelu) bb = *reinterpret_cast<const float4*>(&brelu[col0 + tx * 4]);
    float4 wr = make_float4(0.f, 0.f, 0.f, 0.f), wo = wr;
    if (wrel) {
        wr = *reinterpret_cast<const float4*>(&wrel[col0 + tx * 4]);
        wo = *reinterpret_cast<const float4*>(&wroot[col0 + tx * 4]);
    }
#pragma unroll
    for (int i = 0; i < 4; i++) {
        float4 v = make_float4(acc[i][0], acc[i][1], acc[i][2], acc[i][3]);
        if (brelu) {
            v.x = fmaxf(v.x + bb.x, 0.f);
            v.y = fmaxf(v.y + bb.y, 0.f);
            v.z = fmaxf(v.z + bb.z, 0.f);
            v.w = fmaxf(v.w + bb.w, 0.f);
        }
        *reinterpret_cast<float4*>(&C[(size_t)crow[i] * N + col0 + tx * 4]) = v;
        if (wrel) {
            float s1 = v.x * wr.x + v.y * wr.y + v.z * wr.z + v.w * wr.w;
            float s2 = v.x * wo.x + v.y * wo.y + v.z * wo.z + v.w * wo.w;
            for (int off = 8; off > 0; off >>= 1) {
                s1 += __shfl_down(s1, off, 16);
                s2 += __shfl_down(s2, off, 16);
            }
            if (tx == 0) {
                rrel4[(size_t)crow[i] * 4 + blockIdx.x] = s1;
                rroot4[(size_t)crow[i] * 4 + blockIdx.x] = s2;
            }
        }
    }
}

// stages 2/3: wave per ACTIVE node, branch-free gather over COMPACT edge rows
__global__ __launch_bounds__(256) void k_gcn_agg(const float* __restrict__ hW,
                                                 const float* __restrict__ dis,
                                                 const int* __restrict__ rs,
                                                 const int* __restrict__ re,
                                                 const int* __restrict__ ccsr,
                                                 const float* __restrict__ cwedge,
                                                 const float* __restrict__ bias,
                                                 const int* __restrict__ list, int bpg,
                                                 const float* __restrict__ w_rel,
                                                 const float* __restrict__ w_root,
                                                 float* __restrict__ out,
                                                 float* __restrict__ r_rel,
                                                 float* __restrict__ r_root) {
    int blk = swz_block(blockIdx.x, bpg);
    int idx = blk * 4 + (threadIdx.x >> 6);
    int lane = threadIdx.x & 63;
    int wid = list[idx];
    float di = dis[wid];
    float4 h = *reinterpret_cast<const float4*>(&hW[(size_t)wid * HDIM + lane * 4]);
    float self = di * di;
    float ax = h.x * self, ay = h.y * self, az = h.z * self, aw = h.w * self;
    int e0 = rs[wid], e1 = re[wid];
    for (int e = e0; e < e1; e++) {
        float w = cwedge[e];
        int s = ccsr[e];
        float4 hs = *reinterpret_cast<const float4*>(&hW[(size_t)s * HDIM + lane * 4]);
        ax += hs.x * w; ay += hs.y * w; az += hs.z * w; aw += hs.w * w;
    }
    float4 b = *reinterpret_cast<const float4*>(&bias[lane * 4]);
    float4 o;
    o.x = fmaxf(ax + b.x, 0.f);
    o.y = fmaxf(ay + b.y, 0.f);
    o.z = fmaxf(az + b.z, 0.f);
    o.w = fmaxf(aw + b.w, 0.f);
    *reinterpret_cast<float4*>(&out[(size_t)wid * HDIM + lane * 4]) = o;
    float4 wr = *reinterpret_cast<const float4*>(&w_rel[lane * 4]);
    float4 wo = *reinterpret_cast<const float4*>(&w_root[lane * 4]);
    float s1 = o.x * wr.x + o.y * wr.y + o.z * wr.z + o.w * wr.w;
    float s2 = o.x * wo.x + o.y * wo.y + o.z * wo.z + o.w * wo.w;
    for (int off = 32; off > 0; off >>= 1) {
        s1 += __shfl_down(s1, off);
        s2 += __shfl_down(s2, off);
    }
    if (lane == 0) { r_rel[wid] = s1; r_root[wid] = s2; }
}

// ---------------- fused score + top-k + readout (+compact-CSR emit) ----------------
// grid = NG*4; 4 blocks per graph redundantly compute top-k in LDS; global side
// products (list, tansel, disN, compact CSR) written by block fc==0 only.
// h is READ-ONLY; readout vectorized: 16 lanes x float4 feats, 4 node-subs/wave.
template<bool STAGE1, bool EMIT, bool FIRST>
__global__ __launch_bounds__(256) void k_topkpool(const float* __restrict__ dis,
                                                  const int* __restrict__ rs,
                                                  const int* __restrict__ re,
                                                  const int* __restrict__ csr_in,
                                                  const float* __restrict__ r_rel,
                                                  const float* __restrict__ r_root,
                                                  const float* __restrict__ rrel4,
                                                  const float* __restrict__ rroot4,
                                                  const float* __restrict__ b_rel, int k,
                                                  int* __restrict__ list,
                                                  float* __restrict__ tanselG,
                                                  const float* __restrict__ h,
                                                  float* __restrict__ z, float invk,
                                                  float* __restrict__ disN,
                                                  int* __restrict__ csN,
                                                  int* __restrict__ ceN,
                                                  int* __restrict__ ccsrN,
                                                  float* __restrict__ cwedgeN,
                                                  int EPG) {
    __shared__ float rrel[NPG];
    __shared__ float sc[NPG];
    __shared__ int pref[NPG];
    __shared__ int sels[NPG];
    __shared__ float disn[NPG];
    __shared__ int newl[128];
    __shared__ float tvsel[128];
    __shared__ float4 red4_s[4][16];
    __shared__ float4 red4_m[4][16];
    int g = blockIdx.x >> 2, fc = blockIdx.x & 3;
    int tid = threadIdx.x;
    int n = g * NPG + tid;
    bool act = STAGE1 ? true : (dis[n] > 0.f);
    float rr, ro;
    if (STAGE1) {
        float4 r4 = *reinterpret_cast<const float4*>(&rrel4[(size_t)n * 4]);
        float4 o4 = *reinterpret_cast<const float4*>(&rroot4[(size_t)n * 4]);
        rr = ((r4.x + r4.y) + r4.z) + r4.w;
        ro = ((o4.x + o4.y) + o4.z) + o4.w;
    } else {
        rr = act ? r_rel[n] : 0.f;
        ro = act ? r_root[n] : 0.f;
    }
    rrel[tid] = act ? rr : 0.f;
    __syncthreads();
    int e0 = rs[n], e1 = re[n];
    float my;
    if (act) {
        float s = b_rel[0] + ro;
        for (int e = e0; e < e1; e++) s += rrel[csr_in[e] & (NPG - 1)];
        my = s;
    } else {
        my = -INFINITY;
    }
    sc[tid] = my;
    __syncthreads();
    int cnt = 0;
    for (int j = 0; j < NPG; j++) {
        float v = sc[j];
        cnt += (v > my || (v == my && j < tid)) ? 1 : 0;
    }
    int a = (cnt < k) ? 1 : 0;
    sels[tid] = a;
    pref[tid] = a;
    __syncthreads();
    for (int off = 1; off < NPG; off <<= 1) {
        int v = (tid >= off) ? pref[tid - off] : 0;
        __syncthreads();
        pref[tid] += v;
        __syncthreads();
    }
    if (a) {
        int rk = pref[tid] - 1;
        newl[rk] = tid;
        float t = tanhf(my);
        tvsel[rk] = t;
        if (fc == 0 && list) {
            list[g * k + rk] = n;
            tanselG[g * k + rk] = t;
        }
    }
    if (EMIT) {
        int deg2 = 0;
        if (a) {
            for (int e = e0; e < e1; e++) deg2 += sels[csr_in[e] & (NPG - 1)];
        }
        float dn = a ? rsqrtf((float)(1 + deg2)) : 0.f;
        disn[tid] = dn;
        __syncthreads();
        pref[tid] = deg2;
        __syncthreads();
        for (int off = 1; off < NPG; off <<= 1) {
            int v = (tid >= off) ? pref[tid - off] : 0;
            __syncthreads();
            pref[tid] += v;
            __syncthreads();
        }
        if (fc == 0) {
            disN[n] = dn;
            int start = g * EPG + pref[tid] - deg2;
            csN[n] = start;
            ceN[n] = start + deg2;
            if (a) {
                int p = start;
                for (int e = e0; e < e1; e++) {
                    int srcg = csr_in[e];
                    int j = srcg & (NPG - 1);
                    if (sels[j]) {
                        ccsrN[p] = srcg;
                        cwedgeN[p] = disn[j] * dn;
                        p++;
                    }
                }
            }
        }
    }
    __syncthreads();
    // vectorized readout: wave = 16 lanes (float4 feats) x 4 node-subs; 4 waves
    {
        int q = tid & 15, sub = (tid >> 4) & 3, y = tid >> 6;
        const float4* h4 = reinterpret_cast<const float4*>(h);
        float4 s4 = make_float4(0.f, 0.f, 0.f, 0.f);
        float4 m4 = make_float4(-INFINITY, -INFINITY, -INFINITY, -INFINITY);
        for (int idx = y * 4 + sub; idx < k; idx += 16) {
            int node = g * NPG + newl[idx];
            float t = tvsel[idx];
            float4 v = h4[(size_t)node * (HDIM / 4) + fc * 16 + q];
            v.x *= t; v.y *= t; v.z *= t; v.w *= t;
            s4.x += v.x; s4.y += v.y; s4.z += v.z; s4.w += v.w;
            m4.x = fmaxf(m4.x, v.x); m4.y = fmaxf(m4.y, v.y);
            m4.z = fmaxf(m4.z, v.z); m4.w = fmaxf(m4.w, v.w);
        }
#pragma unroll
        for (int off = 16; off <= 32; off <<= 1) {
            s4.x += __shfl_down(s4.x, off); s4.y += __shfl_down(s4.y, off);
            s4.z += __shfl_down(s4.z, off); s4.w += __shfl_down(s4.w, off);
            m4.x = fmaxf(m4.x, __shfl_down(m4.x, off));
            m4.y = fmaxf(m4.y, __shfl_down(m4.y, off));
            m4.z = fmaxf(m4.z, __shfl_down(m4.z, off));
            m4.w = fmaxf(m4.w, __shfl_down(m4.w, off));
        }
        if (sub == 0) { red4_s[y][q] = s4; red4_m[y][q] = m4; }
        __syncthreads();
        if (tid < 16) {
            float4 a0 = red4_s[0][tid], a1 = red4_s[1][tid];
            float4 a2 = red4_s[2][tid], a3 = red4_s[3][tid];
            float4 S;
            S.x = ((a0.x + a1.x) + a2.x) + a3.x;
            S.y = ((a0.y + a1.y) + a2.y) + a3.y;
            S.z = ((a0.z + a1.z) + a2.z) + a3.z;
            S.w = ((a0.w + a1.w) + a2.w) + a3.w;
            float4 b0 = red4_m[0][tid], b1 = red4_m[1][tid];
            float4 b2 = red4_m[2][tid], b3 = red4_m[3][tid];
            float4 M;
            M.x = fmaxf(fmaxf(b0.x, b1.x), fmaxf(b2.x, b3.x));
            M.y = fmaxf(fmaxf(b0.y, b1.y), fmaxf(b2.y, b3.y));
            M.z = fmaxf(fmaxf(b0.z, b1.z), fmaxf(b2.z, b3.z));
            M.w = fmaxf(fmaxf(b0.w, b1.w), fmaxf(b2.w, b3.w));
            float4 Mean = make_float4(S.x * invk, S.y * invk, S.z * invk, S.w * invk);
            float4* z4 = reinterpret_cast<float4*>(z);
            int zb_ = (g * 768 + fc * 64) / 4 + tid;
            if (FIRST) {
                z4[zb_] = Mean;
                z4[zb_ + 64] = M;
                z4[zb_ + 128] = S;
            } else {
                float4 c0 = z4[zb_], c1 = z4[zb_ + 64], c2 = z4[zb_ + 128];
                c0.x += Mean.x; c0.y += Mean.y; c0.z += Mean.z; c0.w += Mean.w;
                c1.x += M.x; c1.y += M.y; c1.z += M.z; c1.w += M.w;
                c2.x += S.x; c2.y += S.y; c2.z += S.z; c2.w += S.w;
                z4[zb_] = c0;
                z4[zb_ + 64] = c1;
                z4[zb_ + 128] = c2;
            }
        }
    }
}

// ---------------- fused MLP (partial-sum groupings fixed) ----------------
__global__ __launch_bounds__(256) void k_mlp(const float* __restrict__ z,
                                             const float* __restrict__ W1, const float* __restrict__ b1,
                                             const float* __restrict__ W2, const float* __restrict__ b2,
                                             const float* __restrict__ W3, const float* __restrict__ b3,
                                             float* __restrict__ out) {
    __shared__ float zb[768];
    __shared__ float t1[256];
    __shared__ float t2[128];
    __shared__ float t3[10];
    __shared__ float lse;
    int g = blockIdx.x, tid = threadIdx.x;
    zb[tid] = z[g * 768 + tid];
    zb[tid + 256] = z[g * 768 + 256 + tid];
    zb[tid + 512] = z[g * 768 + 512 + tid];
    __syncthreads();
    {
        int col = tid;
        float r0 = 0.f, r1 = 0.f, r2 = 0.f, r3 = 0.f;
        for (int i = 0;   i < 192; i++) r0 += zb[i] * W1[(size_t)i * 256 + col];
        for (int i = 192; i < 384; i++) r1 += zb[i] * W1[(size_t)i * 256 + col];
        for (int i = 384; i < 576; i++) r2 += zb[i] * W1[(size_t)i * 256 + col];
        for (int i = 576; i < 768; i++) r3 += zb[i] * W1[(size_t)i * 256 + col];
        t1[col] = fmaxf(r0 + r1 + r2 + r3 + b1[col], 0.f);
    }
    __syncthreads();
    if (tid < 128) {
        int col = tid;
        float r0 = 0.f, r1 = 0.f, r2 = 0.f, r3 = 0.f;
        for (int i = 0;   i < 64;  i++) r0 += t1[i] * W2[(size_t)i * 128 + col];
        for (int i = 64;  i < 128; i++) r1 += t1[i] * W2[(size_t)i * 128 + col];
        for (int i = 128; i < 192; i++) r2 += t1[i] * W2[(size_t)i * 128 + col];
        for (int i = 192; i < 256; i++) r3 += t1[i] * W2[(size_t)i * 128 + col];
        t2[col] = fmaxf(((r0 + r1) + r2) + r3 + b2[col], 0.f);
    }
    __syncthreads();
    if (tid < 10) {
        float v = b3[tid];
        for (int i = 0; i < 128; i++) v += t2[i] * W3[(size_t)i * 10 + tid];
        t3[tid] = v;
    }
    __syncthreads();
    if (tid == 0) {
        float m = t3[0];
        for (int c = 1; c < 10; c++) m = fmaxf(m, t3[c]);
        float se = 0.f;
        for (int c = 0; c < 10; c++) se += expf(t3[c] - m);
        lse = m + logf(se);
    }
    __syncthreads();
    if (tid < 10) out[g * 10 + tid] = t3[tid] - lse;
}

// ---------------- launcher ----------------
extern "C" void kernel_launch(void* const* d_in, const int* in_sizes, int n_in,
                              void* d_out, int out_size, void* d_ws, size_t ws_size,
                              hipStream_t stream) {
    const float* x        = (const float*)d_in[0];
    const int*   ei       = (const int*)d_in[1];
    const float* conv1_W  = (const float*)d_in[3];
    const float* conv1_b  = (const float*)d_in[4];
    const float* conv2_W  = (const float*)d_in[5];
    const float* conv2_b  = (const float*)d_in[6];
    const float* conv3_W  = (const float*)d_in[7];
    const float* conv3_b  = (const float*)d_in[8];
    const float* p1_relW  = (const float*)d_in[9];
    const float* p1_relb  = (const float*)d_in[10];
    const float* p1_rootW = (const float*)d_in[11];
    const float* p2_relW  = (const float*)d_in[12];
    const float* p2_relb  = (const float*)d_in[13];
    const float* p2_rootW = (const float*)d_in[14];
    const float* fc1_W    = (const float*)d_in[15];
    const float* fc1_b    = (const float*)d_in[16];
    const float* fc2_W    = (const float*)d_in[17];
    const float* fc2_b    = (const float*)d_in[18];
    const float* fc3_W    = (const float*)d_in[19];
    const float* fc3_b    = (const float*)d_in[20];
    float* out = (float*)d_out;

    const int E = in_sizes[1] / 2;
    const int EPG = E / NG;
    const int* e_src = ei;
    const int* e_dst = ei + E;

    // workspace layout
    char* base = (char*)d_ws;
    size_t off = 0;
    auto alloc = [&](size_t bytes) { size_t o = off; off = (off + bytes + 255) & ~(size_t)255; return o; };
    float* hW     = (float*)(base + alloc((size_t)NN * HDIM * 4));   // also xa (NN x FIN)
    float* hcur   = (float*)(base + alloc((size_t)NN * HDIM * 4));
    float* dis    = (float*)(base + alloc(NN * 4));   // stage-2 dis
    float* dis2   = (float*)(base + alloc(NN * 4));   // stage-3 dis
    float* r_rel  = (float*)(base + alloc(NN * 4));
    float* r_root = (float*)(base + alloc(NN * 4));
    float* rrel4  = (float*)(base + alloc((size_t)NN * 4 * 4));
    float* rroot4 = (float*)(base + alloc((size_t)NN * 4 * 4));
    int*   rowptr = (int*)(base + alloc((NN + 1) * 4));
    int*   csr    = (int*)(base + alloc((size_t)E * 4));
    int*   cs1    = (int*)(base + alloc(NN * 4));
    int*   ce1    = (int*)(base + alloc(NN * 4));
    int*   ccsr1  = (int*)(base + alloc((size_t)E * 4));
    float* cwdg1  = (float*)(base + alloc((size_t)E * 4));
    int*   cs2    = (int*)(base + alloc(NN * 4));
    int*   ce2    = (int*)(base + alloc(NN * 4));
    int*   ccsr2  = (int*)(base + alloc((size_t)E * 4));
    float* cwdg2  = (float*)(base + alloc((size_t)E * 4));
    float* z      = (float*)(base + alloc((size_t)NG * 768 * 4));
    int*   list1  = (int*)(base + alloc((size_t)NG * 128 * 4));
    int*   list2  = (int*)(base + alloc((size_t)NG * 64 * 4));
    float* tans1  = (float*)(base + alloc((size_t)NG * 128 * 4));
    float* tans2  = (float*)(base + alloc((size_t)NG * 64 * 4));

    // CSR build + fused sort/stage-1 aggregation
    k_csr<<<NG, 256, 0, stream>>>(e_src, e_dst, EPG, rowptr, csr);
    float* xa = hW;
    k_sortagg<<<NN / 4, 256, 0, stream>>>(x, rowptr, csr, xa);

    // ---- stage 1 ----
    {
        dim3 ggrid(HDIM / BN, NN / BM);
        k_sgemm<<<ggrid, 256, 0, stream>>>(xa, conv1_W, hcur, FIN, nullptr, nullptr, conv1_b,
                                           p1_relW, p1_rootW, rrel4, rroot4);
    }
    k_topkpool<true, true, true><<<NG * 4, 256, 0, stream>>>(
        nullptr, rowptr, rowptr + 1, csr, nullptr, nullptr, rrel4, rroot4, p1_relb, 128,
        list1, tans1, hcur, z, 1.0f / 128.0f, dis, cs1, ce1, ccsr1, cwdg1, EPG);

    // ---- stage 2 ----
    {
        dim3 ggrid(HDIM / BN, (NG * 128) / BM);
        k_sgemm<<<ggrid, 256, 0, stream>>>(hcur, conv2_W, hW, HDIM, list1, tans1, nullptr,
                                           nullptr, nullptr, nullptr, nullptr);
    }
    k_gcn_agg<<<(NG * 128) / 4, 256, 0, stream>>>(hW, dis, cs1, ce1, ccsr1, cwdg1, conv2_b,
                                                  list1, 32, p2_relW, p2_rootW,
                                                  hcur, r_rel, r_root);
    k_topkpool<false, true, false><<<NG * 4, 256, 0, stream>>>(
        dis, cs1, ce1, ccsr1, r_rel, r_root, nullptr, nullptr, p2_relb, 64,
        list2, tans2, hcur, z, 1.0f / 64.0f, dis2, cs2, ce2, ccsr2, cwdg2, EPG);

    // ---- stage 3 ----
    {
        dim3 ggrid(HDIM / BN, (NG * 64) / BM);
        k_sgemm<<<ggrid, 256, 0, stream>>>(hcur, conv3_W, hW, HDIM, list2, tans2, nullptr,
                                           nullptr, nullptr, nullptr, nullptr);
    }
    k_gcn_agg<<<(NG * 64) / 4, 256, 0, stream>>>(hW, dis2, cs2, ce2, ccsr2, cwdg2, conv3_b,
                                                 list2, 16, p2_relW, p2_rootW,
                                                 hcur, r_rel, r_root);
    k_topkpool<false, false, false><<<NG * 4, 256, 0, stream>>>(
        dis2, cs2, ce2, ccsr2, r_rel, r_root, nullptr, nullptr, p2_relb, 32,
        nullptr, nullptr, hcur, z, 1.0f / 32.0f, nullptr, nullptr, nullptr, nullptr, nullptr, EPG);

    // ---- MLP ----
    k_mlp<<<NG, 256, 0, stream>>>(z, fc1_W, fc1_b, fc2_W, fc2_b, fc3_W, fc3_b, out);
}

// Round 15
// 262.095 us; speedup vs baseline: 1.2116x; 1.0111x over previous
//
#include <hip/hip_runtime.h>
#include <math.h>

#define NG 128          // graphs
#define NPG 256         // nodes per graph
#define NN 32768        // total nodes
#define HDIM 256        // hidden
#define FIN 128         // in features

// ---------------- CSR build: block per graph, LDS counting sort ----------------
__global__ __launch_bounds__(256) void k_csr(const int* __restrict__ esrc,
                                             const int* __restrict__ edst, int EPG,
                                             int* __restrict__ rowptr, int* __restrict__ csr) {
    __shared__ int cnt[NPG];
    __shared__ int cur[NPG];
    __shared__ int wtot[4];
    int g = blockIdx.x, tid = threadIdx.x;
    cnt[tid] = 0;
    __syncthreads();
    int base = g * EPG;
    for (int e = base + tid; e < base + EPG; e += 256)
        atomicAdd(&cnt[edst[e] & (NPG - 1)], 1);
    __syncthreads();
    int v = cnt[tid];
    int lane = tid & 63, w4 = tid >> 6;
    int iv = v;
    for (int off = 1; off < 64; off <<= 1) {
        int t = __shfl_up(iv, off);
        if (lane >= off) iv += t;
    }
    if (lane == 63) wtot[w4] = iv;
    __syncthreads();
    int addv = 0;
    for (int i = 0; i < w4; i++) addv += wtot[i];
    int excl = iv + addv - v;
    rowptr[g * NPG + tid] = base + excl;
    cur[tid] = base + excl;
    if (g == 0 && tid == 0) rowptr[NN] = NG * EPG;
    __syncthreads();
    for (int e = base + tid; e < base + EPG; e += 256) {
        int d = edst[e] & (NPG - 1);
        int p = atomicAdd(&cur[d], 1);
        csr[p] = esrc[e];
    }
}

// XCD-locality swizzle
__device__ __forceinline__ int swz_block(int bid, int bpg) {
    int xcd = bid & 7, r = bid >> 3;
    int graph = xcd * (NG / 8) + r / bpg;
    int sub = r - (r / bpg) * bpg;
    return graph * bpg + sub;
}

// ---------------- fused sort + stage-1 aggregation: wave per node ----------------
__global__ __launch_bounds__(256) void k_sortagg(const float* __restrict__ x,
                                                 const int* __restrict__ rowptr,
                                                 int* __restrict__ csr,
                                                 float* __restrict__ xa) {
    __shared__ int skey[4][64];
    __shared__ float swgt[4][64];
    int blk = swz_block(blockIdx.x, NPG / 4);
    int w = threadIdx.x >> 6, lane = threadIdx.x & 63;
    int n = blk * 4 + w;
    int e0 = rowptr[n];
    int d = rowptr[n + 1] - e0;
    float ddst = rsqrtf((float)(1 + d));
    bool big = d > 64;
    if (!big) {
        int key = (lane < d) ? csr[e0 + lane] : 0x7fffffff;
        int rank = 0;
        for (int j = 0; j < d; j++) {
            int kj = __shfl(key, j);
            rank += (kj < key || (kj == key && j < lane)) ? 1 : 0;
        }
        if (lane < d) {
            csr[e0 + rank] = key;
            skey[w][rank] = key;
            swgt[w][rank] = rsqrtf((float)(1 + rowptr[key + 1] - rowptr[key])) * ddst;
        }
    } else if (lane == 0) {
        for (int a = e0 + 1; a < e0 + d; a++) {
            int key = csr[a];
            int b = a - 1;
            while (b >= e0 && csr[b] > key) { csr[b + 1] = csr[b]; b--; }
            csr[b + 1] = key;
        }
    }
    __syncthreads();
    const float2* x2 = reinterpret_cast<const float2*>(x);
    float di = ddst;
    float2 h = x2[(size_t)n * (FIN / 2) + lane];
    float self = di * di;
    float ax = h.x * self, ay = h.y * self;
    if (!big) {
        for (int j = 0; j < d; j++) {
            int s = skey[w][j];
            float we = swgt[w][j];
            float2 hs = x2[(size_t)s * (FIN / 2) + lane];
            ax += hs.x * we; ay += hs.y * we;
        }
    } else {
        for (int e = e0; e < e0 + d; e++) {
            int s = csr[e];
            float we = rsqrtf((float)(1 + rowptr[s + 1] - rowptr[s])) * ddst;
            float2 hs = x2[(size_t)s * (FIN / 2) + lane];
            ax += hs.x * we; ay += hs.y * we;
        }
    }
    float2 o; o.x = ax; o.y = ay;
    reinterpret_cast<float2*>(xa)[(size_t)n * (FIN / 2) + lane] = o;
}

// ---------------- SGEMM (64x64, 4x4, pad 68, reg dbuf) ----------------
#define BM 64
#define BN 64
#define BK 16
#define BMP 68
__global__ __launch_bounds__(256) void k_sgemm(const float* __restrict__ A,
                                               const float* __restrict__ B,
                                               float* __restrict__ C, int K,
                                               const int* __restrict__ list,
                                               const float* __restrict__ tansel,
                                               const float* __restrict__ brelu,
                                               const float* __restrict__ wrel,
                                               const float* __restrict__ wroot,
                                               float* __restrict__ rrel4,
                                               float* __restrict__ rroot4) {
    const int N = HDIM;
    __shared__ float As[BK][BMP];
    __shared__ float Bs[BK][BN];
    int tid = threadIdx.x;
    int tx = tid & 15, ty = tid >> 4;
    int row0 = blockIdx.y * BM, col0 = blockIdx.x * BN;
    int lm = tid >> 2;
    int arow = list ? list[row0 + lm] : (row0 + lm);
    float tv = tansel ? tansel[row0 + lm] : 1.0f;
    int crow[4];
#pragma unroll
    for (int i = 0; i < 4; i++) {
        int r = row0 + ty * 4 + i;
        crow[i] = list ? list[r] : r;
    }
    int k4 = (tid & 3) * 4;
    int kkB = tid >> 4, cB = (tid & 15) * 4;
    float4 aP = *reinterpret_cast<const float4*>(&A[(size_t)arow * K + k4]);
    float4 bP = *reinterpret_cast<const float4*>(&B[(size_t)kkB * N + col0 + cB]);
    float acc[4][4] = {};
    for (int kb = 0; kb < K; kb += BK) {
        As[k4 + 0][lm] = aP.x * tv; As[k4 + 1][lm] = aP.y * tv;
        As[k4 + 2][lm] = aP.z * tv; As[k4 + 3][lm] = aP.w * tv;
        *reinterpret_cast<float4*>(&Bs[kkB][cB]) = bP;
        __syncthreads();
        if (kb + BK < K) {
            aP = *reinterpret_cast<const float4*>(&A[(size_t)arow * K + kb + BK + k4]);
            bP = *reinterpret_cast<const float4*>(&B[(size_t)(kb + BK + kkB) * N + col0 + cB]);
        }
#pragma unroll
        for (int k = 0; k < BK; k++) {
            float4 a = *reinterpret_cast<float4*>(&As[k][ty * 4]);
            float4 b = *reinterpret_cast<float4*>(&Bs[k][tx * 4]);
            float av[4] = {a.x, a.y, a.z, a.w};
            float bv[4] = {b.x, b.y, b.z, b.w};
#pragma unroll
            for (int i = 0; i < 4; i++)
#pragma unroll
                for (int j = 0; j < 4; j++) acc[i][j] += av[i] * bv[j];
        }
        __syncthreads();
    }
    float4 bb = make_float4(0.f, 0.f, 0.f, 0.f);
    if (brelu) bb = *reinterpret_cast<const float4*>(&brelu[col0 + tx * 4]);
    float4 wr = make_float4(0.f, 0.f, 0.f, 0.f), wo = wr;
    if (wrel) {
        wr = *reinterpret_cast<const float4*>(&wrel[col0 + tx * 4]);
        wo = *reinterpret_cast<const float4*>(&wroot[col0 + tx * 4]);
    }
#pragma unroll
    for (int i = 0; i < 4; i++) {
        float4 v = make_float4(acc[i][0], acc[i][1], acc[i][2], acc[i][3]);
        if (brelu) {
            v.x = fmaxf(v.x + bb.x, 0.f);
            v.y = fmaxf(v.y + bb.y, 0.f);
            v.z = fmaxf(v.z + bb.z, 0.f);
            v.w = fmaxf(v.w + bb.w, 0.f);
        }
        *reinterpret_cast<float4*>(&C[(size_t)crow[i] * N + col0 + tx * 4]) = v;
        if (wrel) {
            float s1 = v.x * wr.x + v.y * wr.y + v.z * wr.z + v.w * wr.w;
            float s2 = v.x * wo.x + v.y * wo.y + v.z * wo.z + v.w * wo.w;
            for (int off = 8; off > 0; off >>= 1) {
                s1 += __shfl_down(s1, off, 16);
                s2 += __shfl_down(s2, off, 16);
            }
            if (tx == 0) {
                rrel4[(size_t)crow[i] * 4 + blockIdx.x] = s1;
                rroot4[(size_t)crow[i] * 4 + blockIdx.x] = s2;
            }
        }
    }
}

// stages 2/3: wave per ACTIVE node, branch-free gather over COMPACT edge rows
__global__ __launch_bounds__(256) void k_gcn_agg(const float* __restrict__ hW,
                                                 const float* __restrict__ dis,
                                                 const int* __restrict__ rs,
                                                 const int* __restrict__ re,
                                                 const int* __restrict__ ccsr,
                                                 const float* __restrict__ cwedge,
                                                 const float* __restrict__ bias,
                                                 const int* __restrict__ list, int bpg,
                                                 const float* __restrict__ w_rel,
                                                 const float* __restrict__ w_root,
                                                 float* __restrict__ out,
                                                 float* __restrict__ r_rel,
                                                 float* __restrict__ r_root) {
    int blk = swz_block(blockIdx.x, bpg);
    int idx = blk * 4 + (threadIdx.x >> 6);
    int lane = threadIdx.x & 63;
    int wid = list[idx];
    float di = dis[wid];
    float4 h = *reinterpret_cast<const float4*>(&hW[(size_t)wid * HDIM + lane * 4]);
    float self = di * di;
    float ax = h.x * self, ay = h.y * self, az = h.z * self, aw = h.w * self;
    int e0 = rs[wid], e1 = re[wid];
    for (int e = e0; e < e1; e++) {
        float w = cwedge[e];
        int s = ccsr[e];
        float4 hs = *reinterpret_cast<const float4*>(&hW[(size_t)s * HDIM + lane * 4]);
        ax += hs.x * w; ay += hs.y * w; az += hs.z * w; aw += hs.w * w;
    }
    float4 b = *reinterpret_cast<const float4*>(&bias[lane * 4]);
    float4 o;
    o.x = fmaxf(ax + b.x, 0.f);
    o.y = fmaxf(ay + b.y, 0.f);
    o.z = fmaxf(az + b.z, 0.f);
    o.w = fmaxf(aw + b.w, 0.f);
    *reinterpret_cast<float4*>(&out[(size_t)wid * HDIM + lane * 4]) = o;
    float4 wr = *reinterpret_cast<const float4*>(&w_rel[lane * 4]);
    float4 wo = *reinterpret_cast<const float4*>(&w_root[lane * 4]);
    float s1 = o.x * wr.x + o.y * wr.y + o.z * wr.z + o.w * wr.w;
    float s2 = o.x * wo.x + o.y * wo.y + o.z * wo.z + o.w * wo.w;
    for (int off = 32; off > 0; off >>= 1) {
        s1 += __shfl_down(s1, off);
        s2 += __shfl_down(s2, off);
    }
    if (lane == 0) { r_rel[wid] = s1; r_root[wid] = s2; }
}

// ---------------- fused score + top-k + readout (+compact-CSR emit) ----------------
// grid = NG*4; 4 blocks per graph redundantly compute top-k in LDS; global side
// products (list, tansel, disN, compact CSR) written by block fc==0 only.
// Rank count via float4 LDS reads; prefix scans via 64-wide shfl (2 barriers each).
template<bool STAGE1, bool EMIT, bool FIRST>
__global__ __launch_bounds__(256) void k_topkpool(const float* __restrict__ dis,
                                                  const int* __restrict__ rs,
                                                  const int* __restrict__ re,
                                                  const int* __restrict__ csr_in,
                                                  const float* __restrict__ r_rel,
                                                  const float* __restrict__ r_root,
                                                  const float* __restrict__ rrel4,
                                                  const float* __restrict__ rroot4,
                                                  const float* __restrict__ b_rel, int k,
                                                  int* __restrict__ list,
                                                  float* __restrict__ tanselG,
                                                  const float* __restrict__ h,
                                                  float* __restrict__ z, float invk,
                                                  float* __restrict__ disN,
                                                  int* __restrict__ csN,
                                                  int* __restrict__ ceN,
                                                  int* __restrict__ ccsrN,
                                                  float* __restrict__ cwedgeN,
                                                  int EPG) {
    __shared__ float rrel[NPG];
    __shared__ __align__(16) float sc[NPG];
    __shared__ int sels[NPG];
    __shared__ float disn[NPG];
    __shared__ int newl[128];
    __shared__ float tvsel[128];
    __shared__ int wtot[4];
    __shared__ float4 red4_s[4][16];
    __shared__ float4 red4_m[4][16];
    int g = blockIdx.x >> 2, fc = blockIdx.x & 3;
    int tid = threadIdx.x;
    int lane = tid & 63, w4 = tid >> 6;
    int n = g * NPG + tid;
    bool act = STAGE1 ? true : (dis[n] > 0.f);
    float rr, ro;
    if (STAGE1) {
        float4 r4 = *reinterpret_cast<const float4*>(&rrel4[(size_t)n * 4]);
        float4 o4 = *reinterpret_cast<const float4*>(&rroot4[(size_t)n * 4]);
        rr = ((r4.x + r4.y) + r4.z) + r4.w;
        ro = ((o4.x + o4.y) + o4.z) + o4.w;
    } else {
        rr = act ? r_rel[n] : 0.f;
        ro = act ? r_root[n] : 0.f;
    }
    rrel[tid] = act ? rr : 0.f;
    __syncthreads();
    int e0 = rs[n], e1 = re[n];
    float my;
    if (act) {
        float s = b_rel[0] + ro;
        for (int e = e0; e < e1; e++) s += rrel[csr_in[e] & (NPG - 1)];
        my = s;
    } else {
        my = -INFINITY;
    }
    sc[tid] = my;
    __syncthreads();
    // rank count via float4 LDS reads (64 iters)
    int cnt = 0;
    {
        const float4* sc4 = reinterpret_cast<const float4*>(sc);
        for (int jj = 0; jj < NPG / 4; jj++) {
            float4 v = sc4[jj];
            int j0 = jj * 4;
            cnt += (v.x > my || (v.x == my && (j0 + 0) < tid)) ? 1 : 0;
            cnt += (v.y > my || (v.y == my && (j0 + 1) < tid)) ? 1 : 0;
            cnt += (v.z > my || (v.z == my && (j0 + 2) < tid)) ? 1 : 0;
            cnt += (v.w > my || (v.w == my && (j0 + 3) < tid)) ? 1 : 0;
        }
    }
    int a = (cnt < k) ? 1 : 0;
    sels[tid] = a;
    // scan1: inclusive prefix of a (shfl + cross-wave fixup)
    int incl;
    {
        int v = a;
        for (int off = 1; off < 64; off <<= 1) {
            int t = __shfl_up(v, off);
            if (lane >= off) v += t;
        }
        if (lane == 63) wtot[w4] = v;
        __syncthreads();                       // also publishes sels
        int addv = 0;
        for (int i = 0; i < w4; i++) addv += wtot[i];
        incl = v + addv;
    }
    if (a) {
        int rk = incl - 1;
        newl[rk] = tid;
        float t = tanhf(my);
        tvsel[rk] = t;
        if (fc == 0 && list) {
            list[g * k + rk] = n;
            tanselG[g * k + rk] = t;
        }
    }
    if (EMIT) {
        int deg2 = 0;
        if (a) {
            for (int e = e0; e < e1; e++) deg2 += sels[csr_in[e] & (NPG - 1)];
        }
        float dn = a ? rsqrtf((float)(1 + deg2)) : 0.f;
        disn[tid] = dn;
        if (fc == 0) disN[n] = dn;
        __syncthreads();                       // disn visible; scan1 wtot reads done
        int v = deg2;
        for (int off = 1; off < 64; off <<= 1) {
            int t = __shfl_up(v, off);
            if (lane >= off) v += t;
        }
        if (lane == 63) wtot[w4] = v;
        __syncthreads();
        if (fc == 0) {
            int addv = 0;
            for (int i = 0; i < w4; i++) addv += wtot[i];
            int start = g * EPG + (v + addv) - deg2;
            csN[n] = start;
            ceN[n] = start + deg2;
            if (a) {
                int p = start;
                for (int e = e0; e < e1; e++) {
                    int srcg = csr_in[e];
                    int j = srcg & (NPG - 1);
                    if (sels[j]) {
                        ccsrN[p] = srcg;
                        cwedgeN[p] = disn[j] * dn;
                        p++;
                    }
                }
            }
        }
    }
    __syncthreads();
    // vectorized readout: wave = 16 lanes (float4 feats) x 4 node-subs; 4 waves
    {
        int q = tid & 15, sub = (tid >> 4) & 3, y = tid >> 6;
        const float4* h4 = reinterpret_cast<const float4*>(h);
        float4 s4 = make_float4(0.f, 0.f, 0.f, 0.f);
        float4 m4 = make_float4(-INFINITY, -INFINITY, -INFINITY, -INFINITY);
        for (int idx = y * 4 + sub; idx < k; idx += 16) {
            int node = g * NPG + newl[idx];
            float t = tvsel[idx];
            float4 v = h4[(size_t)node * (HDIM / 4) + fc * 16 + q];
            v.x *= t; v.y *= t; v.z *= t; v.w *= t;
            s4.x += v.x; s4.y += v.y; s4.z += v.z; s4.w += v.w;
            m4.x = fmaxf(m4.x, v.x); m4.y = fmaxf(m4.y, v.y);
            m4.z = fmaxf(m4.z, v.z); m4.w = fmaxf(m4.w, v.w);
        }
#pragma unroll
        for (int off = 16; off <= 32; off <<= 1) {
            s4.x += __shfl_down(s4.x, off); s4.y += __shfl_down(s4.y, off);
            s4.z += __shfl_down(s4.z, off); s4.w += __shfl_down(s4.w, off);
            m4.x = fmaxf(m4.x, __shfl_down(m4.x, off));
            m4.y = fmaxf(m4.y, __shfl_down(m4.y, off));
            m4.z = fmaxf(m4.z, __shfl_down(m4.z, off));
            m4.w = fmaxf(m4.w, __shfl_down(m4.w, off));
        }
        if (sub == 0) { red4_s[y][q] = s4; red4_m[y][q] = m4; }
        __syncthreads();
        if (tid < 16) {
            float4 a0 = red4_s[0][tid], a1 = red4_s[1][tid];
            float4 a2 = red4_s[2][tid], a3 = red4_s[3][tid];
            float4 S;
            S.x = ((a0.x + a1.x) + a2.x) + a3.x;
            S.y = ((a0.y + a1.y) + a2.y) + a3.y;
            S.z = ((a0.z + a1.z) + a2.z) + a3.z;
            S.w = ((a0.w + a1.w) + a2.w) + a3.w;
            float4 b0 = red4_m[0][tid], b1 = red4_m[1][tid];
            float4 b2 = red4_m[2][tid], b3 = red4_m[3][tid];
            float4 M;
            M.x = fmaxf(fmaxf(b0.x, b1.x), fmaxf(b2.x, b3.x));
            M.y = fmaxf(fmaxf(b0.y, b1.y), fmaxf(b2.y, b3.y));
            M.z = fmaxf(fmaxf(b0.z, b1.z), fmaxf(b2.z, b3.z));
            M.w = fmaxf(fmaxf(b0.w, b1.w), fmaxf(b2.w, b3.w));
            float4 Mean = make_float4(S.x * invk, S.y * invk, S.z * invk, S.w * invk);
            float4* z4 = reinterpret_cast<float4*>(z);
            int zb_ = (g * 768 + fc * 64) / 4 + tid;
            if (FIRST) {
                z4[zb_] = Mean;
                z4[zb_ + 64] = M;
                z4[zb_ + 128] = S;
            } else {
                float4 c0 = z4[zb_], c1 = z4[zb_ + 64], c2 = z4[zb_ + 128];
                c0.x += Mean.x; c0.y += Mean.y; c0.z += Mean.z; c0.w += Mean.w;
                c1.x += M.x; c1.y += M.y; c1.z += M.z; c1.w += M.w;
                c2.x += S.x; c2.y += S.y; c2.z += S.z; c2.w += S.w;
                z4[zb_] = c0;
                z4[zb_ + 64] = c1;
                z4[zb_ + 128] = c2;
            }
        }
    }
}

// ---------------- fused MLP (partial-sum groupings fixed) ----------------
__global__ __launch_bounds__(256) void k_mlp(const float* __restrict__ z,
                                             const float* __restrict__ W1, const float* __restrict__ b1,
                                             const float* __restrict__ W2, const float* __restrict__ b2,
                                             const float* __restrict__ W3, const float* __restrict__ b3,
                                             float* __restrict__ out) {
    __shared__ float zb[768];
    __shared__ float t1[256];
    __shared__ float t2[128];
    __shared__ float t3[10];
    __shared__ float lse;
    int g = blockIdx.x, tid = threadIdx.x;
    zb[tid] = z[g * 768 + tid];
    zb[tid + 256] = z[g * 768 + 256 + tid];
    zb[tid + 512] = z[g * 768 + 512 + tid];
    __syncthreads();
    {
        int col = tid;
        float r0 = 0.f, r1 = 0.f, r2 = 0.f, r3 = 0.f;
        for (int i = 0;   i < 192; i++) r0 += zb[i] * W1[(size_t)i * 256 + col];
        for (int i = 192; i < 384; i++) r1 += zb[i] * W1[(size_t)i * 256 + col];
        for (int i = 384; i < 576; i++) r2 += zb[i] * W1[(size_t)i * 256 + col];
        for (int i = 576; i < 768; i++) r3 += zb[i] * W1[(size_t)i * 256 + col];
        t1[col] = fmaxf(r0 + r1 + r2 + r3 + b1[col], 0.f);
    }
    __syncthreads();
    if (tid < 128) {
        int col = tid;
        float r0 = 0.f, r1 = 0.f, r2 = 0.f, r3 = 0.f;
        for (int i = 0;   i < 64;  i++) r0 += t1[i] * W2[(size_t)i * 128 + col];
        for (int i = 64;  i < 128; i++) r1 += t1[i] * W2[(size_t)i * 128 + col];
        for (int i = 128; i < 192; i++) r2 += t1[i] * W2[(size_t)i * 128 + col];
        for (int i = 192; i < 256; i++) r3 += t1[i] * W2[(size_t)i * 128 + col];
        t2[col] = fmaxf(((r0 + r1) + r2) + r3 + b2[col], 0.f);
    }
    __syncthreads();
    if (tid < 10) {
        float v = b3[tid];
        for (int i = 0; i < 128; i++) v += t2[i] * W3[(size_t)i * 10 + tid];
        t3[tid] = v;
    }
    __syncthreads();
    if (tid == 0) {
        float m = t3[0];
        for (int c = 1; c < 10; c++) m = fmaxf(m, t3[c]);
        float se = 0.f;
        for (int c = 0; c < 10; c++) se += expf(t3[c] - m);
        lse = m + logf(se);
    }
    __syncthreads();
    if (tid < 10) out[g * 10 + tid] = t3[tid] - lse;
}

// ---------------- launcher ----------------
extern "C" void kernel_launch(void* const* d_in, const int* in_sizes, int n_in,
                              void* d_out, int out_size, void* d_ws, size_t ws_size,
                              hipStream_t stream) {
    const float* x        = (const float*)d_in[0];
    const int*   ei       = (const int*)d_in[1];
    const float* conv1_W  = (const float*)d_in[3];
    const float* conv1_b  = (const float*)d_in[4];
    const float* conv2_W  = (const float*)d_in[5];
    const float* conv2_b  = (const float*)d_in[6];
    const float* conv3_W  = (const float*)d_in[7];
    const float* conv3_b  = (const float*)d_in[8];
    const float* p1_relW  = (const float*)d_in[9];
    const float* p1_relb  = (const float*)d_in[10];
    const float* p1_rootW = (const float*)d_in[11];
    const float* p2_relW  = (const float*)d_in[12];
    const float* p2_relb  = (const float*)d_in[13];
    const float* p2_rootW = (const float*)d_in[14];
    const float* fc1_W    = (const float*)d_in[15];
    const float* fc1_b    = (const float*)d_in[16];
    const float* fc2_W    = (const float*)d_in[17];
    const float* fc2_b    = (const float*)d_in[18];
    const float* fc3_W    = (const float*)d_in[19];
    const float* fc3_b    = (const float*)d_in[20];
    float* out = (float*)d_out;

    const int E = in_sizes[1] / 2;
    const int EPG = E / NG;
    const int* e_src = ei;
    const int* e_dst = ei + E;

    // workspace layout
    char* base = (char*)d_ws;
    size_t off = 0;
    auto alloc = [&](size_t bytes) { size_t o = off; off = (off + bytes + 255) & ~(size_t)255; return o; };
    float* hW     = (float*)(base + alloc((size_t)NN * HDIM * 4));   // also xa (NN x FIN)
    float* hcur   = (float*)(base + alloc((size_t)NN * HDIM * 4));
    float* dis    = (float*)(base + alloc(NN * 4));   // stage-2 dis
    float* dis2   = (float*)(base + alloc(NN * 4));   // stage-3 dis
    float* r_rel  = (float*)(base + alloc(NN * 4));
    float* r_root = (float*)(base + alloc(NN * 4));
    float* rrel4  = (float*)(base + alloc((size_t)NN * 4 * 4));
    float* rroot4 = (float*)(base + alloc((size_t)NN * 4 * 4));
    int*   rowptr = (int*)(base + alloc((NN + 1) * 4));
    int*   csr    = (int*)(base + alloc((size_t)E * 4));
    int*   cs1    = (int*)(base + alloc(NN * 4));
    int*   ce1    = (int*)(base + alloc(NN * 4));
    int*   ccsr1  = (int*)(base + alloc((size_t)E * 4));
    float* cwdg1  = (float*)(base + alloc((size_t)E * 4));
    int*   cs2    = (int*)(base + alloc(NN * 4));
    int*   ce2    = (int*)(base + alloc(NN * 4));
    int*   ccsr2  = (int*)(base + alloc((size_t)E * 4));
    float* cwdg2  = (float*)(base + alloc((size_t)E * 4));
    float* z      = (float*)(base + alloc((size_t)NG * 768 * 4));
    int*   list1  = (int*)(base + alloc((size_t)NG * 128 * 4));
    int*   list2  = (int*)(base + alloc((size_t)NG * 64 * 4));
    float* tans1  = (float*)(base + alloc((size_t)NG * 128 * 4));
    float* tans2  = (float*)(base + alloc((size_t)NG * 64 * 4));

    // CSR build + fused sort/stage-1 aggregation
    k_csr<<<NG, 256, 0, stream>>>(e_src, e_dst, EPG, rowptr, csr);
    float* xa = hW;
    k_sortagg<<<NN / 4, 256, 0, stream>>>(x, rowptr, csr, xa);

    // ---- stage 1 ----
    {
        dim3 ggrid(HDIM / BN, NN / BM);
        k_sgemm<<<ggrid, 256, 0, stream>>>(xa, conv1_W, hcur, FIN, nullptr, nullptr, conv1_b,
                                           p1_relW, p1_rootW, rrel4, rroot4);
    }
    k_topkpool<true, true, true><<<NG * 4, 256, 0, stream>>>(
        nullptr, rowptr, rowptr + 1, csr, nullptr, nullptr, rrel4, rroot4, p1_relb, 128,
        list1, tans1, hcur, z, 1.0f / 128.0f, dis, cs1, ce1, ccsr1, cwdg1, EPG);

    // ---- stage 2 ----
    {
        dim3 ggrid(HDIM / BN, (NG * 128) / BM);
        k_sgemm<<<ggrid, 256, 0, stream>>>(hcur, conv2_W, hW, HDIM, list1, tans1, nullptr,
                                           nullptr, nullptr, nullptr, nullptr);
    }
    k_gcn_agg<<<(NG * 128) / 4, 256, 0, stream>>>(hW, dis, cs1, ce1, ccsr1, cwdg1, conv2_b,
                                                  list1, 32, p2_relW, p2_rootW,
                                                  hcur, r_rel, r_root);
    k_topkpool<false, true, false><<<NG * 4, 256, 0, stream>>>(
        dis, cs1, ce1, ccsr1, r_rel, r_root, nullptr, nullptr, p2_relb, 64,
        list2, tans2, hcur, z, 1.0f / 64.0f, dis2, cs2, ce2, ccsr2, cwdg2, EPG);

    // ---- stage 3 ----
    {
        dim3 ggrid(HDIM / BN, (NG * 64) / BM);
        k_sgemm<<<ggrid, 256, 0, stream>>>(hcur, conv3_W, hW, HDIM, list2, tans2, nullptr,
                                           nullptr, nullptr, nullptr, nullptr);
    }
    k_gcn_agg<<<(NG * 64) / 4, 256, 0, stream>>>(hW, dis2, cs2, ce2, ccsr2, cwdg2, conv3_b,
                                                 list2, 16, p2_relW, p2_rootW,
                                                 hcur, r_rel, r_root);
    k_topkpool<false, false, false><<<NG * 4, 256, 0, stream>>>(
        dis2, cs2, ce2, ccsr2, r_rel, r_root, nullptr, nullptr, p2_relb, 32,
        nullptr, nullptr, hcur, z, 1.0f / 32.0f, nullptr, nullptr, nullptr, nullptr, nullptr, EPG);

    // ---- MLP ----
    k_mlp<<<NG, 256, 0, stream>>>(z, fc1_W, fc1_b, fc2_W, fc2_b, fc3_W, fc3_b, out);
}

// Round 16
// 259.403 us; speedup vs baseline: 1.2242x; 1.0104x over previous
//
#include <hip/hip_runtime.h>
#include <math.h>

#define NG 128          // graphs
#define NPG 256         // nodes per graph
#define NN 32768        // total nodes
#define HDIM 256        // hidden
#define FIN 128         // in features

// ---------------- CSR build: block per graph, LDS counting sort ----------------
__global__ __launch_bounds__(256) void k_csr(const int* __restrict__ esrc,
                                             const int* __restrict__ edst, int EPG,
                                             int* __restrict__ rowptr, int* __restrict__ csr) {
    __shared__ int cnt[NPG];
    __shared__ int cur[NPG];
    __shared__ int wtot[4];
    int g = blockIdx.x, tid = threadIdx.x;
    cnt[tid] = 0;
    __syncthreads();
    int base = g * EPG;
    for (int e = base + tid; e < base + EPG; e += 256)
        atomicAdd(&cnt[edst[e] & (NPG - 1)], 1);
    __syncthreads();
    int v = cnt[tid];
    int lane = tid & 63, w4 = tid >> 6;
    int iv = v;
    for (int off = 1; off < 64; off <<= 1) {
        int t = __shfl_up(iv, off);
        if (lane >= off) iv += t;
    }
    if (lane == 63) wtot[w4] = iv;
    __syncthreads();
    int addv = 0;
    for (int i = 0; i < w4; i++) addv += wtot[i];
    int excl = iv + addv - v;
    rowptr[g * NPG + tid] = base + excl;
    cur[tid] = base + excl;
    if (g == 0 && tid == 0) rowptr[NN] = NG * EPG;
    __syncthreads();
    for (int e = base + tid; e < base + EPG; e += 256) {
        int d = edst[e] & (NPG - 1);
        int p = atomicAdd(&cur[d], 1);
        csr[p] = esrc[e];
    }
}

// XCD-locality swizzle
__device__ __forceinline__ int swz_block(int bid, int bpg) {
    int xcd = bid & 7, r = bid >> 3;
    int graph = xcd * (NG / 8) + r / bpg;
    int sub = r - (r / bpg) * bpg;
    return graph * bpg + sub;
}

// ---------------- fused sort + stage-1 aggregation: wave per node ----------------
__global__ __launch_bounds__(256) void k_sortagg(const float* __restrict__ x,
                                                 const int* __restrict__ rowptr,
                                                 int* __restrict__ csr,
                                                 float* __restrict__ xa) {
    __shared__ int skey[4][64];
    __shared__ float swgt[4][64];
    int blk = swz_block(blockIdx.x, NPG / 4);
    int w = threadIdx.x >> 6, lane = threadIdx.x & 63;
    int n = blk * 4 + w;
    int e0 = rowptr[n];
    int d = rowptr[n + 1] - e0;
    float ddst = rsqrtf((float)(1 + d));
    bool big = d > 64;
    if (!big) {
        int key = (lane < d) ? csr[e0 + lane] : 0x7fffffff;
        int rank = 0;
        for (int j = 0; j < d; j++) {
            int kj = __shfl(key, j);
            rank += (kj < key || (kj == key && j < lane)) ? 1 : 0;
        }
        if (lane < d) {
            csr[e0 + rank] = key;
            skey[w][rank] = key;
            swgt[w][rank] = rsqrtf((float)(1 + rowptr[key + 1] - rowptr[key])) * ddst;
        }
    } else if (lane == 0) {
        for (int a = e0 + 1; a < e0 + d; a++) {
            int key = csr[a];
            int b = a - 1;
            while (b >= e0 && csr[b] > key) { csr[b + 1] = csr[b]; b--; }
            csr[b + 1] = key;
        }
    }
    __syncthreads();
    const float2* x2 = reinterpret_cast<const float2*>(x);
    float di = ddst;
    float2 h = x2[(size_t)n * (FIN / 2) + lane];
    float self = di * di;
    float ax = h.x * self, ay = h.y * self;
    if (!big) {
        for (int j = 0; j < d; j++) {
            int s = skey[w][j];
            float we = swgt[w][j];
            float2 hs = x2[(size_t)s * (FIN / 2) + lane];
            ax += hs.x * we; ay += hs.y * we;
        }
    } else {
        for (int e = e0; e < e0 + d; e++) {
            int s = csr[e];
            float we = rsqrtf((float)(1 + rowptr[s + 1] - rowptr[s])) * ddst;
            float2 hs = x2[(size_t)s * (FIN / 2) + lane];
            ax += hs.x * we; ay += hs.y * we;
        }
    }
    float2 o; o.x = ax; o.y = ay;
    reinterpret_cast<float2*>(xa)[(size_t)n * (FIN / 2) + lane] = o;
}

// ---------------- SGEMM (64x64, 4x4, pad 68, reg dbuf) — stages 2/3 ----------------
#define BM 64
#define BN 64
#define BK 16
#define BMP 68
__global__ __launch_bounds__(256) void k_sgemm(const float* __restrict__ A,
                                               const float* __restrict__ B,
                                               float* __restrict__ C, int K,
                                               const int* __restrict__ list,
                                               const float* __restrict__ tansel,
                                               const float* __restrict__ brelu,
                                               const float* __restrict__ wrel,
                                               const float* __restrict__ wroot,
                                               float* __restrict__ rrel4,
                                               float* __restrict__ rroot4) {
    const int N = HDIM;
    __shared__ float As[BK][BMP];
    __shared__ float Bs[BK][BN];
    int tid = threadIdx.x;
    int tx = tid & 15, ty = tid >> 4;
    int row0 = blockIdx.y * BM, col0 = blockIdx.x * BN;
    int lm = tid >> 2;
    int arow = list ? list[row0 + lm] : (row0 + lm);
    float tv = tansel ? tansel[row0 + lm] : 1.0f;
    int crow[4];
#pragma unroll
    for (int i = 0; i < 4; i++) {
        int r = row0 + ty * 4 + i;
        crow[i] = list ? list[r] : r;
    }
    int k4 = (tid & 3) * 4;
    int kkB = tid >> 4, cB = (tid & 15) * 4;
    float4 aP = *reinterpret_cast<const float4*>(&A[(size_t)arow * K + k4]);
    float4 bP = *reinterpret_cast<const float4*>(&B[(size_t)kkB * N + col0 + cB]);
    float acc[4][4] = {};
    for (int kb = 0; kb < K; kb += BK) {
        As[k4 + 0][lm] = aP.x * tv; As[k4 + 1][lm] = aP.y * tv;
        As[k4 + 2][lm] = aP.z * tv; As[k4 + 3][lm] = aP.w * tv;
        *reinterpret_cast<float4*>(&Bs[kkB][cB]) = bP;
        __syncthreads();
        if (kb + BK < K) {
            aP = *reinterpret_cast<const float4*>(&A[(size_t)arow * K + kb + BK + k4]);
            bP = *reinterpret_cast<const float4*>(&B[(size_t)(kb + BK + kkB) * N + col0 + cB]);
        }
#pragma unroll
        for (int k = 0; k < BK; k++) {
            float4 a = *reinterpret_cast<float4*>(&As[k][ty * 4]);
            float4 b = *reinterpret_cast<float4*>(&Bs[k][tx * 4]);
            float av[4] = {a.x, a.y, a.z, a.w};
            float bv[4] = {b.x, b.y, b.z, b.w};
#pragma unroll
            for (int i = 0; i < 4; i++)
#pragma unroll
                for (int j = 0; j < 4; j++) acc[i][j] += av[i] * bv[j];
        }
        __syncthreads();
    }
    float4 bb = make_float4(0.f, 0.f, 0.f, 0.f);
    if (brelu) bb = *reinterpret_cast<const float4*>(&brelu[col0 + tx * 4]);
    float4 wr = make_float4(0.f, 0.f, 0.f, 0.f), wo = wr;
    if (wrel) {
        wr = *reinterpret_cast<const float4*>(&wrel[col0 + tx * 4]);
        wo = *reinterpret_cast<const float4*>(&wroot[col0 + tx * 4]);
    }
#pragma unroll
    for (int i = 0; i < 4; i++) {
        float4 v = make_float4(acc[i][0], acc[i][1], acc[i][2], acc[i][3]);
        if (brelu) {
            v.x = fmaxf(v.x + bb.x, 0.f);
            v.y = fmaxf(v.y + bb.y, 0.f);
            v.z = fmaxf(v.z + bb.z, 0.f);
            v.w = fmaxf(v.w + bb.w, 0.f);
        }
        *reinterpret_cast<float4*>(&C[(size_t)crow[i] * N + col0 + tx * 4]) = v;
        if (wrel) {
            float s1 = v.x * wr.x + v.y * wr.y + v.z * wr.z + v.w * wr.w;
            float s2 = v.x * wo.x + v.y * wo.y + v.z * wo.z + v.w * wo.w;
            for (int off = 8; off > 0; off >>= 1) {
                s1 += __shfl_down(s1, off, 16);
                s2 += __shfl_down(s2, off, 16);
            }
            if (tx == 0) {
                rrel4[(size_t)crow[i] * 4 + blockIdx.x] = s1;
                rroot4[(size_t)crow[i] * 4 + blockIdx.x] = s2;
            }
        }
    }
}

// ---------------- stage-1 SGEMM: dual N-tile (64x128), 4x8 micro-tile ----------------
// Same A staging/BM as proven kernel; B tile doubled. Per-64-col-block epilogue
// groupings identical to k_sgemm => C and rrel4/rroot4 bit-identical.
__global__ __launch_bounds__(256) void k_sgemm2(const float* __restrict__ A,
                                                const float* __restrict__ B,
                                                float* __restrict__ C, int K,
                                                const float* __restrict__ brelu,
                                                const float* __restrict__ wrel,
                                                const float* __restrict__ wroot,
                                                float* __restrict__ rrel4,
                                                float* __restrict__ rroot4) {
    const int N = HDIM;
    __shared__ float As[BK][BMP];
    __shared__ float Bs[BK][128];
    int tid = threadIdx.x;
    int tx = tid & 15, ty = tid >> 4;
    int row0 = blockIdx.y * BM, col0 = blockIdx.x * 128;
    int lm = tid >> 2;
    int arow = row0 + lm;
    int k4 = (tid & 3) * 4;
    int kkB0 = tid >> 5, cB0 = (tid & 31) * 4;          // rep 0
    int kkB1 = (256 + tid) >> 5, cB1 = cB0;             // rep 1 (idx&31 same)
    float4 aP = *reinterpret_cast<const float4*>(&A[(size_t)arow * K + k4]);
    float4 bP0 = *reinterpret_cast<const float4*>(&B[(size_t)kkB0 * N + col0 + cB0]);
    float4 bP1 = *reinterpret_cast<const float4*>(&B[(size_t)kkB1 * N + col0 + cB1]);
    float acc0[4][4] = {};
    float acc1[4][4] = {};
    for (int kb = 0; kb < K; kb += BK) {
        As[k4 + 0][lm] = aP.x; As[k4 + 1][lm] = aP.y;
        As[k4 + 2][lm] = aP.z; As[k4 + 3][lm] = aP.w;
        *reinterpret_cast<float4*>(&Bs[kkB0][cB0]) = bP0;
        *reinterpret_cast<float4*>(&Bs[kkB1][cB1]) = bP1;
        __syncthreads();
        if (kb + BK < K) {
            aP = *reinterpret_cast<const float4*>(&A[(size_t)arow * K + kb + BK + k4]);
            bP0 = *reinterpret_cast<const float4*>(&B[(size_t)(kb + BK + kkB0) * N + col0 + cB0]);
            bP1 = *reinterpret_cast<const float4*>(&B[(size_t)(kb + BK + kkB1) * N + col0 + cB1]);
        }
#pragma unroll
        for (int k = 0; k < BK; k++) {
            float4 a = *reinterpret_cast<float4*>(&As[k][ty * 4]);
            float4 b0 = *reinterpret_cast<float4*>(&Bs[k][tx * 4]);
            float4 b1 = *reinterpret_cast<float4*>(&Bs[k][64 + tx * 4]);
            float av[4] = {a.x, a.y, a.z, a.w};
            float bv0[4] = {b0.x, b0.y, b0.z, b0.w};
            float bv1[4] = {b1.x, b1.y, b1.z, b1.w};
#pragma unroll
            for (int i = 0; i < 4; i++) {
#pragma unroll
                for (int j = 0; j < 4; j++) {
                    acc0[i][j] += av[i] * bv0[j];
                    acc1[i][j] += av[i] * bv1[j];
                }
            }
        }
        __syncthreads();
    }
#pragma unroll
    for (int half = 0; half < 2; half++) {
        int cbase = col0 + half * 64;
        float (*acc)[4] = half ? acc1 : acc0;
        float4 bb = *reinterpret_cast<const float4*>(&brelu[cbase + tx * 4]);
        float4 wr = *reinterpret_cast<const float4*>(&wrel[cbase + tx * 4]);
        float4 wo = *reinterpret_cast<const float4*>(&wroot[cbase + tx * 4]);
        int cb = blockIdx.x * 2 + half;
#pragma unroll
        for (int i = 0; i < 4; i++) {
            int crow = row0 + ty * 4 + i;
            float4 v = make_float4(acc[i][0], acc[i][1], acc[i][2], acc[i][3]);
            v.x = fmaxf(v.x + bb.x, 0.f);
            v.y = fmaxf(v.y + bb.y, 0.f);
            v.z = fmaxf(v.z + bb.z, 0.f);
            v.w = fmaxf(v.w + bb.w, 0.f);
            *reinterpret_cast<float4*>(&C[(size_t)crow * N + cbase + tx * 4]) = v;
            float s1 = v.x * wr.x + v.y * wr.y + v.z * wr.z + v.w * wr.w;
            float s2 = v.x * wo.x + v.y * wo.y + v.z * wo.z + v.w * wo.w;
            for (int off = 8; off > 0; off >>= 1) {
                s1 += __shfl_down(s1, off, 16);
                s2 += __shfl_down(s2, off, 16);
            }
            if (tx == 0) {
                rrel4[(size_t)crow * 4 + cb] = s1;
                rroot4[(size_t)crow * 4 + cb] = s2;
            }
        }
    }
}

// stages 2/3: wave per ACTIVE node, branch-free gather over COMPACT edge rows
__global__ __launch_bounds__(256) void k_gcn_agg(const float* __restrict__ hW,
                                                 const float* __restrict__ dis,
                                                 const int* __restrict__ rs,
                                                 const int* __restrict__ re,
                                                 const int* __restrict__ ccsr,
                                                 const float* __restrict__ cwedge,
                                                 const float* __restrict__ bias,
                                                 const int* __restrict__ list, int bpg,
                                                 const float* __restrict__ w_rel,
                                                 const float* __restrict__ w_root,
                                                 float* __restrict__ out,
                                                 float* __restrict__ r_rel,
                                                 float* __restrict__ r_root) {
    int blk = swz_block(blockIdx.x, bpg);
    int idx = blk * 4 + (threadIdx.x >> 6);
    int lane = threadIdx.x & 63;
    int wid = list[idx];
    float di = dis[wid];
    float4 h = *reinterpret_cast<const float4*>(&hW[(size_t)wid * HDIM + lane * 4]);
    float self = di * di;
    float ax = h.x * self, ay = h.y * self, az = h.z * self, aw = h.w * self;
    int e0 = rs[wid], e1 = re[wid];
    for (int e = e0; e < e1; e++) {
        float w = cwedge[e];
        int s = ccsr[e];
        float4 hs = *reinterpret_cast<const float4*>(&hW[(size_t)s * HDIM + lane * 4]);
        ax += hs.x * w; ay += hs.y * w; az += hs.z * w; aw += hs.w * w;
    }
    float4 b = *reinterpret_cast<const float4*>(&bias[lane * 4]);
    float4 o;
    o.x = fmaxf(ax + b.x, 0.f);
    o.y = fmaxf(ay + b.y, 0.f);
    o.z = fmaxf(az + b.z, 0.f);
    o.w = fmaxf(aw + b.w, 0.f);
    *reinterpret_cast<float4*>(&out[(size_t)wid * HDIM + lane * 4]) = o;
    float4 wr = *reinterpret_cast<const float4*>(&w_rel[lane * 4]);
    float4 wo = *reinterpret_cast<const float4*>(&w_root[lane * 4]);
    float s1 = o.x * wr.x + o.y * wr.y + o.z * wr.z + o.w * wr.w;
    float s2 = o.x * wo.x + o.y * wo.y + o.z * wo.z + o.w * wo.w;
    for (int off = 32; off > 0; off >>= 1) {
        s1 += __shfl_down(s1, off);
        s2 += __shfl_down(s2, off);
    }
    if (lane == 0) { r_rel[wid] = s1; r_root[wid] = s2; }
}

// ---------------- fused score + top-k + readout (+compact-CSR emit) ----------------
template<bool STAGE1, bool EMIT, bool FIRST>
__global__ __launch_bounds__(256) void k_topkpool(const float* __restrict__ dis,
                                                  const int* __restrict__ rs,
                                                  const int* __restrict__ re,
                                                  const int* __restrict__ csr_in,
                                                  const float* __restrict__ r_rel,
                                                  const float* __restrict__ r_root,
                                                  const float* __restrict__ rrel4,
                                                  const float* __restrict__ rroot4,
                                                  const float* __restrict__ b_rel, int k,
                                                  int* __restrict__ list,
                                                  float* __restrict__ tanselG,
                                                  const float* __restrict__ h,
                                                  float* __restrict__ z, float invk,
                                                  float* __restrict__ disN,
                                                  int* __restrict__ csN,
                                                  int* __restrict__ ceN,
                                                  int* __restrict__ ccsrN,
                                                  float* __restrict__ cwedgeN,
                                                  int EPG) {
    __shared__ float rrel[NPG];
    __shared__ __align__(16) float sc[NPG];
    __shared__ int sels[NPG];
    __shared__ float disn[NPG];
    __shared__ int newl[128];
    __shared__ float tvsel[128];
    __shared__ int wtot[4];
    __shared__ float4 red4_s[4][16];
    __shared__ float4 red4_m[4][16];
    int g = blockIdx.x >> 2, fc = blockIdx.x & 3;
    int tid = threadIdx.x;
    int lane = tid & 63, w4 = tid >> 6;
    int n = g * NPG + tid;
    bool act = STAGE1 ? true : (dis[n] > 0.f);
    float rr, ro;
    if (STAGE1) {
        float4 r4 = *reinterpret_cast<const float4*>(&rrel4[(size_t)n * 4]);
        float4 o4 = *reinterpret_cast<const float4*>(&rroot4[(size_t)n * 4]);
        rr = ((r4.x + r4.y) + r4.z) + r4.w;
        ro = ((o4.x + o4.y) + o4.z) + o4.w;
    } else {
        rr = act ? r_rel[n] : 0.f;
        ro = act ? r_root[n] : 0.f;
    }
    rrel[tid] = act ? rr : 0.f;
    __syncthreads();
    int e0 = rs[n], e1 = re[n];
    float my;
    if (act) {
        float s = b_rel[0] + ro;
        for (int e = e0; e < e1; e++) s += rrel[csr_in[e] & (NPG - 1)];
        my = s;
    } else {
        my = -INFINITY;
    }
    sc[tid] = my;
    __syncthreads();
    int cnt = 0;
    {
        const float4* sc4 = reinterpret_cast<const float4*>(sc);
        for (int jj = 0; jj < NPG / 4; jj++) {
            float4 v = sc4[jj];
            int j0 = jj * 4;
            cnt += (v.x > my || (v.x == my && (j0 + 0) < tid)) ? 1 : 0;
            cnt += (v.y > my || (v.y == my && (j0 + 1) < tid)) ? 1 : 0;
            cnt += (v.z > my || (v.z == my && (j0 + 2) < tid)) ? 1 : 0;
            cnt += (v.w > my || (v.w == my && (j0 + 3) < tid)) ? 1 : 0;
        }
    }
    int a = (cnt < k) ? 1 : 0;
    sels[tid] = a;
    int incl;
    {
        int v = a;
        for (int off = 1; off < 64; off <<= 1) {
            int t = __shfl_up(v, off);
            if (lane >= off) v += t;
        }
        if (lane == 63) wtot[w4] = v;
        __syncthreads();
        int addv = 0;
        for (int i = 0; i < w4; i++) addv += wtot[i];
        incl = v + addv;
    }
    if (a) {
        int rk = incl - 1;
        newl[rk] = tid;
        float t = tanhf(my);
        tvsel[rk] = t;
        if (fc == 0 && list) {
            list[g * k + rk] = n;
            tanselG[g * k + rk] = t;
        }
    }
    if (EMIT) {
        int deg2 = 0;
        if (a) {
            for (int e = e0; e < e1; e++) deg2 += sels[csr_in[e] & (NPG - 1)];
        }
        float dn = a ? rsqrtf((float)(1 + deg2)) : 0.f;
        disn[tid] = dn;
        if (fc == 0) disN[n] = dn;
        __syncthreads();
        int v = deg2;
        for (int off = 1; off < 64; off <<= 1) {
            int t = __shfl_up(v, off);
            if (lane >= off) v += t;
        }
        if (lane == 63) wtot[w4] = v;
        __syncthreads();
        if (fc == 0) {
            int addv = 0;
            for (int i = 0; i < w4; i++) addv += wtot[i];
            int start = g * EPG + (v + addv) - deg2;
            csN[n] = start;
            ceN[n] = start + deg2;
            if (a) {
                int p = start;
                for (int e = e0; e < e1; e++) {
                    int srcg = csr_in[e];
                    int j = srcg & (NPG - 1);
                    if (sels[j]) {
                        ccsrN[p] = srcg;
                        cwedgeN[p] = disn[j] * dn;
                        p++;
                    }
                }
            }
        }
    }
    __syncthreads();
    {
        int q = tid & 15, sub = (tid >> 4) & 3, y = tid >> 6;
        const float4* h4 = reinterpret_cast<const float4*>(h);
        float4 s4 = make_float4(0.f, 0.f, 0.f, 0.f);
        float4 m4 = make_float4(-INFINITY, -INFINITY, -INFINITY, -INFINITY);
        for (int idx = y * 4 + sub; idx < k; idx += 16) {
            int node = g * NPG + newl[idx];
            float t = tvsel[idx];
            float4 v = h4[(size_t)node * (HDIM / 4) + fc * 16 + q];
            v.x *= t; v.y *= t; v.z *= t; v.w *= t;
            s4.x += v.x; s4.y += v.y; s4.z += v.z; s4.w += v.w;
            m4.x = fmaxf(m4.x, v.x); m4.y = fmaxf(m4.y, v.y);
            m4.z = fmaxf(m4.z, v.z); m4.w = fmaxf(m4.w, v.w);
        }
#pragma unroll
        for (int off = 16; off <= 32; off <<= 1) {
            s4.x += __shfl_down(s4.x, off); s4.y += __shfl_down(s4.y, off);
            s4.z += __shfl_down(s4.z, off); s4.w += __shfl_down(s4.w, off);
            m4.x = fmaxf(m4.x, __shfl_down(m4.x, off));
            m4.y = fmaxf(m4.y, __shfl_down(m4.y, off));
            m4.z = fmaxf(m4.z, __shfl_down(m4.z, off));
            m4.w = fmaxf(m4.w, __shfl_down(m4.w, off));
        }
        if (sub == 0) { red4_s[y][q] = s4; red4_m[y][q] = m4; }
        __syncthreads();
        if (tid < 16) {
            float4 a0 = red4_s[0][tid], a1 = red4_s[1][tid];
            float4 a2 = red4_s[2][tid], a3 = red4_s[3][tid];
            float4 S;
            S.x = ((a0.x + a1.x) + a2.x) + a3.x;
            S.y = ((a0.y + a1.y) + a2.y) + a3.y;
            S.z = ((a0.z + a1.z) + a2.z) + a3.z;
            S.w = ((a0.w + a1.w) + a2.w) + a3.w;
            float4 b0 = red4_m[0][tid], b1 = red4_m[1][tid];
            float4 b2 = red4_m[2][tid], b3 = red4_m[3][tid];
            float4 M;
            M.x = fmaxf(fmaxf(b0.x, b1.x), fmaxf(b2.x, b3.x));
            M.y = fmaxf(fmaxf(b0.y, b1.y), fmaxf(b2.y, b3.y));
            M.z = fmaxf(fmaxf(b0.z, b1.z), fmaxf(b2.z, b3.z));
            M.w = fmaxf(fmaxf(b0.w, b1.w), fmaxf(b2.w, b3.w));
            float4 Mean = make_float4(S.x * invk, S.y * invk, S.z * invk, S.w * invk);
            float4* z4 = reinterpret_cast<float4*>(z);
            int zb_ = (g * 768 + fc * 64) / 4 + tid;
            if (FIRST) {
                z4[zb_] = Mean;
                z4[zb_ + 64] = M;
                z4[zb_ + 128] = S;
            } else {
                float4 c0 = z4[zb_], c1 = z4[zb_ + 64], c2 = z4[zb_ + 128];
                c0.x += Mean.x; c0.y += Mean.y; c0.z += Mean.z; c0.w += Mean.w;
                c1.x += M.x; c1.y += M.y; c1.z += M.z; c1.w += M.w;
                c2.x += S.x; c2.y += S.y; c2.z += S.z; c2.w += S.w;
                z4[zb_] = c0;
                z4[zb_ + 64] = c1;
                z4[zb_ + 128] = c2;
            }
        }
    }
}

// ---------------- fused MLP (partial-sum groupings fixed) ----------------
__global__ __launch_bounds__(256) void k_mlp(const float* __restrict__ z,
                                             const float* __restrict__ W1, const float* __restrict__ b1,
                                             const float* __restrict__ W2, const float* __restrict__ b2,
                                             const float* __restrict__ W3, const float* __restrict__ b3,
                                             float* __restrict__ out) {
    __shared__ float zb[768];
    __shared__ float t1[256];
    __shared__ float t2[128];
    __shared__ float t3[10];
    __shared__ float lse;
    int g = blockIdx.x, tid = threadIdx.x;
    zb[tid] = z[g * 768 + tid];
    zb[tid + 256] = z[g * 768 + 256 + tid];
    zb[tid + 512] = z[g * 768 + 512 + tid];
    __syncthreads();
    {
        int col = tid;
        float r0 = 0.f, r1 = 0.f, r2 = 0.f, r3 = 0.f;
        for (int i = 0;   i < 192; i++) r0 += zb[i] * W1[(size_t)i * 256 + col];
        for (int i = 192; i < 384; i++) r1 += zb[i] * W1[(size_t)i * 256 + col];
        for (int i = 384; i < 576; i++) r2 += zb[i] * W1[(size_t)i * 256 + col];
        for (int i = 576; i < 768; i++) r3 += zb[i] * W1[(size_t)i * 256 + col];
        t1[col] = fmaxf(r0 + r1 + r2 + r3 + b1[col], 0.f);
    }
    __syncthreads();
    if (tid < 128) {
        int col = tid;
        float r0 = 0.f, r1 = 0.f, r2 = 0.f, r3 = 0.f;
        for (int i = 0;   i < 64;  i++) r0 += t1[i] * W2[(size_t)i * 128 + col];
        for (int i = 64;  i < 128; i++) r1 += t1[i] * W2[(size_t)i * 128 + col];
        for (int i = 128; i < 192; i++) r2 += t1[i] * W2[(size_t)i * 128 + col];
        for (int i = 192; i < 256; i++) r3 += t1[i] * W2[(size_t)i * 128 + col];
        t2[col] = fmaxf(((r0 + r1) + r2) + r3 + b2[col], 0.f);
    }
    __syncthreads();
    if (tid < 10) {
        float v = b3[tid];
        for (int i = 0; i < 128; i++) v += t2[i] * W3[(size_t)i * 10 + tid];
        t3[tid] = v;
    }
    __syncthreads();
    if (tid == 0) {
        float m = t3[0];
        for (int c = 1; c < 10; c++) m = fmaxf(m, t3[c]);
        float se = 0.f;
        for (int c = 0; c < 10; c++) se += expf(t3[c] - m);
        lse = m + logf(se);
    }
    __syncthreads();
    if (tid < 10) out[g * 10 + tid] = t3[tid] - lse;
}

// ---------------- launcher ----------------
extern "C" void kernel_launch(void* const* d_in, const int* in_sizes, int n_in,
                              void* d_out, int out_size, void* d_ws, size_t ws_size,
                              hipStream_t stream) {
    const float* x        = (const float*)d_in[0];
    const int*   ei       = (const int*)d_in[1];
    const float* conv1_W  = (const float*)d_in[3];
    const float* conv1_b  = (const float*)d_in[4];
    const float* conv2_W  = (const float*)d_in[5];
    const float* conv2_b  = (const float*)d_in[6];
    const float* conv3_W  = (const float*)d_in[7];
    const float* conv3_b  = (const float*)d_in[8];
    const float* p1_relW  = (const float*)d_in[9];
    const float* p1_relb  = (const float*)d_in[10];
    const float* p1_rootW = (const float*)d_in[11];
    const float* p2_relW  = (const float*)d_in[12];
    const float* p2_relb  = (const float*)d_in[13];
    const float* p2_rootW = (const float*)d_in[14];
    const float* fc1_W    = (const float*)d_in[15];
    const float* fc1_b    = (const float*)d_in[16];
    const float* fc2_W    = (const float*)d_in[17];
    const float* fc2_b    = (const float*)d_in[18];
    const float* fc3_W    = (const float*)d_in[19];
    const float* fc3_b    = (const float*)d_in[20];
    float* out = (float*)d_out;

    const int E = in_sizes[1] / 2;
    const int EPG = E / NG;
    const int* e_src = ei;
    const int* e_dst = ei + E;

    // workspace layout
    char* base = (char*)d_ws;
    size_t off = 0;
    auto alloc = [&](size_t bytes) { size_t o = off; off = (off + bytes + 255) & ~(size_t)255; return o; };
    float* hW     = (float*)(base + alloc((size_t)NN * HDIM * 4));   // also xa (NN x FIN)
    float* hcur   = (float*)(base + alloc((size_t)NN * HDIM * 4));
    float* dis    = (float*)(base + alloc(NN * 4));   // stage-2 dis
    float* dis2   = (float*)(base + alloc(NN * 4));   // stage-3 dis
    float* r_rel  = (float*)(base + alloc(NN * 4));
    float* r_root = (float*)(base + alloc(NN * 4));
    float* rrel4  = (float*)(base + alloc((size_t)NN * 4 * 4));
    float* rroot4 = (float*)(base + alloc((size_t)NN * 4 * 4));
    int*   rowptr = (int*)(base + alloc((NN + 1) * 4));
    int*   csr    = (int*)(base + alloc((size_t)E * 4));
    int*   cs1    = (int*)(base + alloc(NN * 4));
    int*   ce1    = (int*)(base + alloc(NN * 4));
    int*   ccsr1  = (int*)(base + alloc((size_t)E * 4));
    float* cwdg1  = (float*)(base + alloc((size_t)E * 4));
    int*   cs2    = (int*)(base + alloc(NN * 4));
    int*   ce2    = (int*)(base + alloc(NN * 4));
    int*   ccsr2  = (int*)(base + alloc((size_t)E * 4));
    float* cwdg2  = (float*)(base + alloc((size_t)E * 4));
    float* z      = (float*)(base + alloc((size_t)NG * 768 * 4));
    int*   list1  = (int*)(base + alloc((size_t)NG * 128 * 4));
    int*   list2  = (int*)(base + alloc((size_t)NG * 64 * 4));
    float* tans1  = (float*)(base + alloc((size_t)NG * 128 * 4));
    float* tans2  = (float*)(base + alloc((size_t)NG * 64 * 4));

    // CSR build + fused sort/stage-1 aggregation
    k_csr<<<NG, 256, 0, stream>>>(e_src, e_dst, EPG, rowptr, csr);
    float* xa = hW;
    k_sortagg<<<NN / 4, 256, 0, stream>>>(x, rowptr, csr, xa);

    // ---- stage 1 ----
    {
        dim3 ggrid(HDIM / 128, NN / BM);
        k_sgemm2<<<ggrid, 256, 0, stream>>>(xa, conv1_W, hcur, FIN, conv1_b,
                                            p1_relW, p1_rootW, rrel4, rroot4);
    }
    k_topkpool<true, true, true><<<NG * 4, 256, 0, stream>>>(
        nullptr, rowptr, rowptr + 1, csr, nullptr, nullptr, rrel4, rroot4, p1_relb, 128,
        list1, tans1, hcur, z, 1.0f / 128.0f, dis, cs1, ce1, ccsr1, cwdg1, EPG);

    // ---- stage 2 ----
    {
        dim3 ggrid(HDIM / BN, (NG * 128) / BM);
        k_sgemm<<<ggrid, 256, 0, stream>>>(hcur, conv2_W, hW, HDIM, list1, tans1, nullptr,
                                           nullptr, nullptr, nullptr, nullptr);
    }
    k_gcn_agg<<<(NG * 128) / 4, 256, 0, stream>>>(hW, dis, cs1, ce1, ccsr1, cwdg1, conv2_b,
                                                  list1, 32, p2_relW, p2_rootW,
                                                  hcur, r_rel, r_root);
    k_topkpool<false, true, false><<<NG * 4, 256, 0, stream>>>(
        dis, cs1, ce1, ccsr1, r_rel, r_root, nullptr, nullptr, p2_relb, 64,
        list2, tans2, hcur, z, 1.0f / 64.0f, dis2, cs2, ce2, ccsr2, cwdg2, EPG);

    // ---- stage 3 ----
    {
        dim3 ggrid(HDIM / BN, (NG * 64) / BM);
        k_sgemm<<<ggrid, 256, 0, stream>>>(hcur, conv3_W, hW, HDIM, list2, tans2, nullptr,
                                           nullptr, nullptr, nullptr, nullptr);
    }
    k_gcn_agg<<<(NG * 64) / 4, 256, 0, stream>>>(hW, dis2, cs2, ce2, ccsr2, cwdg2, conv3_b,
                                                 list2, 16, p2_relW, p2_rootW,
                                                 hcur, r_rel, r_root);
    k_topkpool<false, false, false><<<NG * 4, 256, 0, stream>>>(
        dis2, cs2, ce2, ccsr2, r_rel, r_root, nullptr, nullptr, p2_relb, 32,
        nullptr, nullptr, hcur, z, 1.0f / 32.0f, nullptr, nullptr, nullptr, nullptr, nullptr, EPG);

    // ---- MLP ----
    k_mlp<<<NG, 256, 0, stream>>>(z, fc1_W, fc1_b, fc2_W, fc2_b, fc3_W, fc3_b, out);
}

// Round 17
// 255.536 us; speedup vs baseline: 1.2427x; 1.0151x over previous
//
#include <hip/hip_runtime.h>
#include <math.h>

#define NG 128          // graphs
#define NPG 256         // nodes per graph
#define NN 32768        // total nodes
#define HDIM 256        // hidden
#define FIN 128         // in features

// ---------------- CSR build: block per graph, LDS counting sort ----------------
__global__ __launch_bounds__(256) void k_csr(const int* __restrict__ esrc,
                                             const int* __restrict__ edst, int EPG,
                                             int* __restrict__ rowptr, int* __restrict__ csr) {
    __shared__ int cnt[NPG];
    __shared__ int cur[NPG];
    __shared__ int wtot[4];
    int g = blockIdx.x, tid = threadIdx.x;
    cnt[tid] = 0;
    __syncthreads();
    int base = g * EPG;
    for (int e = base + tid; e < base + EPG; e += 256)
        atomicAdd(&cnt[edst[e] & (NPG - 1)], 1);
    __syncthreads();
    int v = cnt[tid];
    int lane = tid & 63, w4 = tid >> 6;
    int iv = v;
    for (int off = 1; off < 64; off <<= 1) {
        int t = __shfl_up(iv, off);
        if (lane >= off) iv += t;
    }
    if (lane == 63) wtot[w4] = iv;
    __syncthreads();
    int addv = 0;
    for (int i = 0; i < w4; i++) addv += wtot[i];
    int excl = iv + addv - v;
    rowptr[g * NPG + tid] = base + excl;
    cur[tid] = base + excl;
    if (g == 0 && tid == 0) rowptr[NN] = NG * EPG;
    __syncthreads();
    for (int e = base + tid; e < base + EPG; e += 256) {
        int d = edst[e] & (NPG - 1);
        int p = atomicAdd(&cur[d], 1);
        csr[p] = esrc[e];
    }
}

// XCD-locality swizzle
__device__ __forceinline__ int swz_block(int bid, int bpg) {
    int xcd = bid & 7, r = bid >> 3;
    int graph = xcd * (NG / 8) + r / bpg;
    int sub = r - (r / bpg) * bpg;
    return graph * bpg + sub;
}

// ---------------- fused sort + stage-1 aggregation: wave per node ----------------
__global__ __launch_bounds__(256) void k_sortagg(const float* __restrict__ x,
                                                 const int* __restrict__ rowptr,
                                                 int* __restrict__ csr,
                                                 float* __restrict__ xa) {
    __shared__ int skey[4][64];
    __shared__ float swgt[4][64];
    int blk = swz_block(blockIdx.x, NPG / 4);
    int w = threadIdx.x >> 6, lane = threadIdx.x & 63;
    int n = blk * 4 + w;
    int e0 = rowptr[n];
    int d = rowptr[n + 1] - e0;
    float ddst = rsqrtf((float)(1 + d));
    bool big = d > 64;
    if (!big) {
        int key = (lane < d) ? csr[e0 + lane] : 0x7fffffff;
        int rank = 0;
        for (int j = 0; j < d; j++) {
            int kj = __shfl(key, j);
            rank += (kj < key || (kj == key && j < lane)) ? 1 : 0;
        }
        if (lane < d) {
            csr[e0 + rank] = key;
            skey[w][rank] = key;
            swgt[w][rank] = rsqrtf((float)(1 + rowptr[key + 1] - rowptr[key])) * ddst;
        }
    } else if (lane == 0) {
        for (int a = e0 + 1; a < e0 + d; a++) {
            int key = csr[a];
            int b = a - 1;
            while (b >= e0 && csr[b] > key) { csr[b + 1] = csr[b]; b--; }
            csr[b + 1] = key;
        }
    }
    __syncthreads();
    const float2* x2 = reinterpret_cast<const float2*>(x);
    float di = ddst;
    float2 h = x2[(size_t)n * (FIN / 2) + lane];
    float self = di * di;
    float ax = h.x * self, ay = h.y * self;
    if (!big) {
        for (int j = 0; j < d; j++) {
            int s = skey[w][j];
            float we = swgt[w][j];
            float2 hs = x2[(size_t)s * (FIN / 2) + lane];
            ax += hs.x * we; ay += hs.y * we;
        }
    } else {
        for (int e = e0; e < e0 + d; e++) {
            int s = csr[e];
            float we = rsqrtf((float)(1 + rowptr[s + 1] - rowptr[s])) * ddst;
            float2 hs = x2[(size_t)s * (FIN / 2) + lane];
            ax += hs.x * we; ay += hs.y * we;
        }
    }
    float2 o; o.x = ax; o.y = ay;
    reinterpret_cast<float2*>(xa)[(size_t)n * (FIN / 2) + lane] = o;
}

// ---------------- SGEMM (64x64, 4x4, pad 68, reg dbuf) — stage 3 ----------------
#define BM 64
#define BN 64
#define BK 16
#define BMP 68
__global__ __launch_bounds__(256) void k_sgemm(const float* __restrict__ A,
                                               const float* __restrict__ B,
                                               float* __restrict__ C, int K,
                                               const int* __restrict__ list,
                                               const float* __restrict__ tansel,
                                               const float* __restrict__ brelu,
                                               const float* __restrict__ wrel,
                                               const float* __restrict__ wroot,
                                               float* __restrict__ rrel4,
                                               float* __restrict__ rroot4) {
    const int N = HDIM;
    __shared__ float As[BK][BMP];
    __shared__ float Bs[BK][BN];
    int tid = threadIdx.x;
    int tx = tid & 15, ty = tid >> 4;
    int row0 = blockIdx.y * BM, col0 = blockIdx.x * BN;
    int lm = tid >> 2;
    int arow = list ? list[row0 + lm] : (row0 + lm);
    float tv = tansel ? tansel[row0 + lm] : 1.0f;
    int crow[4];
#pragma unroll
    for (int i = 0; i < 4; i++) {
        int r = row0 + ty * 4 + i;
        crow[i] = list ? list[r] : r;
    }
    int k4 = (tid & 3) * 4;
    int kkB = tid >> 4, cB = (tid & 15) * 4;
    float4 aP = *reinterpret_cast<const float4*>(&A[(size_t)arow * K + k4]);
    float4 bP = *reinterpret_cast<const float4*>(&B[(size_t)kkB * N + col0 + cB]);
    float acc[4][4] = {};
    for (int kb = 0; kb < K; kb += BK) {
        As[k4 + 0][lm] = aP.x * tv; As[k4 + 1][lm] = aP.y * tv;
        As[k4 + 2][lm] = aP.z * tv; As[k4 + 3][lm] = aP.w * tv;
        *reinterpret_cast<float4*>(&Bs[kkB][cB]) = bP;
        __syncthreads();
        if (kb + BK < K) {
            aP = *reinterpret_cast<const float4*>(&A[(size_t)arow * K + kb + BK + k4]);
            bP = *reinterpret_cast<const float4*>(&B[(size_t)(kb + BK + kkB) * N + col0 + cB]);
        }
#pragma unroll
        for (int k = 0; k < BK; k++) {
            float4 a = *reinterpret_cast<float4*>(&As[k][ty * 4]);
            float4 b = *reinterpret_cast<float4*>(&Bs[k][tx * 4]);
            float av[4] = {a.x, a.y, a.z, a.w};
            float bv[4] = {b.x, b.y, b.z, b.w};
#pragma unroll
            for (int i = 0; i < 4; i++)
#pragma unroll
                for (int j = 0; j < 4; j++) acc[i][j] += av[i] * bv[j];
        }
        __syncthreads();
    }
    float4 bb = make_float4(0.f, 0.f, 0.f, 0.f);
    if (brelu) bb = *reinterpret_cast<const float4*>(&brelu[col0 + tx * 4]);
    float4 wr = make_float4(0.f, 0.f, 0.f, 0.f), wo = wr;
    if (wrel) {
        wr = *reinterpret_cast<const float4*>(&wrel[col0 + tx * 4]);
        wo = *reinterpret_cast<const float4*>(&wroot[col0 + tx * 4]);
    }
#pragma unroll
    for (int i = 0; i < 4; i++) {
        float4 v = make_float4(acc[i][0], acc[i][1], acc[i][2], acc[i][3]);
        if (brelu) {
            v.x = fmaxf(v.x + bb.x, 0.f);
            v.y = fmaxf(v.y + bb.y, 0.f);
            v.z = fmaxf(v.z + bb.z, 0.f);
            v.w = fmaxf(v.w + bb.w, 0.f);
        }
        *reinterpret_cast<float4*>(&C[(size_t)crow[i] * N + col0 + tx * 4]) = v;
        if (wrel) {
            float s1 = v.x * wr.x + v.y * wr.y + v.z * wr.z + v.w * wr.w;
            float s2 = v.x * wo.x + v.y * wo.y + v.z * wo.z + v.w * wo.w;
            for (int off = 8; off > 0; off >>= 1) {
                s1 += __shfl_down(s1, off, 16);
                s2 += __shfl_down(s2, off, 16);
            }
            if (tx == 0) {
                rrel4[(size_t)crow[i] * 4 + blockIdx.x] = s1;
                rroot4[(size_t)crow[i] * 4 + blockIdx.x] = s2;
            }
        }
    }
}

// ---------------- dual N-tile SGEMM (64x128), stages 1 & 2 ----------------
// nullable list/tansel; per-64-col-block epilogue groupings identical to k_sgemm.
__global__ __launch_bounds__(256) void k_sgemm2(const float* __restrict__ A,
                                                const float* __restrict__ B,
                                                float* __restrict__ C, int K,
                                                const int* __restrict__ list,
                                                const float* __restrict__ tansel,
                                                const float* __restrict__ brelu,
                                                const float* __restrict__ wrel,
                                                const float* __restrict__ wroot,
                                                float* __restrict__ rrel4,
                                                float* __restrict__ rroot4) {
    const int N = HDIM;
    __shared__ float As[BK][BMP];
    __shared__ float Bs[BK][128];
    int tid = threadIdx.x;
    int tx = tid & 15, ty = tid >> 4;
    int row0 = blockIdx.y * BM, col0 = blockIdx.x * 128;
    int lm = tid >> 2;
    int arow = list ? list[row0 + lm] : (row0 + lm);
    float tv = tansel ? tansel[row0 + lm] : 1.0f;
    int crow[4];
#pragma unroll
    for (int i = 0; i < 4; i++) {
        int r = row0 + ty * 4 + i;
        crow[i] = list ? list[r] : r;
    }
    int k4 = (tid & 3) * 4;
    int kkB0 = tid >> 5, cB0 = (tid & 31) * 4;
    int kkB1 = (256 + tid) >> 5, cB1 = cB0;
    float4 aP = *reinterpret_cast<const float4*>(&A[(size_t)arow * K + k4]);
    float4 bP0 = *reinterpret_cast<const float4*>(&B[(size_t)kkB0 * N + col0 + cB0]);
    float4 bP1 = *reinterpret_cast<const float4*>(&B[(size_t)kkB1 * N + col0 + cB1]);
    float acc0[4][4] = {};
    float acc1[4][4] = {};
    for (int kb = 0; kb < K; kb += BK) {
        As[k4 + 0][lm] = aP.x * tv; As[k4 + 1][lm] = aP.y * tv;
        As[k4 + 2][lm] = aP.z * tv; As[k4 + 3][lm] = aP.w * tv;
        *reinterpret_cast<float4*>(&Bs[kkB0][cB0]) = bP0;
        *reinterpret_cast<float4*>(&Bs[kkB1][cB1]) = bP1;
        __syncthreads();
        if (kb + BK < K) {
            aP = *reinterpret_cast<const float4*>(&A[(size_t)arow * K + kb + BK + k4]);
            bP0 = *reinterpret_cast<const float4*>(&B[(size_t)(kb + BK + kkB0) * N + col0 + cB0]);
            bP1 = *reinterpret_cast<const float4*>(&B[(size_t)(kb + BK + kkB1) * N + col0 + cB1]);
        }
#pragma unroll
        for (int k = 0; k < BK; k++) {
            float4 a = *reinterpret_cast<float4*>(&As[k][ty * 4]);
            float4 b0 = *reinterpret_cast<float4*>(&Bs[k][tx * 4]);
            float4 b1 = *reinterpret_cast<float4*>(&Bs[k][64 + tx * 4]);
            float av[4] = {a.x, a.y, a.z, a.w};
            float bv0[4] = {b0.x, b0.y, b0.z, b0.w};
            float bv1[4] = {b1.x, b1.y, b1.z, b1.w};
#pragma unroll
            for (int i = 0; i < 4; i++) {
#pragma unroll
                for (int j = 0; j < 4; j++) {
                    acc0[i][j] += av[i] * bv0[j];
                    acc1[i][j] += av[i] * bv1[j];
                }
            }
        }
        __syncthreads();
    }
#pragma unroll
    for (int half = 0; half < 2; half++) {
        int cbase = col0 + half * 64;
        float (*acc)[4] = half ? acc1 : acc0;
        float4 bb = make_float4(0.f, 0.f, 0.f, 0.f);
        if (brelu) bb = *reinterpret_cast<const float4*>(&brelu[cbase + tx * 4]);
        float4 wr = make_float4(0.f, 0.f, 0.f, 0.f), wo = wr;
        if (wrel) {
            wr = *reinterpret_cast<const float4*>(&wrel[cbase + tx * 4]);
            wo = *reinterpret_cast<const float4*>(&wroot[cbase + tx * 4]);
        }
        int cb = blockIdx.x * 2 + half;
#pragma unroll
        for (int i = 0; i < 4; i++) {
            float4 v = make_float4(acc[i][0], acc[i][1], acc[i][2], acc[i][3]);
            if (brelu) {
                v.x = fmaxf(v.x + bb.x, 0.f);
                v.y = fmaxf(v.y + bb.y, 0.f);
                v.z = fmaxf(v.z + bb.z, 0.f);
                v.w = fmaxf(v.w + bb.w, 0.f);
            }
            *reinterpret_cast<float4*>(&C[(size_t)crow[i] * N + cbase + tx * 4]) = v;
            if (wrel) {
                float s1 = v.x * wr.x + v.y * wr.y + v.z * wr.z + v.w * wr.w;
                float s2 = v.x * wo.x + v.y * wo.y + v.z * wo.z + v.w * wo.w;
                for (int off = 8; off > 0; off >>= 1) {
                    s1 += __shfl_down(s1, off, 16);
                    s2 += __shfl_down(s2, off, 16);
                }
                if (tx == 0) {
                    rrel4[(size_t)crow[i] * 4 + cb] = s1;
                    rroot4[(size_t)crow[i] * 4 + cb] = s2;
                }
            }
        }
    }
}

// stages 2/3: wave per ACTIVE node, branch-free gather over COMPACT edge rows
__global__ __launch_bounds__(256) void k_gcn_agg(const float* __restrict__ hW,
                                                 const float* __restrict__ dis,
                                                 const int* __restrict__ rs,
                                                 const int* __restrict__ re,
                                                 const int* __restrict__ ccsr,
                                                 const float* __restrict__ cwedge,
                                                 const float* __restrict__ bias,
                                                 const int* __restrict__ list, int bpg,
                                                 const float* __restrict__ w_rel,
                                                 const float* __restrict__ w_root,
                                                 float* __restrict__ out,
                                                 float* __restrict__ r_rel,
                                                 float* __restrict__ r_root) {
    int blk = swz_block(blockIdx.x, bpg);
    int idx = blk * 4 + (threadIdx.x >> 6);
    int lane = threadIdx.x & 63;
    int wid = list[idx];
    float di = dis[wid];
    float4 h = *reinterpret_cast<const float4*>(&hW[(size_t)wid * HDIM + lane * 4]);
    float self = di * di;
    float ax = h.x * self, ay = h.y * self, az = h.z * self, aw = h.w * self;
    int e0 = rs[wid], e1 = re[wid];
    for (int e = e0; e < e1; e++) {
        float w = cwedge[e];
        int s = ccsr[e];
        float4 hs = *reinterpret_cast<const float4*>(&hW[(size_t)s * HDIM + lane * 4]);
        ax += hs.x * w; ay += hs.y * w; az += hs.z * w; aw += hs.w * w;
    }
    float4 b = *reinterpret_cast<const float4*>(&bias[lane * 4]);
    float4 o;
    o.x = fmaxf(ax + b.x, 0.f);
    o.y = fmaxf(ay + b.y, 0.f);
    o.z = fmaxf(az + b.z, 0.f);
    o.w = fmaxf(aw + b.w, 0.f);
    *reinterpret_cast<float4*>(&out[(size_t)wid * HDIM + lane * 4]) = o;
    float4 wr = *reinterpret_cast<const float4*>(&w_rel[lane * 4]);
    float4 wo = *reinterpret_cast<const float4*>(&w_root[lane * 4]);
    float s1 = o.x * wr.x + o.y * wr.y + o.z * wr.z + o.w * wr.w;
    float s2 = o.x * wo.x + o.y * wo.y + o.z * wo.z + o.w * wo.w;
    for (int off = 32; off > 0; off >>= 1) {
        s1 += __shfl_down(s1, off);
        s2 += __shfl_down(s2, off);
    }
    if (lane == 0) { r_rel[wid] = s1; r_root[wid] = s2; }
}

// ---------------- fused score + top-k + readout (+compact-CSR emit) ----------------
template<bool STAGE1, bool EMIT, bool FIRST>
__global__ __launch_bounds__(256) void k_topkpool(const float* __restrict__ dis,
                                                  const int* __restrict__ rs,
                                                  const int* __restrict__ re,
                                                  const int* __restrict__ csr_in,
                                                  const float* __restrict__ r_rel,
                                                  const float* __restrict__ r_root,
                                                  const float* __restrict__ rrel4,
                                                  const float* __restrict__ rroot4,
                                                  const float* __restrict__ b_rel, int k,
                                                  int* __restrict__ list,
                                                  float* __restrict__ tanselG,
                                                  const float* __restrict__ h,
                                                  float* __restrict__ z, float invk,
                                                  float* __restrict__ disN,
                                                  int* __restrict__ csN,
                                                  int* __restrict__ ceN,
                                                  int* __restrict__ ccsrN,
                                                  float* __restrict__ cwedgeN,
                                                  int EPG) {
    __shared__ float rrel[NPG];
    __shared__ __align__(16) float sc[NPG];
    __shared__ int sels[NPG];
    __shared__ float disn[NPG];
    __shared__ int newl[128];
    __shared__ float tvsel[128];
    __shared__ int wtot[4];
    __shared__ float4 red4_s[4][16];
    __shared__ float4 red4_m[4][16];
    int g = blockIdx.x >> 2, fc = blockIdx.x & 3;
    int tid = threadIdx.x;
    int lane = tid & 63, w4 = tid >> 6;
    int n = g * NPG + tid;
    bool act = STAGE1 ? true : (dis[n] > 0.f);
    float rr, ro;
    if (STAGE1) {
        float4 r4 = *reinterpret_cast<const float4*>(&rrel4[(size_t)n * 4]);
        float4 o4 = *reinterpret_cast<const float4*>(&rroot4[(size_t)n * 4]);
        rr = ((r4.x + r4.y) + r4.z) + r4.w;
        ro = ((o4.x + o4.y) + o4.z) + o4.w;
    } else {
        rr = act ? r_rel[n] : 0.f;
        ro = act ? r_root[n] : 0.f;
    }
    rrel[tid] = act ? rr : 0.f;
    __syncthreads();
    int e0 = rs[n], e1 = re[n];
    float my;
    if (act) {
        float s = b_rel[0] + ro;
        for (int e = e0; e < e1; e++) s += rrel[csr_in[e] & (NPG - 1)];
        my = s;
    } else {
        my = -INFINITY;
    }
    sc[tid] = my;
    __syncthreads();
    int cnt = 0;
    {
        const float4* sc4 = reinterpret_cast<const float4*>(sc);
        for (int jj = 0; jj < NPG / 4; jj++) {
            float4 v = sc4[jj];
            int j0 = jj * 4;
            cnt += (v.x > my || (v.x == my && (j0 + 0) < tid)) ? 1 : 0;
            cnt += (v.y > my || (v.y == my && (j0 + 1) < tid)) ? 1 : 0;
            cnt += (v.z > my || (v.z == my && (j0 + 2) < tid)) ? 1 : 0;
            cnt += (v.w > my || (v.w == my && (j0 + 3) < tid)) ? 1 : 0;
        }
    }
    int a = (cnt < k) ? 1 : 0;
    sels[tid] = a;
    int incl;
    {
        int v = a;
        for (int off = 1; off < 64; off <<= 1) {
            int t = __shfl_up(v, off);
            if (lane >= off) v += t;
        }
        if (lane == 63) wtot[w4] = v;
        __syncthreads();
        int addv = 0;
        for (int i = 0; i < w4; i++) addv += wtot[i];
        incl = v + addv;
    }
    if (a) {
        int rk = incl - 1;
        newl[rk] = tid;
        float t = tanhf(my);
        tvsel[rk] = t;
        if (fc == 0 && list) {
            list[g * k + rk] = n;
            tanselG[g * k + rk] = t;
        }
    }
    if (EMIT) {
        int deg2 = 0;
        if (a) {
            for (int e = e0; e < e1; e++) deg2 += sels[csr_in[e] & (NPG - 1)];
        }
        float dn = a ? rsqrtf((float)(1 + deg2)) : 0.f;
        disn[tid] = dn;
        if (fc == 0) disN[n] = dn;
        __syncthreads();
        int v = deg2;
        for (int off = 1; off < 64; off <<= 1) {
            int t = __shfl_up(v, off);
            if (lane >= off) v += t;
        }
        if (lane == 63) wtot[w4] = v;
        __syncthreads();
        if (fc == 0) {
            int addv = 0;
            for (int i = 0; i < w4; i++) addv += wtot[i];
            int start = g * EPG + (v + addv) - deg2;
            csN[n] = start;
            ceN[n] = start + deg2;
            if (a) {
                int p = start;
                for (int e = e0; e < e1; e++) {
                    int srcg = csr_in[e];
                    int j = srcg & (NPG - 1);
                    if (sels[j]) {
                        ccsrN[p] = srcg;
                        cwedgeN[p] = disn[j] * dn;
                        p++;
                    }
                }
            }
        }
    }
    __syncthreads();
    {
        int q = tid & 15, sub = (tid >> 4) & 3, y = tid >> 6;
        const float4* h4 = reinterpret_cast<const float4*>(h);
        float4 s4 = make_float4(0.f, 0.f, 0.f, 0.f);
        float4 m4 = make_float4(-INFINITY, -INFINITY, -INFINITY, -INFINITY);
        for (int idx = y * 4 + sub; idx < k; idx += 16) {
            int node = g * NPG + newl[idx];
            float t = tvsel[idx];
            float4 v = h4[(size_t)node * (HDIM / 4) + fc * 16 + q];
            v.x *= t; v.y *= t; v.z *= t; v.w *= t;
            s4.x += v.x; s4.y += v.y; s4.z += v.z; s4.w += v.w;
            m4.x = fmaxf(m4.x, v.x); m4.y = fmaxf(m4.y, v.y);
            m4.z = fmaxf(m4.z, v.z); m4.w = fmaxf(m4.w, v.w);
        }
#pragma unroll
        for (int off = 16; off <= 32; off <<= 1) {
            s4.x += __shfl_down(s4.x, off); s4.y += __shfl_down(s4.y, off);
            s4.z += __shfl_down(s4.z, off); s4.w += __shfl_down(s4.w, off);
            m4.x = fmaxf(m4.x, __shfl_down(m4.x, off));
            m4.y = fmaxf(m4.y, __shfl_down(m4.y, off));
            m4.z = fmaxf(m4.z, __shfl_down(m4.z, off));
            m4.w = fmaxf(m4.w, __shfl_down(m4.w, off));
        }
        if (sub == 0) { red4_s[y][q] = s4; red4_m[y][q] = m4; }
        __syncthreads();
        if (tid < 16) {
            float4 a0 = red4_s[0][tid], a1 = red4_s[1][tid];
            float4 a2 = red4_s[2][tid], a3 = red4_s[3][tid];
            float4 S;
            S.x = ((a0.x + a1.x) + a2.x) + a3.x;
            S.y = ((a0.y + a1.y) + a2.y) + a3.y;
            S.z = ((a0.z + a1.z) + a2.z) + a3.z;
            S.w = ((a0.w + a1.w) + a2.w) + a3.w;
            float4 b0 = red4_m[0][tid], b1 = red4_m[1][tid];
            float4 b2 = red4_m[2][tid], b3 = red4_m[3][tid];
            float4 M;
            M.x = fmaxf(fmaxf(b0.x, b1.x), fmaxf(b2.x, b3.x));
            M.y = fmaxf(fmaxf(b0.y, b1.y), fmaxf(b2.y, b3.y));
            M.z = fmaxf(fmaxf(b0.z, b1.z), fmaxf(b2.z, b3.z));
            M.w = fmaxf(fmaxf(b0.w, b1.w), fmaxf(b2.w, b3.w));
            float4 Mean = make_float4(S.x * invk, S.y * invk, S.z * invk, S.w * invk);
            float4* z4 = reinterpret_cast<float4*>(z);
            int zb_ = (g * 768 + fc * 64) / 4 + tid;
            if (FIRST) {
                z4[zb_] = Mean;
                z4[zb_ + 64] = M;
                z4[zb_ + 128] = S;
            } else {
                float4 c0 = z4[zb_], c1 = z4[zb_ + 64], c2 = z4[zb_ + 128];
                c0.x += Mean.x; c0.y += Mean.y; c0.z += Mean.z; c0.w += Mean.w;
                c1.x += M.x; c1.y += M.y; c1.z += M.z; c1.w += M.w;
                c2.x += S.x; c2.y += S.y; c2.z += S.z; c2.w += S.w;
                z4[zb_] = c0;
                z4[zb_ + 64] = c1;
                z4[zb_ + 128] = c2;
            }
        }
    }
}

// ---------------- fused MLP (partial-sum groupings fixed) ----------------
__global__ __launch_bounds__(256) void k_mlp(const float* __restrict__ z,
                                             const float* __restrict__ W1, const float* __restrict__ b1,
                                             const float* __restrict__ W2, const float* __restrict__ b2,
                                             const float* __restrict__ W3, const float* __restrict__ b3,
                                             float* __restrict__ out) {
    __shared__ float zb[768];
    __shared__ float t1[256];
    __shared__ float t2[128];
    __shared__ float t3[10];
    __shared__ float lse;
    int g = blockIdx.x, tid = threadIdx.x;
    zb[tid] = z[g * 768 + tid];
    zb[tid + 256] = z[g * 768 + 256 + tid];
    zb[tid + 512] = z[g * 768 + 512 + tid];
    __syncthreads();
    {
        int col = tid;
        float r0 = 0.f, r1 = 0.f, r2 = 0.f, r3 = 0.f;
        for (int i = 0;   i < 192; i++) r0 += zb[i] * W1[(size_t)i * 256 + col];
        for (int i = 192; i < 384; i++) r1 += zb[i] * W1[(size_t)i * 256 + col];
        for (int i = 384; i < 576; i++) r2 += zb[i] * W1[(size_t)i * 256 + col];
        for (int i = 576; i < 768; i++) r3 += zb[i] * W1[(size_t)i * 256 + col];
        t1[col] = fmaxf(r0 + r1 + r2 + r3 + b1[col], 0.f);
    }
    __syncthreads();
    if (tid < 128) {
        int col = tid;
        float r0 = 0.f, r1 = 0.f, r2 = 0.f, r3 = 0.f;
        for (int i = 0;   i < 64;  i++) r0 += t1[i] * W2[(size_t)i * 128 + col];
        for (int i = 64;  i < 128; i++) r1 += t1[i] * W2[(size_t)i * 128 + col];
        for (int i = 128; i < 192; i++) r2 += t1[i] * W2[(size_t)i * 128 + col];
        for (int i = 192; i < 256; i++) r3 += t1[i] * W2[(size_t)i * 128 + col];
        t2[col] = fmaxf(((r0 + r1) + r2) + r3 + b2[col], 0.f);
    }
    __syncthreads();
    if (tid < 10) {
        float v = b3[tid];
        for (int i = 0; i < 128; i++) v += t2[i] * W3[(size_t)i * 10 + tid];
        t3[tid] = v;
    }
    __syncthreads();
    if (tid == 0) {
        float m = t3[0];
        for (int c = 1; c < 10; c++) m = fmaxf(m, t3[c]);
        float se = 0.f;
        for (int c = 0; c < 10; c++) se += expf(t3[c] - m);
        lse = m + logf(se);
    }
    __syncthreads();
    if (tid < 10) out[g * 10 + tid] = t3[tid] - lse;
}

// ---------------- launcher ----------------
extern "C" void kernel_launch(void* const* d_in, const int* in_sizes, int n_in,
                              void* d_out, int out_size, void* d_ws, size_t ws_size,
                              hipStream_t stream) {
    const float* x        = (const float*)d_in[0];
    const int*   ei       = (const int*)d_in[1];
    const float* conv1_W  = (const float*)d_in[3];
    const float* conv1_b  = (const float*)d_in[4];
    const float* conv2_W  = (const float*)d_in[5];
    const float* conv2_b  = (const float*)d_in[6];
    const float* conv3_W  = (const float*)d_in[7];
    const float* conv3_b  = (const float*)d_in[8];
    const float* p1_relW  = (const float*)d_in[9];
    const float* p1_relb  = (const float*)d_in[10];
    const float* p1_rootW = (const float*)d_in[11];
    const float* p2_relW  = (const float*)d_in[12];
    const float* p2_relb  = (const float*)d_in[13];
    const float* p2_rootW = (const float*)d_in[14];
    const float* fc1_W    = (const float*)d_in[15];
    const float* fc1_b    = (const float*)d_in[16];
    const float* fc2_W    = (const float*)d_in[17];
    const float* fc2_b    = (const float*)d_in[18];
    const float* fc3_W    = (const float*)d_in[19];
    const float* fc3_b    = (const float*)d_in[20];
    float* out = (float*)d_out;

    const int E = in_sizes[1] / 2;
    const int EPG = E / NG;
    const int* e_src = ei;
    const int* e_dst = ei + E;

    // workspace layout
    char* base = (char*)d_ws;
    size_t off = 0;
    auto alloc = [&](size_t bytes) { size_t o = off; off = (off + bytes + 255) & ~(size_t)255; return o; };
    float* hW     = (float*)(base + alloc((size_t)NN * HDIM * 4));   // also xa (NN x FIN)
    float* hcur   = (float*)(base + alloc((size_t)NN * HDIM * 4));
    float* dis    = (float*)(base + alloc(NN * 4));   // stage-2 dis
    float* dis2   = (float*)(base + alloc(NN * 4));   // stage-3 dis
    float* r_rel  = (float*)(base + alloc(NN * 4));
    float* r_root = (float*)(base + alloc(NN * 4));
    float* rrel4  = (float*)(base + alloc((size_t)NN * 4 * 4));
    float* rroot4 = (float*)(base + alloc((size_t)NN * 4 * 4));
    int*   rowptr = (int*)(base + alloc((NN + 1) * 4));
    int*   csr    = (int*)(base + alloc((size_t)E * 4));
    int*   cs1    = (int*)(base + alloc(NN * 4));
    int*   ce1    = (int*)(base + alloc(NN * 4));
    int*   ccsr1  = (int*)(base + alloc((size_t)E * 4));
    float* cwdg1  = (float*)(base + alloc((size_t)E * 4));
    int*   cs2    = (int*)(base + alloc(NN * 4));
    int*   ce2    = (int*)(base + alloc(NN * 4));
    int*   ccsr2  = (int*)(base + alloc((size_t)E * 4));
    float* cwdg2  = (float*)(base + alloc((size_t)E * 4));
    float* z      = (float*)(base + alloc((size_t)NG * 768 * 4));
    int*   list1  = (int*)(base + alloc((size_t)NG * 128 * 4));
    int*   list2  = (int*)(base + alloc((size_t)NG * 64 * 4));
    float* tans1  = (float*)(base + alloc((size_t)NG * 128 * 4));
    float* tans2  = (float*)(base + alloc((size_t)NG * 64 * 4));

    // CSR build + fused sort/stage-1 aggregation
    k_csr<<<NG, 256, 0, stream>>>(e_src, e_dst, EPG, rowptr, csr);
    float* xa = hW;
    k_sortagg<<<NN / 4, 256, 0, stream>>>(x, rowptr, csr, xa);

    // ---- stage 1 ----
    {
        dim3 ggrid(HDIM / 128, NN / BM);
        k_sgemm2<<<ggrid, 256, 0, stream>>>(xa, conv1_W, hcur, FIN, nullptr, nullptr,
                                            conv1_b, p1_relW, p1_rootW, rrel4, rroot4);
    }
    k_topkpool<true, true, true><<<NG * 4, 256, 0, stream>>>(
        nullptr, rowptr, rowptr + 1, csr, nullptr, nullptr, rrel4, rroot4, p1_relb, 128,
        list1, tans1, hcur, z, 1.0f / 128.0f, dis, cs1, ce1, ccsr1, cwdg1, EPG);

    // ---- stage 2 ----
    {
        dim3 ggrid(HDIM / 128, (NG * 128) / BM);
        k_sgemm2<<<ggrid, 256, 0, stream>>>(hcur, conv2_W, hW, HDIM, list1, tans1,
                                            nullptr, nullptr, nullptr, nullptr, nullptr);
    }
    k_gcn_agg<<<(NG * 128) / 4, 256, 0, stream>>>(hW, dis, cs1, ce1, ccsr1, cwdg1, conv2_b,
                                                  list1, 32, p2_relW, p2_rootW,
                                                  hcur, r_rel, r_root);
    k_topkpool<false, true, false><<<NG * 4, 256, 0, stream>>>(
        dis, cs1, ce1, ccsr1, r_rel, r_root, nullptr, nullptr, p2_relb, 64,
        list2, tans2, hcur, z, 1.0f / 64.0f, dis2, cs2, ce2, ccsr2, cwdg2, EPG);

    // ---- stage 3 ----
    {
        dim3 ggrid(HDIM / BN, (NG * 64) / BM);
        k_sgemm<<<ggrid, 256, 0, stream>>>(hcur, conv3_W, hW, HDIM, list2, tans2, nullptr,
                                           nullptr, nullptr, nullptr, nullptr);
    }
    k_gcn_agg<<<(NG * 64) / 4, 256, 0, stream>>>(hW, dis2, cs2, ce2, ccsr2, cwdg2, conv3_b,
                                                 list2, 16, p2_relW, p2_rootW,
                                                 hcur, r_rel, r_root);
    k_topkpool<false, false, false><<<NG * 4, 256, 0, stream>>>(
        dis2, cs2, ce2, ccsr2, r_rel, r_root, nullptr, nullptr, p2_relb, 32,
        nullptr, nullptr, hcur, z, 1.0f / 32.0f, nullptr, nullptr, nullptr, nullptr, nullptr, EPG);

    // ---- MLP ----
    k_mlp<<<NG, 256, 0, stream>>>(z, fc1_W, fc1_b, fc2_W, fc2_b, fc3_W, fc3_b, out);
}

// Round 18
// 253.637 us; speedup vs baseline: 1.2520x; 1.0075x over previous
//
#include <hip/hip_runtime.h>
#include <math.h>

#define NG 128          // graphs
#define NPG 256         // nodes per graph
#define NN 32768        // total nodes
#define HDIM 256        // hidden
#define FIN 128         // in features

// ---------------- CSR build: block per graph, LDS counting sort ----------------
__global__ __launch_bounds__(256) void k_csr(const int* __restrict__ esrc,
                                             const int* __restrict__ edst, int EPG,
                                             int* __restrict__ rowptr, int* __restrict__ csr) {
    __shared__ int cnt[NPG];
    __shared__ int cur[NPG];
    __shared__ int wtot[4];
    int g = blockIdx.x, tid = threadIdx.x;
    cnt[tid] = 0;
    __syncthreads();
    int base = g * EPG;
    for (int e = base + tid; e < base + EPG; e += 256)
        atomicAdd(&cnt[edst[e] & (NPG - 1)], 1);
    __syncthreads();
    int v = cnt[tid];
    int lane = tid & 63, w4 = tid >> 6;
    int iv = v;
    for (int off = 1; off < 64; off <<= 1) {
        int t = __shfl_up(iv, off);
        if (lane >= off) iv += t;
    }
    if (lane == 63) wtot[w4] = iv;
    __syncthreads();
    int addv = 0;
    for (int i = 0; i < w4; i++) addv += wtot[i];
    int excl = iv + addv - v;
    rowptr[g * NPG + tid] = base + excl;
    cur[tid] = base + excl;
    if (g == 0 && tid == 0) rowptr[NN] = NG * EPG;
    __syncthreads();
    for (int e = base + tid; e < base + EPG; e += 256) {
        int d = edst[e] & (NPG - 1);
        int p = atomicAdd(&cur[d], 1);
        csr[p] = esrc[e];
    }
}

// XCD-locality swizzle
__device__ __forceinline__ int swz_block(int bid, int bpg) {
    int xcd = bid & 7, r = bid >> 3;
    int graph = xcd * (NG / 8) + r / bpg;
    int sub = r - (r / bpg) * bpg;
    return graph * bpg + sub;
}

// ---------------- fused sort + stage-1 aggregation: wave per node ----------------
__global__ __launch_bounds__(256) void k_sortagg(const float* __restrict__ x,
                                                 const int* __restrict__ rowptr,
                                                 int* __restrict__ csr,
                                                 float* __restrict__ xa) {
    __shared__ int skey[4][64];
    __shared__ float swgt[4][64];
    int blk = swz_block(blockIdx.x, NPG / 4);
    int w = threadIdx.x >> 6, lane = threadIdx.x & 63;
    int n = blk * 4 + w;
    int e0 = rowptr[n];
    int d = rowptr[n + 1] - e0;
    float ddst = rsqrtf((float)(1 + d));
    bool big = d > 64;
    if (!big) {
        int key = (lane < d) ? csr[e0 + lane] : 0x7fffffff;
        int rank = 0;
        for (int j = 0; j < d; j++) {
            int kj = __shfl(key, j);
            rank += (kj < key || (kj == key && j < lane)) ? 1 : 0;
        }
        if (lane < d) {
            csr[e0 + rank] = key;
            skey[w][rank] = key;
            swgt[w][rank] = rsqrtf((float)(1 + rowptr[key + 1] - rowptr[key])) * ddst;
        }
    } else if (lane == 0) {
        for (int a = e0 + 1; a < e0 + d; a++) {
            int key = csr[a];
            int b = a - 1;
            while (b >= e0 && csr[b] > key) { csr[b + 1] = csr[b]; b--; }
            csr[b + 1] = key;
        }
    }
    __syncthreads();
    const float2* x2 = reinterpret_cast<const float2*>(x);
    float di = ddst;
    float2 h = x2[(size_t)n * (FIN / 2) + lane];
    float self = di * di;
    float ax = h.x * self, ay = h.y * self;
    if (!big) {
        for (int j = 0; j < d; j++) {
            int s = skey[w][j];
            float we = swgt[w][j];
            float2 hs = x2[(size_t)s * (FIN / 2) + lane];
            ax += hs.x * we; ay += hs.y * we;
        }
    } else {
        for (int e = e0; e < e0 + d; e++) {
            int s = csr[e];
            float we = rsqrtf((float)(1 + rowptr[s + 1] - rowptr[s])) * ddst;
            float2 hs = x2[(size_t)s * (FIN / 2) + lane];
            ax += hs.x * we; ay += hs.y * we;
        }
    }
    float2 o; o.x = ax; o.y = ay;
    reinterpret_cast<float2*>(xa)[(size_t)n * (FIN / 2) + lane] = o;
}

// ---------------- SGEMM (64x64, 4x4, pad 68, reg dbuf) — stage 3 ----------------
#define BM 64
#define BN 64
#define BK 16
#define BMP 68
__global__ __launch_bounds__(256) void k_sgemm(const float* __restrict__ A,
                                               const float* __restrict__ B,
                                               float* __restrict__ C, int K,
                                               const int* __restrict__ list,
                                               const float* __restrict__ tansel,
                                               const float* __restrict__ brelu,
                                               const float* __restrict__ wrel,
                                               const float* __restrict__ wroot,
                                               float* __restrict__ rrel4,
                                               float* __restrict__ rroot4) {
    const int N = HDIM;
    __shared__ float As[BK][BMP];
    __shared__ float Bs[BK][BN];
    int tid = threadIdx.x;
    int tx = tid & 15, ty = tid >> 4;
    int row0 = blockIdx.y * BM, col0 = blockIdx.x * BN;
    int lm = tid >> 2;
    int arow = list ? list[row0 + lm] : (row0 + lm);
    float tv = tansel ? tansel[row0 + lm] : 1.0f;
    int crow[4];
#pragma unroll
    for (int i = 0; i < 4; i++) {
        int r = row0 + ty * 4 + i;
        crow[i] = list ? list[r] : r;
    }
    int k4 = (tid & 3) * 4;
    int kkB = tid >> 4, cB = (tid & 15) * 4;
    float4 aP = *reinterpret_cast<const float4*>(&A[(size_t)arow * K + k4]);
    float4 bP = *reinterpret_cast<const float4*>(&B[(size_t)kkB * N + col0 + cB]);
    float acc[4][4] = {};
    for (int kb = 0; kb < K; kb += BK) {
        As[k4 + 0][lm] = aP.x * tv; As[k4 + 1][lm] = aP.y * tv;
        As[k4 + 2][lm] = aP.z * tv; As[k4 + 3][lm] = aP.w * tv;
        *reinterpret_cast<float4*>(&Bs[kkB][cB]) = bP;
        __syncthreads();
        if (kb + BK < K) {
            aP = *reinterpret_cast<const float4*>(&A[(size_t)arow * K + kb + BK + k4]);
            bP = *reinterpret_cast<const float4*>(&B[(size_t)(kb + BK + kkB) * N + col0 + cB]);
        }
#pragma unroll
        for (int k = 0; k < BK; k++) {
            float4 a = *reinterpret_cast<float4*>(&As[k][ty * 4]);
            float4 b = *reinterpret_cast<float4*>(&Bs[k][tx * 4]);
            float av[4] = {a.x, a.y, a.z, a.w};
            float bv[4] = {b.x, b.y, b.z, b.w};
#pragma unroll
            for (int i = 0; i < 4; i++)
#pragma unroll
                for (int j = 0; j < 4; j++) acc[i][j] += av[i] * bv[j];
        }
        __syncthreads();
    }
    float4 bb = make_float4(0.f, 0.f, 0.f, 0.f);
    if (brelu) bb = *reinterpret_cast<const float4*>(&brelu[col0 + tx * 4]);
    float4 wr = make_float4(0.f, 0.f, 0.f, 0.f), wo = wr;
    if (wrel) {
        wr = *reinterpret_cast<const float4*>(&wrel[col0 + tx * 4]);
        wo = *reinterpret_cast<const float4*>(&wroot[col0 + tx * 4]);
    }
#pragma unroll
    for (int i = 0; i < 4; i++) {
        float4 v = make_float4(acc[i][0], acc[i][1], acc[i][2], acc[i][3]);
        if (brelu) {
            v.x = fmaxf(v.x + bb.x, 0.f);
            v.y = fmaxf(v.y + bb.y, 0.f);
            v.z = fmaxf(v.z + bb.z, 0.f);
            v.w = fmaxf(v.w + bb.w, 0.f);
        }
        *reinterpret_cast<float4*>(&C[(size_t)crow[i] * N + col0 + tx * 4]) = v;
        if (wrel) {
            float s1 = v.x * wr.x + v.y * wr.y + v.z * wr.z + v.w * wr.w;
            float s2 = v.x * wo.x + v.y * wo.y + v.z * wo.z + v.w * wo.w;
            for (int off = 8; off > 0; off >>= 1) {
                s1 += __shfl_down(s1, off, 16);
                s2 += __shfl_down(s2, off, 16);
            }
            if (tx == 0) {
                rrel4[(size_t)crow[i] * 4 + blockIdx.x] = s1;
                rroot4[(size_t)crow[i] * 4 + blockIdx.x] = s2;
            }
        }
    }
}

// ---------------- dual N-tile SGEMM (64x128), stages 1 & 2 ----------------
__global__ __launch_bounds__(256) void k_sgemm2(const float* __restrict__ A,
                                                const float* __restrict__ B,
                                                float* __restrict__ C, int K,
                                                const int* __restrict__ list,
                                                const float* __restrict__ tansel,
                                                const float* __restrict__ brelu,
                                                const float* __restrict__ wrel,
                                                const float* __restrict__ wroot,
                                                float* __restrict__ rrel4,
                                                float* __restrict__ rroot4) {
    const int N = HDIM;
    __shared__ float As[BK][BMP];
    __shared__ float Bs[BK][128];
    int tid = threadIdx.x;
    int tx = tid & 15, ty = tid >> 4;
    int row0 = blockIdx.y * BM, col0 = blockIdx.x * 128;
    int lm = tid >> 2;
    int arow = list ? list[row0 + lm] : (row0 + lm);
    float tv = tansel ? tansel[row0 + lm] : 1.0f;
    int crow[4];
#pragma unroll
    for (int i = 0; i < 4; i++) {
        int r = row0 + ty * 4 + i;
        crow[i] = list ? list[r] : r;
    }
    int k4 = (tid & 3) * 4;
    int kkB0 = tid >> 5, cB0 = (tid & 31) * 4;
    int kkB1 = (256 + tid) >> 5, cB1 = cB0;
    float4 aP = *reinterpret_cast<const float4*>(&A[(size_t)arow * K + k4]);
    float4 bP0 = *reinterpret_cast<const float4*>(&B[(size_t)kkB0 * N + col0 + cB0]);
    float4 bP1 = *reinterpret_cast<const float4*>(&B[(size_t)kkB1 * N + col0 + cB1]);
    float acc0[4][4] = {};
    float acc1[4][4] = {};
    for (int kb = 0; kb < K; kb += BK) {
        As[k4 + 0][lm] = aP.x * tv; As[k4 + 1][lm] = aP.y * tv;
        As[k4 + 2][lm] = aP.z * tv; As[k4 + 3][lm] = aP.w * tv;
        *reinterpret_cast<float4*>(&Bs[kkB0][cB0]) = bP0;
        *reinterpret_cast<float4*>(&Bs[kkB1][cB1]) = bP1;
        __syncthreads();
        if (kb + BK < K) {
            aP = *reinterpret_cast<const float4*>(&A[(size_t)arow * K + kb + BK + k4]);
            bP0 = *reinterpret_cast<const float4*>(&B[(size_t)(kb + BK + kkB0) * N + col0 + cB0]);
            bP1 = *reinterpret_cast<const float4*>(&B[(size_t)(kb + BK + kkB1) * N + col0 + cB1]);
        }
#pragma unroll
        for (int k = 0; k < BK; k++) {
            float4 a = *reinterpret_cast<float4*>(&As[k][ty * 4]);
            float4 b0 = *reinterpret_cast<float4*>(&Bs[k][tx * 4]);
            float4 b1 = *reinterpret_cast<float4*>(&Bs[k][64 + tx * 4]);
            float av[4] = {a.x, a.y, a.z, a.w};
            float bv0[4] = {b0.x, b0.y, b0.z, b0.w};
            float bv1[4] = {b1.x, b1.y, b1.z, b1.w};
#pragma unroll
            for (int i = 0; i < 4; i++) {
#pragma unroll
                for (int j = 0; j < 4; j++) {
                    acc0[i][j] += av[i] * bv0[j];
                    acc1[i][j] += av[i] * bv1[j];
                }
            }
        }
        __syncthreads();
    }
#pragma unroll
    for (int half = 0; half < 2; half++) {
        int cbase = col0 + half * 64;
        float (*acc)[4] = half ? acc1 : acc0;
        float4 bb = make_float4(0.f, 0.f, 0.f, 0.f);
        if (brelu) bb = *reinterpret_cast<const float4*>(&brelu[cbase + tx * 4]);
        float4 wr = make_float4(0.f, 0.f, 0.f, 0.f), wo = wr;
        if (wrel) {
            wr = *reinterpret_cast<const float4*>(&wrel[cbase + tx * 4]);
            wo = *reinterpret_cast<const float4*>(&wroot[cbase + tx * 4]);
        }
        int cb = blockIdx.x * 2 + half;
#pragma unroll
        for (int i = 0; i < 4; i++) {
            float4 v = make_float4(acc[i][0], acc[i][1], acc[i][2], acc[i][3]);
            if (brelu) {
                v.x = fmaxf(v.x + bb.x, 0.f);
                v.y = fmaxf(v.y + bb.y, 0.f);
                v.z = fmaxf(v.z + bb.z, 0.f);
                v.w = fmaxf(v.w + bb.w, 0.f);
            }
            *reinterpret_cast<float4*>(&C[(size_t)crow[i] * N + cbase + tx * 4]) = v;
            if (wrel) {
                float s1 = v.x * wr.x + v.y * wr.y + v.z * wr.z + v.w * wr.w;
                float s2 = v.x * wo.x + v.y * wo.y + v.z * wo.z + v.w * wo.w;
                for (int off = 8; off > 0; off >>= 1) {
                    s1 += __shfl_down(s1, off, 16);
                    s2 += __shfl_down(s2, off, 16);
                }
                if (tx == 0) {
                    rrel4[(size_t)crow[i] * 4 + cb] = s1;
                    rroot4[(size_t)crow[i] * 4 + cb] = s2;
                }
            }
        }
    }
}

// stages 2/3: wave per ACTIVE node; edges prefetched in lanes, broadcast via shfl
// (removes the serial ccsr[e]->addr->load chain; summation order identical)
__global__ __launch_bounds__(256) void k_gcn_agg(const float* __restrict__ hW,
                                                 const float* __restrict__ dis,
                                                 const int* __restrict__ rs,
                                                 const int* __restrict__ re,
                                                 const int* __restrict__ ccsr,
                                                 const float* __restrict__ cwedge,
                                                 const float* __restrict__ bias,
                                                 const int* __restrict__ list, int bpg,
                                                 const float* __restrict__ w_rel,
                                                 const float* __restrict__ w_root,
                                                 float* __restrict__ out,
                                                 float* __restrict__ r_rel,
                                                 float* __restrict__ r_root) {
    int blk = swz_block(blockIdx.x, bpg);
    int idx = blk * 4 + (threadIdx.x >> 6);
    int lane = threadIdx.x & 63;
    int wid = list[idx];
    float di = dis[wid];
    int e0 = rs[wid];
    int ne = re[wid] - e0;
    // parallel edge prefetch (ne <= 64 always: compact degree <= 16)
    int pse = (lane < ne) ? ccsr[e0 + lane] : 0;
    float psw = (lane < ne) ? cwedge[e0 + lane] : 0.f;
    float4 h = *reinterpret_cast<const float4*>(&hW[(size_t)wid * HDIM + lane * 4]);
    float self = di * di;
    float ax = h.x * self, ay = h.y * self, az = h.z * self, aw = h.w * self;
    for (int j = 0; j < ne; j++) {
        int s = __shfl(pse, j);
        float w = __shfl(psw, j);
        float4 hs = *reinterpret_cast<const float4*>(&hW[(size_t)s * HDIM + lane * 4]);
        ax += hs.x * w; ay += hs.y * w; az += hs.z * w; aw += hs.w * w;
    }
    float4 b = *reinterpret_cast<const float4*>(&bias[lane * 4]);
    float4 o;
    o.x = fmaxf(ax + b.x, 0.f);
    o.y = fmaxf(ay + b.y, 0.f);
    o.z = fmaxf(az + b.z, 0.f);
    o.w = fmaxf(aw + b.w, 0.f);
    *reinterpret_cast<float4*>(&out[(size_t)wid * HDIM + lane * 4]) = o;
    float4 wr = *reinterpret_cast<const float4*>(&w_rel[lane * 4]);
    float4 wo = *reinterpret_cast<const float4*>(&w_root[lane * 4]);
    float s1 = o.x * wr.x + o.y * wr.y + o.z * wr.z + o.w * wr.w;
    float s2 = o.x * wo.x + o.y * wo.y + o.z * wo.z + o.w * wo.w;
    for (int off = 32; off > 0; off >>= 1) {
        s1 += __shfl_down(s1, off);
        s2 += __shfl_down(s2, off);
    }
    if (lane == 0) { r_rel[wid] = s1; r_root[wid] = s2; }
}

// ---------------- fused score + top-k + readout (+compact-CSR emit) ----------------
// EMIT phase now runs only in block fc==0 (block-uniform branch; barrier structure
// uniform within each block).
template<bool STAGE1, bool EMIT, bool FIRST>
__global__ __launch_bounds__(256) void k_topkpool(const float* __restrict__ dis,
                                                  const int* __restrict__ rs,
                                                  const int* __restrict__ re,
                                                  const int* __restrict__ csr_in,
                                                  const float* __restrict__ r_rel,
                                                  const float* __restrict__ r_root,
                                                  const float* __restrict__ rrel4,
                                                  const float* __restrict__ rroot4,
                                                  const float* __restrict__ b_rel, int k,
                                                  int* __restrict__ list,
                                                  float* __restrict__ tanselG,
                                                  const float* __restrict__ h,
                                                  float* __restrict__ z, float invk,
                                                  float* __restrict__ disN,
                                                  int* __restrict__ csN,
                                                  int* __restrict__ ceN,
                                                  int* __restrict__ ccsrN,
                                                  float* __restrict__ cwedgeN,
                                                  int EPG) {
    __shared__ float rrel[NPG];
    __shared__ __align__(16) float sc[NPG];
    __shared__ int sels[NPG];
    __shared__ float disn[NPG];
    __shared__ int newl[128];
    __shared__ float tvsel[128];
    __shared__ int wtot[4];
    __shared__ float4 red4_s[4][16];
    __shared__ float4 red4_m[4][16];
    int g = blockIdx.x >> 2, fc = blockIdx.x & 3;
    int tid = threadIdx.x;
    int lane = tid & 63, w4 = tid >> 6;
    int n = g * NPG + tid;
    bool act = STAGE1 ? true : (dis[n] > 0.f);
    float rr, ro;
    if (STAGE1) {
        float4 r4 = *reinterpret_cast<const float4*>(&rrel4[(size_t)n * 4]);
        float4 o4 = *reinterpret_cast<const float4*>(&rroot4[(size_t)n * 4]);
        rr = ((r4.x + r4.y) + r4.z) + r4.w;
        ro = ((o4.x + o4.y) + o4.z) + o4.w;
    } else {
        rr = act ? r_rel[n] : 0.f;
        ro = act ? r_root[n] : 0.f;
    }
    rrel[tid] = act ? rr : 0.f;
    __syncthreads();
    int e0 = rs[n], e1 = re[n];
    float my;
    if (act) {
        float s = b_rel[0] + ro;
        for (int e = e0; e < e1; e++) s += rrel[csr_in[e] & (NPG - 1)];
        my = s;
    } else {
        my = -INFINITY;
    }
    sc[tid] = my;
    __syncthreads();
    int cnt = 0;
    {
        const float4* sc4 = reinterpret_cast<const float4*>(sc);
        for (int jj = 0; jj < NPG / 4; jj++) {
            float4 v = sc4[jj];
            int j0 = jj * 4;
            cnt += (v.x > my || (v.x == my && (j0 + 0) < tid)) ? 1 : 0;
            cnt += (v.y > my || (v.y == my && (j0 + 1) < tid)) ? 1 : 0;
            cnt += (v.z > my || (v.z == my && (j0 + 2) < tid)) ? 1 : 0;
            cnt += (v.w > my || (v.w == my && (j0 + 3) < tid)) ? 1 : 0;
        }
    }
    int a = (cnt < k) ? 1 : 0;
    sels[tid] = a;
    int incl;
    {
        int v = a;
        for (int off = 1; off < 64; off <<= 1) {
            int t = __shfl_up(v, off);
            if (lane >= off) v += t;
        }
        if (lane == 63) wtot[w4] = v;
        __syncthreads();
        int addv = 0;
        for (int i = 0; i < w4; i++) addv += wtot[i];
        incl = v + addv;
    }
    if (a) {
        int rk = incl - 1;
        newl[rk] = tid;
        float t = tanhf(my);
        tvsel[rk] = t;
        if (fc == 0 && list) {
            list[g * k + rk] = n;
            tanselG[g * k + rk] = t;
        }
    }
    if (EMIT) {
        if (fc == 0) {                 // block-uniform: only block 0 does emit work
            int deg2 = 0;
            if (a) {
                for (int e = e0; e < e1; e++) deg2 += sels[csr_in[e] & (NPG - 1)];
            }
            float dn = a ? rsqrtf((float)(1 + deg2)) : 0.f;
            disn[tid] = dn;
            disN[n] = dn;
            __syncthreads();
            int v = deg2;
            for (int off = 1; off < 64; off <<= 1) {
                int t = __shfl_up(v, off);
                if (lane >= off) v += t;
            }
            if (lane == 63) wtot[w4] = v;
            __syncthreads();
            int addv = 0;
            for (int i = 0; i < w4; i++) addv += wtot[i];
            int start = g * EPG + (v + addv) - deg2;
            csN[n] = start;
            ceN[n] = start + deg2;
            if (a) {
                int p = start;
                for (int e = e0; e < e1; e++) {
                    int srcg = csr_in[e];
                    int j = srcg & (NPG - 1);
                    if (sels[j]) {
                        ccsrN[p] = srcg;
                        cwedgeN[p] = disn[j] * dn;
                        p++;
                    }
                }
            }
        }
    }
    __syncthreads();
    {
        int q = tid & 15, sub = (tid >> 4) & 3, y = tid >> 6;
        const float4* h4 = reinterpret_cast<const float4*>(h);
        float4 s4 = make_float4(0.f, 0.f, 0.f, 0.f);
        float4 m4 = make_float4(-INFINITY, -INFINITY, -INFINITY, -INFINITY);
        for (int idx = y * 4 + sub; idx < k; idx += 16) {
            int node = g * NPG + newl[idx];
            float t = tvsel[idx];
            float4 v = h4[(size_t)node * (HDIM / 4) + fc * 16 + q];
            v.x *= t; v.y *= t; v.z *= t; v.w *= t;
            s4.x += v.x; s4.y += v.y; s4.z += v.z; s4.w += v.w;
            m4.x = fmaxf(m4.x, v.x); m4.y = fmaxf(m4.y, v.y);
            m4.z = fmaxf(m4.z, v.z); m4.w = fmaxf(m4.w, v.w);
        }
#pragma unroll
        for (int off = 16; off <= 32; off <<= 1) {
            s4.x += __shfl_down(s4.x, off); s4.y += __shfl_down(s4.y, off);
            s4.z += __shfl_down(s4.z, off); s4.w += __shfl_down(s4.w, off);
            m4.x = fmaxf(m4.x, __shfl_down(m4.x, off));
            m4.y = fmaxf(m4.y, __shfl_down(m4.y, off));
            m4.z = fmaxf(m4.z, __shfl_down(m4.z, off));
            m4.w = fmaxf(m4.w, __shfl_down(m4.w, off));
        }
        if (sub == 0) { red4_s[y][q] = s4; red4_m[y][q] = m4; }
        __syncthreads();
        if (tid < 16) {
            float4 a0 = red4_s[0][tid], a1 = red4_s[1][tid];
            float4 a2 = red4_s[2][tid], a3 = red4_s[3][tid];
            float4 S;
            S.x = ((a0.x + a1.x) + a2.x) + a3.x;
            S.y = ((a0.y + a1.y) + a2.y) + a3.y;
            S.z = ((a0.z + a1.z) + a2.z) + a3.z;
            S.w = ((a0.w + a1.w) + a2.w) + a3.w;
            float4 b0 = red4_m[0][tid], b1 = red4_m[1][tid];
            float4 b2 = red4_m[2][tid], b3 = red4_m[3][tid];
            float4 M;
            M.x = fmaxf(fmaxf(b0.x, b1.x), fmaxf(b2.x, b3.x));
            M.y = fmaxf(fmaxf(b0.y, b1.y), fmaxf(b2.y, b3.y));
            M.z = fmaxf(fmaxf(b0.z, b1.z), fmaxf(b2.z, b3.z));
            M.w = fmaxf(fmaxf(b0.w, b1.w), fmaxf(b2.w, b3.w));
            float4 Mean = make_float4(S.x * invk, S.y * invk, S.z * invk, S.w * invk);
            float4* z4 = reinterpret_cast<float4*>(z);
            int zb_ = (g * 768 + fc * 64) / 4 + tid;
            if (FIRST) {
                z4[zb_] = Mean;
                z4[zb_ + 64] = M;
                z4[zb_ + 128] = S;
            } else {
                float4 c0 = z4[zb_], c1 = z4[zb_ + 64], c2 = z4[zb_ + 128];
                c0.x += Mean.x; c0.y += Mean.y; c0.z += Mean.z; c0.w += Mean.w;
                c1.x += M.x; c1.y += M.y; c1.z += M.z; c1.w += M.w;
                c2.x += S.x; c2.y += S.y; c2.z += S.z; c2.w += S.w;
                z4[zb_] = c0;
                z4[zb_ + 64] = c1;
                z4[zb_ + 128] = c2;
            }
        }
    }
}

// ---------------- fused MLP (partial-sum groupings fixed) ----------------
__global__ __launch_bounds__(256) void k_mlp(const float* __restrict__ z,
                                             const float* __restrict__ W1, const float* __restrict__ b1,
                                             const float* __restrict__ W2, const float* __restrict__ b2,
                                             const float* __restrict__ W3, const float* __restrict__ b3,
                                             float* __restrict__ out) {
    __shared__ float zb[768];
    __shared__ float t1[256];
    __shared__ float t2[128];
    __shared__ float t3[10];
    __shared__ float lse;
    int g = blockIdx.x, tid = threadIdx.x;
    zb[tid] = z[g * 768 + tid];
    zb[tid + 256] = z[g * 768 + 256 + tid];
    zb[tid + 512] = z[g * 768 + 512 + tid];
    __syncthreads();
    {
        int col = tid;
        float r0 = 0.f, r1 = 0.f, r2 = 0.f, r3 = 0.f;
        for (int i = 0;   i < 192; i++) r0 += zb[i] * W1[(size_t)i * 256 + col];
        for (int i = 192; i < 384; i++) r1 += zb[i] * W1[(size_t)i * 256 + col];
        for (int i = 384; i < 576; i++) r2 += zb[i] * W1[(size_t)i * 256 + col];
        for (int i = 576; i < 768; i++) r3 += zb[i] * W1[(size_t)i * 256 + col];
        t1[col] = fmaxf(r0 + r1 + r2 + r3 + b1[col], 0.f);
    }
    __syncthreads();
    if (tid < 128) {
        int col = tid;
        float r0 = 0.f, r1 = 0.f, r2 = 0.f, r3 = 0.f;
        for (int i = 0;   i < 64;  i++) r0 += t1[i] * W2[(size_t)i * 128 + col];
        for (int i = 64;  i < 128; i++) r1 += t1[i] * W2[(size_t)i * 128 + col];
        for (int i = 128; i < 192; i++) r2 += t1[i] * W2[(size_t)i * 128 + col];
        for (int i = 192; i < 256; i++) r3 += t1[i] * W2[(size_t)i * 128 + col];
        t2[col] = fmaxf(((r0 + r1) + r2) + r3 + b2[col], 0.f);
    }
    __syncthreads();
    if (tid < 10) {
        float v = b3[tid];
        for (int i = 0; i < 128; i++) v += t2[i] * W3[(size_t)i * 10 + tid];
        t3[tid] = v;
    }
    __syncthreads();
    if (tid == 0) {
        float m = t3[0];
        for (int c = 1; c < 10; c++) m = fmaxf(m, t3[c]);
        float se = 0.f;
        for (int c = 0; c < 10; c++) se += expf(t3[c] - m);
        lse = m + logf(se);
    }
    __syncthreads();
    if (tid < 10) out[g * 10 + tid] = t3[tid] - lse;
}

// ---------------- launcher ----------------
extern "C" void kernel_launch(void* const* d_in, const int* in_sizes, int n_in,
                              void* d_out, int out_size, void* d_ws, size_t ws_size,
                              hipStream_t stream) {
    const float* x        = (const float*)d_in[0];
    const int*   ei       = (const int*)d_in[1];
    const float* conv1_W  = (const float*)d_in[3];
    const float* conv1_b  = (const float*)d_in[4];
    const float* conv2_W  = (const float*)d_in[5];
    const float* conv2_b  = (const float*)d_in[6];
    const float* conv3_W  = (const float*)d_in[7];
    const float* conv3_b  = (const float*)d_in[8];
    const float* p1_relW  = (const float*)d_in[9];
    const float* p1_relb  = (const float*)d_in[10];
    const float* p1_rootW = (const float*)d_in[11];
    const float* p2_relW  = (const float*)d_in[12];
    const float* p2_relb  = (const float*)d_in[13];
    const float* p2_rootW = (const float*)d_in[14];
    const float* fc1_W    = (const float*)d_in[15];
    const float* fc1_b    = (const float*)d_in[16];
    const float* fc2_W    = (const float*)d_in[17];
    const float* fc2_b    = (const float*)d_in[18];
    const float* fc3_W    = (const float*)d_in[19];
    const float* fc3_b    = (const float*)d_in[20];
    float* out = (float*)d_out;

    const int E = in_sizes[1] / 2;
    const int EPG = E / NG;
    const int* e_src = ei;
    const int* e_dst = ei + E;

    // workspace layout
    char* base = (char*)d_ws;
    size_t off = 0;
    auto alloc = [&](size_t bytes) { size_t o = off; off = (off + bytes + 255) & ~(size_t)255; return o; };
    float* hW     = (float*)(base + alloc((size_t)NN * HDIM * 4));   // also xa (NN x FIN)
    float* hcur   = (float*)(base + alloc((size_t)NN * HDIM * 4));
    float* dis    = (float*)(base + alloc(NN * 4));   // stage-2 dis
    float* dis2   = (float*)(base + alloc(NN * 4));   // stage-3 dis
    float* r_rel  = (float*)(base + alloc(NN * 4));
    float* r_root = (float*)(base + alloc(NN * 4));
    float* rrel4  = (float*)(base + alloc((size_t)NN * 4 * 4));
    float* rroot4 = (float*)(base + alloc((size_t)NN * 4 * 4));
    int*   rowptr = (int*)(base + alloc((NN + 1) * 4));
    int*   csr    = (int*)(base + alloc((size_t)E * 4));
    int*   cs1    = (int*)(base + alloc(NN * 4));
    int*   ce1    = (int*)(base + alloc(NN * 4));
    int*   ccsr1  = (int*)(base + alloc((size_t)E * 4));
    float* cwdg1  = (float*)(base + alloc((size_t)E * 4));
    int*   cs2    = (int*)(base + alloc(NN * 4));
    int*   ce2    = (int*)(base + alloc(NN * 4));
    int*   ccsr2  = (int*)(base + alloc((size_t)E * 4));
    float* cwdg2  = (float*)(base + alloc((size_t)E * 4));
    float* z      = (float*)(base + alloc((size_t)NG * 768 * 4));
    int*   list1  = (int*)(base + alloc((size_t)NG * 128 * 4));
    int*   list2  = (int*)(base + alloc((size_t)NG * 64 * 4));
    float* tans1  = (float*)(base + alloc((size_t)NG * 128 * 4));
    float* tans2  = (float*)(base + alloc((size_t)NG * 64 * 4));

    // CSR build + fused sort/stage-1 aggregation
    k_csr<<<NG, 256, 0, stream>>>(e_src, e_dst, EPG, rowptr, csr);
    float* xa = hW;
    k_sortagg<<<NN / 4, 256, 0, stream>>>(x, rowptr, csr, xa);

    // ---- stage 1 ----
    {
        dim3 ggrid(HDIM / 128, NN / BM);
        k_sgemm2<<<ggrid, 256, 0, stream>>>(xa, conv1_W, hcur, FIN, nullptr, nullptr,
                                            conv1_b, p1_relW, p1_rootW, rrel4, rroot4);
    }
    k_topkpool<true, true, true><<<NG * 4, 256, 0, stream>>>(
        nullptr, rowptr, rowptr + 1, csr, nullptr, nullptr, rrel4, rroot4, p1_relb, 128,
        list1, tans1, hcur, z, 1.0f / 128.0f, dis, cs1, ce1, ccsr1, cwdg1, EPG);

    // ---- stage 2 ----
    {
        dim3 ggrid(HDIM / 128, (NG * 128) / BM);
        k_sgemm2<<<ggrid, 256, 0, stream>>>(hcur, conv2_W, hW, HDIM, list1, tans1,
                                            nullptr, nullptr, nullptr, nullptr, nullptr);
    }
    k_gcn_agg<<<(NG * 128) / 4, 256, 0, stream>>>(hW, dis, cs1, ce1, ccsr1, cwdg1, conv2_b,
                                                  list1, 32, p2_relW, p2_rootW,
                                                  hcur, r_rel, r_root);
    k_topkpool<false, true, false><<<NG * 4, 256, 0, stream>>>(
        dis, cs1, ce1, ccsr1, r_rel, r_root, nullptr, nullptr, p2_relb, 64,
        list2, tans2, hcur, z, 1.0f / 64.0f, dis2, cs2, ce2, ccsr2, cwdg2, EPG);

    // ---- stage 3 ----
    {
        dim3 ggrid(HDIM / BN, (NG * 64) / BM);
        k_sgemm<<<ggrid, 256, 0, stream>>>(hcur, conv3_W, hW, HDIM, list2, tans2, nullptr,
                                           nullptr, nullptr, nullptr, nullptr);
    }
    k_gcn_agg<<<(NG * 64) / 4, 256, 0, stream>>>(hW, dis2, cs2, ce2, ccsr2, cwdg2, conv3_b,
                                                 list2, 16, p2_relW, p2_rootW,
                                                 hcur, r_rel, r_root);
    k_topkpool<false, false, false><<<NG * 4, 256, 0, stream>>>(
        dis2, cs2, ce2, ccsr2, r_rel, r_root, nullptr, nullptr, p2_relb, 32,
        nullptr, nullptr, hcur, z, 1.0f / 32.0f, nullptr, nullptr, nullptr, nullptr, nullptr, EPG);

    // ---- MLP ----
    k_mlp<<<NG, 256, 0, stream>>>(z, fc1_W, fc1_b, fc2_W, fc2_b, fc3_W, fc3_b, out);
}